// Round 1
// 2797.662 us; speedup vs baseline: 1.5754x; 1.5754x over previous
//
#include <hip/hip_runtime.h>
#include <hip/hip_bf16.h>
#include <math.h>

typedef __hip_bfloat16 bf16;
typedef __attribute__((ext_vector_type(8))) short short8;
typedef __attribute__((ext_vector_type(4))) float f32x4;

#define BQ 1024
#define NUME 20000
#define NET 17
#define DIMT 28
#define DIME 100
#define DIM 200
#define HEADS 4
#define OH 50
#define N0 160000
#define N1 40000
#define RNODES 8192
#define E0 60000
#define E1 16000
#define KK 500000
#define DIMR 100
#define HATT 4
#define OA 50
#define DIN0 128
#define DIN1 228
#define HD 800
#define NROWS 2048

__device__ __forceinline__ float b2f(bf16 v){ return __bfloat162float(v); }
__device__ __forceinline__ bf16 f2b(float v){ return __float2bfloat16(v); }
__device__ __forceinline__ float bs2f(unsigned short u){ return __uint_as_float((unsigned)u << 16); }

// ---- dtype normalization ----------------------------------------------------
static constexpr int CVT_NREG = 29;
static constexpr int CVT_N[CVT_NREG] = {
  2000000, 28, 28, 435200, 3400, 3400, 3400, 775200, 3400, 3400, 3400,
  800, 800, 40000, 200, 40000, 200, 800, 800, 160000, 200, 800, 800,
  20000, 20000, 800, 800, 20000, 20000
};
static constexpr int CVT_DIN[CVT_NREG] = {
  12,13,14,15,16,17,18,19,20,21,22,23,24,25,26,27,28,29,30,31,32,33,34,36,38,39,40,42,44
};
struct CvtSrcs { const void* p[CVT_NREG]; };
struct CvtMeta { int cum[CVT_NREG+1]; int bcum[CVT_NREG+1]; };

__global__ __launch_bounds__(64) void k_detect(const unsigned* tfw, unsigned* flag){
  if (threadIdx.x == 0) flag[0] = ((tfw[0] & 0xFFFFu) == 0u) ? 1u : 0u;
}

__global__ __launch_bounds__(256) void k_cvt(CvtSrcs srcs, CvtMeta meta, bf16* dst, const unsigned* flagp){
  int b = blockIdx.x;
  int r = 0;
  while (meta.bcum[r+1] <= b) r++;          // uniform per block (scalar loop)
  int i = (b - meta.bcum[r])*256 + threadIdx.x;
  int n = meta.cum[r+1] - meta.cum[r];
  if (i >= n) return;
  bool f32m = flagp[0] != 0u;
  bf16 v;
  if (f32m) v = f2b(((const float*)srcs.p[r])[i]);
  else      v = ((const bf16*)srcs.p[r])[i];
  dst[meta.cum[r] + i] = v;
}

__global__ __launch_bounds__(256) void k_fill_u32(unsigned* p, unsigned v, long n){
  long i = (long)blockIdx.x*256 + threadIdx.x;
  if (i < n) p[i] = v;
}

__global__ __launch_bounds__(256) void k_fill_out(void* outb, const unsigned* flagp){
  bool f32m = flagp[0] != 0u;
  long nwords = f32m ? (long)2*BQ*NUME : (long)BQ*NUME;
  long i = (long)blockIdx.x*256 + threadIdx.x;
  if (i >= nwords) return;
  unsigned* p = (unsigned*)((char*)outb + (size_t)2*BQ*NUME * (f32m ? 4 : 2));
  p[i] = f32m ? 0xC2C80000u : 0xC2C8C2C8u;
}

__global__ __launch_bounds__(256) void k_prep_w(const bf16* Wg, const bf16* al, const bf16* ar,
                                                float* wal, float* war, int DIN){
  int idx = blockIdx.x*256 + threadIdx.x;
  int total = NET*DIN*4;
  if (idx >= total) return;
  int h = idx & 3; int ri = idx >> 2; int i = ri % DIN; int r = ri / DIN;
  const bf16* wrow = Wg + ((size_t)(r*DIN + i))*HEADS*OH + h*OH;
  const bf16* alr = al + (size_t)(r*HEADS + h)*OH;
  const bf16* arr = ar + (size_t)(r*HEADS + h)*OH;
  float sl=0.f, sr=0.f;
  for (int o=0;o<OH;o++){ float w=b2f(wrow[o]); sl += w*b2f(alr[o]); sr += w*b2f(arr[o]); }
  wal[idx]=sl; war[idx]=sr;
}

// pack W into MFMA B-fragment order: wpk[((r*KS+ks)*13+nt)*512 + lane*8 + j]
__global__ __launch_bounds__(256) void k_pack(const bf16* Wg, bf16* wpk, int DIN, int KS){
  int idx = blockIdx.x*256 + threadIdx.x;
  int total = NET*KS*13*512;
  if (idx >= total) return;
  int j = idx & 7, lane = (idx>>3) & 63;
  int rem = idx >> 9;
  int nt = rem % 13, rks = rem / 13;
  int ks = rks % KS, r = rks / KS;
  int k = ks*32 + (lane>>4)*8 + j;
  int n = nt*16 + (lane&15);
  bf16 v = f2b(0.f);
  if (k < DIN && n < 200) v = Wg[((size_t)r*DIN + k)*200 + n];
  wpk[idx] = v;
}

__global__ __launch_bounds__(256) void k_bgs(const bf16* bg0, const bf16* bg1, float* bgs0, float* bgs1){
  int j = blockIdx.x*256 + threadIdx.x;
  if (j < DIM){ float s=0.f; for(int r=0;r<NET;r++) s += b2f(bg0[r*DIM+j]); bgs0[j]=s; }
  else if (j < 2*DIM){ int jj=j-DIM; float s=0.f; for(int r=0;r<NET;r++) s += b2f(bg1[r*DIM+jj]); bgs1[jj]=s; }
}

__global__ __launch_bounds__(256) void k_build_x0(const int* nid0, const int* ts_p, const bf16* emb,
                                                  const bf16* tf, const bf16* tp, bf16* x0){
  long idx = (long)blockIdx.x*256 + threadIdx.x;
  if (idx >= (long)N0*DIN0) return;
  int n = idx / DIN0, j = idx % DIN0;
  int nid = nid0[n];
  bf16 v;
  if (j < DIME) v = emb[(size_t)(nid % NUME)*DIME + j];
  else {
    float t = (float)(ts_p[0] - nid / NUME);
    int jj = j - DIME;
    v = f2b(cosf(t * b2f(tf[jj]) + b2f(tp[jj])));
  }
  x0[idx] = v;
}

__global__ __launch_bounds__(256) void k_build_x1(const int* nid0, const int* ts_p, const float* msg0,
                                                  const float* bgs0, const bf16* tf, const bf16* tp, bf16* x1){
  long idx = (long)blockIdx.x*256 + threadIdx.x;
  if (idx >= (long)N1*DIN1) return;
  int n = idx / DIN1, j = idx % DIN1;
  bf16 v;
  if (j < DIM){
    v = f2b(fmaxf((msg0[(size_t)n*DIM + j] + bgs0[j]) * (1.0f/NET), 0.0f));
  } else {
    int nid = nid0[n];
    float t = (float)(ts_p[0] - nid / NUME);
    int jj = j - DIM;
    v = f2b(cosf(t * b2f(tf[jj]) + b2f(tp[jj])));
  }
  x1[idx] = v;
}

template<int DIN>
__global__ __launch_bounds__(256) void k_er(const bf16* __restrict__ x, const float* __restrict__ war,
                                            bf16* __restrict__ er, int nd){
  int idx = blockIdx.x*256 + threadIdx.x;
  if (idx >= NET*nd) return;
  int r = idx / nd, n = idx % nd;
  const ushort4* xr = (const ushort4*)(x + (size_t)n*DIN);
  const float4* w = (const float4*)(war + (size_t)r*DIN*4);
  float a0=0.f,a1=0.f,a2=0.f,a3=0.f;
  #pragma unroll 4
  for (int i=0;i<DIN/4;i++){
    ushort4 xv = xr[i];
    float x0=bs2f(xv.x), x1=bs2f(xv.y), x2=bs2f(xv.z), x3=bs2f(xv.w);
    float4 w0=w[4*i], w1=w[4*i+1], w2=w[4*i+2], w3=w[4*i+3];
    a0 += x0*w0.x + x1*w1.x + x2*w2.x + x3*w3.x;
    a1 += x0*w0.y + x1*w1.y + x2*w2.y + x3*w3.y;
    a2 += x0*w0.z + x1*w1.z + x2*w2.z + x3*w3.z;
    a3 += x0*w0.w + x1*w1.w + x2*w2.w + x3*w3.w;
  }
  bf16* e = er + (size_t)idx*4;
  e[0]=f2b(a0); e[1]=f2b(a1); e[2]=f2b(a2); e[3]=f2b(a3);
}

template<int DIN>
__global__ __launch_bounds__(256) void k_edge(const bf16* __restrict__ x, const float* __restrict__ wal,
                                              const bf16* __restrict__ er,
                                              const int* __restrict__ src, const int* __restrict__ dst,
                                              bf16* abuf, float* z, int nE, int nd){
  int idx = blockIdx.x*256 + threadIdx.x;
  if (idx >= NET*nE) return;
  int r = idx / nE;
  int s = src[idx], d = dst[idx];
  const ushort4* xr = (const ushort4*)(x + (size_t)s*DIN);
  const float4* w = (const float4*)(wal + (size_t)r*DIN*4);
  float a0=0.f,a1=0.f,a2=0.f,a3=0.f;
  #pragma unroll 4
  for (int i=0;i<DIN/4;i++){
    ushort4 xv = xr[i];
    float x0=bs2f(xv.x), x1=bs2f(xv.y), x2=bs2f(xv.z), x3=bs2f(xv.w);
    float4 w0=w[4*i], w1=w[4*i+1], w2=w[4*i+2], w3=w[4*i+3];
    a0 += x0*w0.x + x1*w1.x + x2*w2.x + x3*w3.x;
    a1 += x0*w0.y + x1*w1.y + x2*w2.y + x3*w3.y;
    a2 += x0*w0.z + x1*w1.z + x2*w2.z + x3*w3.z;
    a3 += x0*w0.w + x1*w1.w + x2*w2.w + x3*w3.w;
  }
  float acc[4] = {a0,a1,a2,a3};
  const bf16* ern = er + ((size_t)r*nd + d)*4;
  float* zp = z + ((size_t)r*nd + d)*4;
  bf16* ao = abuf + (size_t)idx*4;
  #pragma unroll
  for (int h=0;h<4;h++){
    float v = acc[h] + b2f(ern[h]);
    v = v>0.f ? v : 0.2f*v;
    float a = expf(fminf(v, 80.f));
    ao[h] = f2b(a);
    atomicAdd(&zp[h], a);
  }
}

// ---- CSR build over destination ids ----------------------------------------
__global__ __launch_bounds__(256) void k_count(const int* __restrict__ dst, long n, unsigned* cnt){
  long i = (long)blockIdx.x*256 + threadIdx.x;
  if (i >= n) return;
  atomicAdd(&cnt[dst[i]], 1u);
}

__global__ __launch_bounds__(256) void k_scan(const unsigned* __restrict__ cnt, unsigned* offs, unsigned* cur, int n){
  __shared__ unsigned part[256];
  __shared__ unsigned tot;
  int t = threadIdx.x;
  int chunk = (n + 255)/256;
  int lo = t*chunk, hi = lo+chunk; if (hi > n) hi = n; if (lo > n) lo = n;
  unsigned s = 0;
  for (int i=lo;i<hi;i++) s += cnt[i];
  part[t] = s;
  __syncthreads();
  if (t==0){
    unsigned r = 0;
    for (int i=0;i<256;i++){ unsigned v = part[i]; part[i] = r; r += v; }
    tot = r;
  }
  __syncthreads();
  unsigned run = part[t];
  for (int i=lo;i<hi;i++){ offs[i]=run; cur[i]=run; run += cnt[i]; }
  if (t==0) offs[n] = tot;
}

__global__ __launch_bounds__(256) void k_fillcsr(const int* __restrict__ dst, long n, unsigned* cur, int* ids){
  long i = (long)blockIdx.x*256 + threadIdx.x;
  if (i >= n) return;
  unsigned pos = atomicAdd(&cur[dst[i]], 1u);
  ids[pos] = (int)i;                    // i == (r-r0)*nE + e, the F row index
}

// ---- MFMA edge-GEMM ---------------------------------------------------------
// mode 0: atomic scatter into msg (fallback).  mode 1: write alpha*fs rows to
// fbuf (bf16, linear per edge) for the CSR gather stage.
template<int DIN, int KS>
__global__ __launch_bounds__(256) void k_acc_mfma(const bf16* __restrict__ x, const bf16* __restrict__ wpk,
                                                  const bf16* __restrict__ abuf, const float* __restrict__ z,
                                                  const int* __restrict__ src, const int* __restrict__ dst,
                                                  float* msg, bf16* fbuf, int nE, int nd, int r0, int mode){
  constexpr int KM = KS*32;
  constexpr int SR = KM + 8;          // LDS row stride (bf16): +8 breaks bank aliasing
  __shared__ bf16 xs[64*SR];
  __shared__ float alpha_s[64*4];
  __shared__ int sdst[64], ssrc[64];
  int r = r0 + blockIdx.y;
  int eb = blockIdx.x*64;
  int me = min(64, nE - eb);
  int t = threadIdx.x;
  if (t < 64){
    int v_src=0, v_dst=0;
    if (t < me){ v_src = src[(size_t)r*nE + eb + t]; v_dst = dst[(size_t)r*nE + eb + t]; }
    ssrc[t]=v_src; sdst[t]=v_dst;
  }
  __syncthreads();
  { // alpha per (edge, head)
    int m = t>>2, h = t&3;
    float al = 0.f;
    if (m < me){
      float a = b2f(abuf[((size_t)r*nE + eb + m)*4 + h]);
      float zz = z[((size_t)r*nd + sdst[m])*4 + h];
      al = a / fmaxf(zz, 1e-30f);
    }
    alpha_s[m*4+h] = al;
  }
  // stage x rows (zero-pad cols >= DIN and rows >= me)
  constexpr int CH = KM/4;           // 8-byte chunks per row
  for (int c = t; c < 64*CH; c += 256){
    int m = c / CH, j4 = c % CH;
    uint2 v = make_uint2(0u,0u);
    if (m < me && j4*4 < DIN) v = *(const uint2*)(x + (size_t)ssrc[m]*DIN + j4*4);
    *(uint2*)(xs + m*SR + j4*4) = v;
  }
  __syncthreads();

  int lane = t & 63, w = t >> 6;
  int n_idx = lane & 15, quad = lane >> 4;
  const short8* wpk8 = (const short8*)wpk;
  for (int mt=0; mt<4; mt++){
    short8 a[KS];
    const bf16* abase = xs + (size_t)(mt*16 + n_idx)*SR + quad*8;
    #pragma unroll
    for (int ks=0; ks<KS; ks++) a[ks] = *(const short8*)(abase + ks*32);
    for (int nt=w; nt<13; nt+=4){
      const short8* bp = wpk8 + (((size_t)r*KS)*13 + nt)*64 + lane;
      f32x4 acc = {0.f,0.f,0.f,0.f};
      #pragma unroll
      for (int ks=0; ks<KS; ks++){
        short8 b = bp[(size_t)ks*13*64];
        acc = __builtin_amdgcn_mfma_f32_16x16x32_bf16(a[ks], b, acc, 0, 0, 0);
      }
      int n = nt*16 + n_idx;
      if (n < 200){
        int h = n / 50;
        #pragma unroll
        for (int reg=0; reg<4; reg++){
          int m = mt*16 + quad*4 + reg;
          float val = acc[reg] * alpha_s[m*4+h];
          if (mode == 0){
            atomicAdd(&msg[(size_t)sdst[m]*200 + n], val);
          } else {
            int e = eb + m;
            if (e < nE) fbuf[((size_t)(r - r0)*nE + e)*200 + n] = f2b(val);
          }
        }
      }
    }
  }
}

// ---- CSR gather: one wave per destination row, zero atomics ----------------
__global__ __launch_bounds__(256) void k_gather(const bf16* __restrict__ F, const unsigned* __restrict__ offs,
                                                const int* __restrict__ ids, float* __restrict__ msg,
                                                int nd, int accum){
  int w = threadIdx.x >> 6, lane = threadIdx.x & 63;
  int d = blockIdx.x*4 + w;
  if (d >= nd) return;
  unsigned k0 = offs[d], k1 = offs[d+1];
  float a0=0.f, a1=0.f, a2=0.f, a3=0.f;
  for (unsigned k=k0; k<k1; k++){
    int id = ids[k];
    if (lane < 50){
      ushort4 v = *(const ushort4*)(F + (size_t)id*200 + lane*4);
      a0 += bs2f(v.x); a1 += bs2f(v.y); a2 += bs2f(v.z); a3 += bs2f(v.w);
    }
  }
  if (lane < 50){
    float4* out = (float4*)(msg + (size_t)d*200 + lane*4);
    if (accum){ float4 p = *out; a0 += p.x; a1 += p.y; a2 += p.z; a3 += p.w; }
    float4 o; o.x=a0; o.y=a1; o.z=a2; o.w=a3;
    *out = o;
  }
}

__global__ __launch_bounds__(256) void k_hid(const float* msg1, const float* bgs1, const int* root_idx, float* hid){
  long idx = (long)blockIdx.x*256 + threadIdx.x;
  if (idx >= (long)NROWS*HD) return;
  int b = idx / HD, c = idx % HD;
  int s = c / DIM, j = c % DIM;
  int n = root_idx[b*4 + s];
  hid[idx] = fmaxf((msg1[(size_t)n*DIM + j] + bgs1[j]) * (1.0f/NET), 0.0f);
}

__global__ __launch_bounds__(256) void k_ln(const float* xin, const bf16* w, const bf16* b, float* xout){
  int row = blockIdx.x;
  const float* xr = xin + (size_t)row*HD;
  __shared__ float red[16];
  __shared__ float mu_s, rs_s;
  float s=0.f, s2=0.f;
  for (int j=threadIdx.x;j<HD;j+=256){ float v=xr[j]; s+=v; s2+=v*v; }
  for (int off=32; off; off>>=1){ s += __shfl_down(s,off); s2 += __shfl_down(s2,off); }
  int lane = threadIdx.x & 63, wid = threadIdx.x >> 6;
  if (lane==0){ red[wid]=s; red[8+wid]=s2; }
  __syncthreads();
  if (threadIdx.x==0){
    float S = red[0]+red[1]+red[2]+red[3];
    float S2 = red[8]+red[9]+red[10]+red[11];
    float mu = S * (1.0f/HD);
    float var = fmaxf(S2 * (1.0f/HD) - mu*mu, 0.f);
    mu_s = mu; rs_s = rsqrtf(var + 1e-5f);
  }
  __syncthreads();
  float mu = mu_s, rs = rs_s;
  for (int j=threadIdx.x;j<HD;j+=256){
    float v = (xr[j]-mu)*rs;
    xout[(size_t)row*HD + j] = v*b2f(w[j]) + b2f(b[j]);
  }
}

__global__ __launch_bounds__(256) void k_att(const float* xln, const bf16* Wq, const bf16* bq,
                                             const bf16* Wv, const bf16* bv, float* x2){
  __shared__ float xs[HD], qs[HD], vs[HD], att_s[64];
  int b = blockIdx.x, t = threadIdx.x;
  for (int j=t;j<HD;j+=256) xs[j] = xln[(size_t)b*HD + j];
  __syncthreads();
  for (int idx=t; idx<HD; idx+=256){
    int ha = idx/200, srow=(idx%200)/50, o=idx%50;
    const float* xr = xs + srow*200;
    const bf16* wq = Wq + (size_t)ha*DIM*OA + o;
    const bf16* wv = Wv + (size_t)ha*DIM*OA + o;
    float q=0.f, v=0.f;
    for (int e=0;e<DIM;e++){ float xv=xr[e]; q += xv*b2f(wq[(size_t)e*OA]); v += xv*b2f(wv[(size_t)e*OA]); }
    qs[idx] = q + b2f(bq[ha*OA+o]);
    vs[idx] = v + b2f(bv[ha*OA+o]);
  }
  __syncthreads();
  if (t < 64){
    int ha=t>>4, srow=(t>>2)&3, tt=t&3;
    const float* qa = qs + ha*200 + srow*50;
    const float* qb = qs + ha*200 + tt*50;
    float sc=0.f;
    for (int o=0;o<50;o++) sc += qa[o]*qb[o];
    att_s[ha*16 + srow*4 + tt] = sc;
  }
  __syncthreads();
  if (t < 16){
    int ha=t>>2, tt=t&3;
    float m=-1e30f;
    for (int srow=0;srow<4;srow++) m = fmaxf(m, att_s[ha*16+srow*4+tt]);
    float ex[4]; float zz=0.f;
    for (int srow=0;srow<4;srow++){ ex[srow]=expf(att_s[ha*16+srow*4+tt]-m); zz+=ex[srow]; }
    for (int srow=0;srow<4;srow++) att_s[ha*16+srow*4+tt] = ex[srow]/zz;
  }
  __syncthreads();
  for (int idx=t; idx<HD; idx+=256){
    int ha = idx/200, srow=(idx%200)/50, o=idx%50;
    float a=0.f;
    for (int tt=0;tt<4;tt++) a += att_s[ha*16+srow*4+tt]*vs[ha*200+tt*50+o];
    x2[(size_t)b*HD + srow*200 + ha*50 + o] = fmaxf(a, 0.f);
  }
}

__global__ __launch_bounds__(256) void k_d1(const float* x3, const bf16* Wd1, const bf16* bd1, float* x4){
  __shared__ float xs[8*HD];
  int rb = blockIdx.x*8, t = threadIdx.x;
  for (int idx=t; idx<8*HD; idx+=256) xs[idx] = x3[(size_t)rb*HD + idx];
  __syncthreads();
  if (t < DIM){
    float acc[8] = {0,0,0,0,0,0,0,0};
    for (int k=0;k<HD;k++){
      float w = b2f(Wd1[(size_t)k*DIM + t]);
      #pragma unroll
      for (int r=0;r<8;r++) acc[r] += xs[r*HD+k]*w;
    }
    float bb = b2f(bd1[t]);
    for (int r=0;r<8;r++) x4[(size_t)(rb+r)*DIM + t] = fmaxf(acc[r]+bb, 0.f);
  }
}

__global__ __launch_bounds__(256) void k_pred(const float* xemb, const bf16* relemb, const int* rel,
                                              const void* W, const bf16* bias, void* outb, size_t elem_off,
                                              const unsigned* flagp){
  __shared__ float As[16*304];
  bool f32m = flagp[0] != 0u;
  int rb = blockIdx.y*16;
  int cb = blockIdx.x*512;
  int t = threadIdx.x;
  for (int idx=t; idx<16*300; idx+=256){
    int r = idx/300, i = idx%300;
    int row = rb + r;
    float v = (i < DIM) ? xemb[(size_t)row*DIM + i]
                        : b2f(relemb[(size_t)rel[row]*DIMR + (i-DIM)]);
    As[r*304+i] = v;
  }
  __syncthreads();
  int c0 = cb + t, c1 = cb + 256 + t;
  bool g0 = c0 < NUME, g1 = c1 < NUME;
  float acc0[16], acc1[16];
  #pragma unroll
  for (int r=0;r<16;r++){ acc0[r]=0.f; acc1[r]=0.f; }
  if (f32m){
    const float* W32 = (const float*)W;
    for (int k=0;k<300;k++){
      float w0 = g0 ? W32[(size_t)k*NUME + c0] : 0.f;
      float w1 = g1 ? W32[(size_t)k*NUME + c1] : 0.f;
      #pragma unroll
      for (int r=0;r<16;r++){ float a = As[r*304+k]; acc0[r] += a*w0; acc1[r] += a*w1; }
    }
  } else {
    const bf16* W16 = (const bf16*)W;
    for (int k=0;k<300;k++){
      float w0 = g0 ? b2f(W16[(size_t)k*NUME + c0]) : 0.f;
      float w1 = g1 ? b2f(W16[(size_t)k*NUME + c1]) : 0.f;
      #pragma unroll
      for (int r=0;r<16;r++){ float a = As[r*304+k]; acc0[r] += a*w0; acc1[r] += a*w1; }
    }
  }
  #pragma unroll
  for (int rr=0; rr<2; rr++){
    int c = rr ? c1 : c0;
    float* acc = rr ? acc1 : acc0;
    if (c < NUME){
      float bb = b2f(bias[c]);
      for (int r=0;r<16;r++){
        size_t oi = elem_off + (size_t)(rb+r)*NUME + c;
        float val = acc[r] + bb;
        if (f32m) ((float*)outb)[oi] = val; else ((bf16*)outb)[oi] = f2b(val);
      }
    }
  }
}

__global__ __launch_bounds__(256) void k_transpose(const void* in, bf16* out, int rows, int cols,
                                                   const unsigned* flagp){
  __shared__ bf16 tile[32][33];
  bool f32m = flagp[0] != 0u;
  int c0 = blockIdx.x*32, r0 = blockIdx.y*32;
  int tx = threadIdx.x % 32, ty = threadIdx.x / 32;
  for (int rr=ty; rr<32; rr+=8){
    int r = r0+rr, c = c0+tx;
    if (r<rows && c<cols){
      size_t i = (size_t)r*cols + c;
      tile[rr][tx] = f32m ? f2b(((const float*)in)[i]) : ((const bf16*)in)[i];
    }
  }
  __syncthreads();
  for (int rr=ty; rr<32; rr+=8){
    int ocol = c0+rr, orow = r0+tx;
    if (ocol<cols && orow<rows) out[(size_t)ocol*rows + orow] = tile[tx][rr];
  }
}

__global__ __launch_bounds__(256) void k_scatter(const int* copy_rows, const int* copy_cols, const int* rel,
                                                 const float* hid, const bf16* csrel, const bf16* corel,
                                                 const bf16* cWsubT, const bf16* cWobjT,
                                                 const bf16* cbsub, const bf16* cbobj,
                                                 void* outb, const unsigned* flagp){
  bool f32m = flagp[0] != 0u;
  int wid = threadIdx.x >> 6, lane = threadIdx.x & 63;
  long k = (long)blockIdx.x*4 + wid;
  if (k >= KK) return;
  int row = copy_rows[k], col = copy_cols[k];
  const float* chrow; const bf16* re; const bf16* wt; float bias_v;
  if (row < BQ){
    chrow = hid + ((size_t)(BQ+row))*HD + 600;
    re = corel + (size_t)rel[row]*DIMR;
    wt = cWsubT + (size_t)col*300;
    bias_v = b2f(cbsub[col]);
  } else {
    int rr = row - BQ;
    chrow = hid + ((size_t)rr)*HD + 600;
    re = csrel + (size_t)rel[rr]*DIMR;
    wt = cWobjT + (size_t)col*300;
    bias_v = b2f(cbobj[col]);
  }
  float s = 0.f;
  for (int i=lane; i<300; i+=64){
    float a = (i < DIM) ? chrow[i] : b2f(re[i-DIM]);
    s += a * b2f(wt[i]);
  }
  for (int off=32; off; off>>=1) s += __shfl_down(s, off);
  if (lane==0){
    size_t oi = (size_t)2*BQ*NUME + (size_t)row*NUME + col;
    float val = s + bias_v;
    if (f32m) ((float*)outb)[oi] = val; else ((bf16*)outb)[oi] = f2b(val);
  }
}

static inline dim3 GS(long n){ return dim3((unsigned)((n + 255)/256)); }

extern "C" void kernel_launch(void* const* d_in, const int* in_sizes, int n_in,
                              void* d_out, int out_size, void* d_ws, size_t ws_size,
                              hipStream_t stream){
  const int* rel       = (const int*)d_in[2];
  const int* ts_p      = (const int*)d_in[3];
  const int* nid0      = (const int*)d_in[4];
  const int* root_idx  = (const int*)d_in[5];
  const int* src0      = (const int*)d_in[6];
  const int* dst0      = (const int*)d_in[7];
  const int* src1      = (const int*)d_in[8];
  const int* dst1      = (const int*)d_in[9];
  const int* copy_rows = (const int*)d_in[10];
  const int* copy_cols = (const int*)d_in[11];
  const void* Wsub  = d_in[35];
  const void* Wobj  = d_in[37];
  const void* cWsub = d_in[41];
  const void* cWobj = d_in[43];

  // ---- workspace layout ----
  char* base = (char*)d_ws;
  size_t off = 0;
  auto alloc = [&](size_t bytes)->char*{
    char* p = base + off; off = (off + bytes + 255) & ~(size_t)255; return p;
  };
  unsigned* flagp = (unsigned*)alloc(256);
  long cvt_total = 0; for (int i=0;i<CVT_NREG;i++) cvt_total += CVT_N[i];
  bf16* normb = (bf16*)alloc((size_t)cvt_total*2);
  bf16* x0    = (bf16*)alloc((size_t)N0*DIN0*2);       // 40.96 MB (reused for cW*T later)
  bf16* x1    = (bf16*)alloc((size_t)N1*DIN1*2);       // 18.24 MB
  float* msg0 = (float*)alloc((size_t)N1*DIM*4);       // 32 MB
  float* wal0 = (float*)alloc((size_t)NET*DIN0*4*4);
  float* war0 = (float*)alloc((size_t)NET*DIN0*4*4);
  float* wal1 = (float*)alloc((size_t)NET*DIN1*4*4);
  float* war1 = (float*)alloc((size_t)NET*DIN1*4*4);
  float* bgs0 = (float*)alloc(DIM*4);
  float* bgs1 = (float*)alloc(DIM*4);
  bf16* wpk0  = (bf16*)alloc((size_t)NET*4*13*512*2);  // 0.91 MB
  bf16* wpk1  = (bf16*)alloc((size_t)NET*8*13*512*2);  // 1.81 MB
  size_t arena = off;
  // phase-1 (GAT layer 0): er0/a0 bf16, z0 f32
  bf16*  er0 = (bf16*)(base + arena);
  bf16*  a0b = (bf16*)((char*)er0 + (size_t)NET*N1*8);
  float* z0  = (float*)((char*)a0b + (size_t)NET*E0*8);
  // phase-2 (layer 1 + tail) — overlays phase-1
  char* A = base + arena;
  bf16*  er1  = (bf16*)A;
  bf16*  a1b  = (bf16*)(A + 1114112);          // er1: 17*8192*8
  float* z1   = (float*)(A + 3290112);         // + a1b: 17*16000*8
  float* msg1 = (float*)(A + 5518336);         // + z1: 17*8192*16
  float* hid  = (float*)(A + 12071936);        // + msg1: 8192*200*4
  float* xln  = (float*)(A + 0);               // overlays er1/a1b/z1/msg1-head (dead by k_ln)
  float* x2   = (float*)(A + 6553600);
  float* x3   = (float*)(A + 13107200);
  float* x4   = (float*)(A + 19660800);
  bf16* cWsubT = (bf16*)x0;
  bf16* cWobjT = (bf16*)((char*)x0 + (size_t)NUME*300*2);

  // ---- tail region (after the largest phase overlay): CSR + F buffers ------
  size_t extent1 = (size_t)NET*N1*8 + (size_t)NET*E0*8 + (size_t)NET*N1*16;  // 24,480,000 (> phase-2 extent)
  size_t tail = (arena + extent1 + 255) & ~(size_t)255;
  size_t cntsz = (((size_t)(N1+1)*4) + 255) & ~(size_t)255;  // sized for max(N1,RNODES)+1
  unsigned* cnt  = (unsigned*)(base + tail);
  unsigned* offs = (unsigned*)(base + tail + cntsz);
  unsigned* cur  = (unsigned*)(base + tail + 2*cntsz);
  size_t ids_sz = (((size_t)NET*E0*4) + 255) & ~(size_t)255;
  int* ids = (int*)(base + tail + 3*cntsz);
  size_t F_off = tail + 3*cntsz + ids_sz;
  bf16* fbuf = (bf16*)(base + F_off);
  size_t fcap = (ws_size > F_off) ? (ws_size - F_off) : 0;
  size_t relF0 = (size_t)E0*200*2, relF1 = (size_t)E1*200*2;
  int nrelc0 = (int)((fcap / relF0 < (size_t)NET) ? (fcap / relF0) : (size_t)NET);
  int nrelc1 = (int)((fcap / relF1 < (size_t)NET) ? (fcap / relF1) : (size_t)NET);

  long cum[CVT_NREG+1]; cum[0]=0;
  for (int i=0;i<CVT_NREG;i++) cum[i+1] = cum[i] + CVT_N[i];
  auto NP = [&](int i)->const bf16*{ return normb + cum[i]; };
  const bf16 *nEmb=NP(0), *nTf=NP(1), *nTp=NP(2), *nWg0=NP(3), *nAl0=NP(4), *nAr0=NP(5), *nBg0=NP(6),
             *nWg1=NP(7), *nAl1=NP(8), *nAr1=NP(9), *nBg1=NP(10), *nLn0w=NP(11), *nLn0b=NP(12),
             *nWq=NP(13), *nBq=NP(14), *nWv=NP(15), *nBv=NP(16), *nLn1w=NP(17), *nLn1b=NP(18),
             *nWd1=NP(19), *nBd1=NP(20), *nSrel=NP(21), *nOrel=NP(22), *nBsub=NP(23), *nBobj=NP(24),
             *nCsrel=NP(25), *nCorel=NP(26), *nCbsub=NP(27), *nCbobj=NP(28);

  // ---- phase 0: dtype detect + normalize + prep ----
  k_detect<<<dim3(1),64,0,stream>>>((const unsigned*)d_in[13], flagp);
  CvtSrcs srcs;
  for (int i=0;i<CVT_NREG;i++) srcs.p[i] = d_in[CVT_DIN[i]];
  CvtMeta meta;
  { int c=0, bc=0;
    for (int i=0;i<CVT_NREG;i++){ meta.cum[i]=c; meta.bcum[i]=bc; c+=CVT_N[i]; bc += (CVT_N[i]+255)/256; }
    meta.cum[CVT_NREG]=c; meta.bcum[CVT_NREG]=bc;
    k_cvt<<<dim3((unsigned)bc),256,0,stream>>>(srcs, meta, normb, flagp);
  }
  k_fill_u32<<<GS((long)NET*N1*4),256,0,stream>>>((unsigned*)z0, 0u, (long)NET*N1*4);
  k_fill_out<<<GS((long)2*BQ*NUME),256,0,stream>>>(d_out, flagp);
  k_prep_w<<<GS(NET*DIN0*4),256,0,stream>>>(nWg0, nAl0, nAr0, wal0, war0, DIN0);
  k_prep_w<<<GS(NET*DIN1*4),256,0,stream>>>(nWg1, nAl1, nAr1, wal1, war1, DIN1);
  k_pack<<<GS((long)NET*4*13*512),256,0,stream>>>(nWg0, wpk0, DIN0, 4);
  k_pack<<<GS((long)NET*8*13*512),256,0,stream>>>(nWg1, wpk1, DIN1, 8);
  k_bgs<<<GS(2*DIM),256,0,stream>>>(nBg0, nBg1, bgs0, bgs1);
  k_build_x0<<<GS((long)N0*DIN0),256,0,stream>>>(nid0, ts_p, nEmb, nTf, nTp, x0);

  // ---- GAT layer 0 ----
  k_er<DIN0><<<GS((long)NET*N1),256,0,stream>>>(x0, war0, er0, N1);
  k_edge<DIN0><<<GS((long)NET*E0),256,0,stream>>>(x0, wal0, er0, src0, dst0, a0b, z0, E0, N1);
  if (nrelc0 >= 1){
    for (int r0=0; r0<NET; r0+=nrelc0){
      int nr = (NET - r0 < nrelc0) ? (NET - r0) : nrelc0;
      long nEd = (long)nr*E0;
      k_fill_u32<<<GS((long)N1+1),256,0,stream>>>(cnt, 0u, (long)N1+1);
      k_count<<<GS(nEd),256,0,stream>>>(dst0 + (size_t)r0*E0, nEd, cnt);
      k_scan<<<dim3(1),256,0,stream>>>(cnt, offs, cur, N1);
      k_fillcsr<<<GS(nEd),256,0,stream>>>(dst0 + (size_t)r0*E0, nEd, cur, ids);
      k_acc_mfma<DIN0,4><<<dim3((E0+63)/64, nr),256,0,stream>>>(x0, wpk0, a0b, z0, src0, dst0,
                                                                 msg0, fbuf, E0, N1, r0, 1);
      k_gather<<<dim3((N1+3)/4),256,0,stream>>>(fbuf, offs, ids, msg0, N1, r0>0 ? 1 : 0);
    }
  } else {
    k_fill_u32<<<GS((long)N1*DIM),256,0,stream>>>((unsigned*)msg0, 0u, (long)N1*DIM);
    k_acc_mfma<DIN0,4><<<dim3((E0+63)/64, NET),256,0,stream>>>(x0, wpk0, a0b, z0, src0, dst0,
                                                                msg0, (bf16*)nullptr, E0, N1, 0, 0);
  }

  // ---- build x1, GAT layer 1 ----
  k_build_x1<<<GS((long)N1*DIN1),256,0,stream>>>(nid0, ts_p, msg0, bgs0, nTf, nTp, x1);
  k_fill_u32<<<GS((long)NET*RNODES*4),256,0,stream>>>((unsigned*)z1, 0u, (long)NET*RNODES*4);
  k_er<DIN1><<<GS((long)NET*RNODES),256,0,stream>>>(x1, war1, er1, RNODES);
  k_edge<DIN1><<<GS((long)NET*E1),256,0,stream>>>(x1, wal1, er1, src1, dst1, a1b, z1, E1, RNODES);
  if (nrelc1 >= 1){
    for (int r0=0; r0<NET; r0+=nrelc1){
      int nr = (NET - r0 < nrelc1) ? (NET - r0) : nrelc1;
      long nEd = (long)nr*E1;
      k_fill_u32<<<GS((long)RNODES+1),256,0,stream>>>(cnt, 0u, (long)RNODES+1);
      k_count<<<GS(nEd),256,0,stream>>>(dst1 + (size_t)r0*E1, nEd, cnt);
      k_scan<<<dim3(1),256,0,stream>>>(cnt, offs, cur, RNODES);
      k_fillcsr<<<GS(nEd),256,0,stream>>>(dst1 + (size_t)r0*E1, nEd, cur, ids);
      k_acc_mfma<DIN1,8><<<dim3((E1+63)/64, nr),256,0,stream>>>(x1, wpk1, a1b, z1, src1, dst1,
                                                                 msg1, fbuf, E1, RNODES, r0, 1);
      k_gather<<<dim3((RNODES+3)/4),256,0,stream>>>(fbuf, offs, ids, msg1, RNODES, r0>0 ? 1 : 0);
    }
  } else {
    k_fill_u32<<<GS((long)RNODES*DIM),256,0,stream>>>((unsigned*)msg1, 0u, (long)RNODES*DIM);
    k_acc_mfma<DIN1,8><<<dim3((E1+63)/64, NET),256,0,stream>>>(x1, wpk1, a1b, z1, src1, dst1,
                                                                msg1, (bf16*)nullptr, E1, RNODES, 0, 0);
  }

  // ---- gather hid, copy-head scatter ----
  k_hid<<<GS((long)NROWS*HD),256,0,stream>>>(msg1, bgs1, root_idx, hid);
  k_transpose<<<dim3(625,10),256,0,stream>>>(cWsub, cWsubT, 300, NUME, flagp);
  k_transpose<<<dim3(625,10),256,0,stream>>>(cWobj, cWobjT, 300, NUME, flagp);
  k_scatter<<<dim3((KK+3)/4),256,0,stream>>>(copy_rows, copy_cols, rel, hid, nCsrel, nCorel,
                                             cWsubT, cWobjT, nCbsub, nCbobj, d_out, flagp);

  // ---- attention tail ----
  k_ln<<<dim3(NROWS),256,0,stream>>>(hid, nLn0w, nLn0b, xln);
  k_att<<<dim3(NROWS),256,0,stream>>>(xln, nWq, nBq, nWv, nBv, x2);
  k_ln<<<dim3(NROWS),256,0,stream>>>(x2, nLn1w, nLn1b, x3);
  k_d1<<<dim3(NROWS/8),256,0,stream>>>(x3, nWd1, nBd1, x4);

  // ---- final predictions ----
  k_pred<<<dim3(40,64),256,0,stream>>>(x4 + (size_t)BQ*DIM, nOrel, rel, Wsub, nBsub, d_out, 0, flagp);
  k_pred<<<dim3(40,64),256,0,stream>>>(x4,                  nSrel, rel, Wobj, nBobj, d_out, (size_t)BQ*NUME, flagp);
  (void)in_sizes; (void)n_in; (void)out_size; (void)ws_size;
}

// Round 2
// 2442.826 us; speedup vs baseline: 1.8043x; 1.1453x over previous
//
#include <hip/hip_runtime.h>
#include <hip/hip_bf16.h>
#include <math.h>

typedef __hip_bfloat16 bf16;
typedef __attribute__((ext_vector_type(8))) short short8;
typedef __attribute__((ext_vector_type(4))) float f32x4;

#define BQ 1024
#define NUME 20000
#define NET 17
#define DIMT 28
#define DIME 100
#define DIM 200
#define HEADS 4
#define OH 50
#define N0 160000
#define N1 40000
#define RNODES 8192
#define E0 60000
#define E1 16000
#define KK 500000
#define DIMR 100
#define HATT 4
#define OA 50
#define DIN0 128
#define DIN1 228
#define HD 800
#define NROWS 2048
#define PKS 10
#define PNT 1250

__device__ __forceinline__ float b2f(bf16 v){ return __bfloat162float(v); }
__device__ __forceinline__ bf16 f2b(float v){ return __float2bfloat16(v); }
__device__ __forceinline__ float bs2f(unsigned short u){ return __uint_as_float((unsigned)u << 16); }
__device__ __forceinline__ unsigned short f2bu(float v){ bf16 t = f2b(v); return *reinterpret_cast<unsigned short*>(&t); }

// ---- dtype normalization ----------------------------------------------------
static constexpr int CVT_NREG = 29;
static constexpr int CVT_N[CVT_NREG] = {
  2000000, 28, 28, 435200, 3400, 3400, 3400, 775200, 3400, 3400, 3400,
  800, 800, 40000, 200, 40000, 200, 800, 800, 160000, 200, 800, 800,
  20000, 20000, 800, 800, 20000, 20000
};
static constexpr int CVT_DIN[CVT_NREG] = {
  12,13,14,15,16,17,18,19,20,21,22,23,24,25,26,27,28,29,30,31,32,33,34,36,38,39,40,42,44
};
struct CvtSrcs { const void* p[CVT_NREG]; };
struct CvtMeta { int cum[CVT_NREG+1]; int bcum[CVT_NREG+1]; };

__global__ __launch_bounds__(64) void k_detect(const unsigned* tfw, unsigned* flag){
  if (threadIdx.x == 0) flag[0] = ((tfw[0] & 0xFFFFu) == 0u) ? 1u : 0u;
}

__global__ __launch_bounds__(256) void k_cvt(CvtSrcs srcs, CvtMeta meta, bf16* dst, const unsigned* flagp){
  int b = blockIdx.x;
  int r = 0;
  while (meta.bcum[r+1] <= b) r++;          // uniform per block (scalar loop)
  int i = (b - meta.bcum[r])*256 + threadIdx.x;
  int n = meta.cum[r+1] - meta.cum[r];
  if (i >= n) return;
  bool f32m = flagp[0] != 0u;
  bf16 v;
  if (f32m) v = f2b(((const float*)srcs.p[r])[i]);
  else      v = ((const bf16*)srcs.p[r])[i];
  dst[meta.cum[r] + i] = v;
}

__global__ __launch_bounds__(256) void k_fill_u32(unsigned* p, unsigned v, long n){
  long i = (long)blockIdx.x*256 + threadIdx.x;
  if (i < n) p[i] = v;
}

__global__ __launch_bounds__(256) void k_fill_out(void* outb, const unsigned* flagp){
  bool f32m = flagp[0] != 0u;
  long nwords = f32m ? (long)2*BQ*NUME : (long)BQ*NUME;
  long i = (long)blockIdx.x*256 + threadIdx.x;
  if (i >= nwords) return;
  unsigned* p = (unsigned*)((char*)outb + (size_t)2*BQ*NUME * (f32m ? 4 : 2));
  p[i] = f32m ? 0xC2C80000u : 0xC2C8C2C8u;
}

__global__ __launch_bounds__(256) void k_prep_w(const bf16* Wg, const bf16* al, const bf16* ar,
                                                float* wal, float* war, int DIN){
  int idx = blockIdx.x*256 + threadIdx.x;
  int total = NET*DIN*4;
  if (idx >= total) return;
  int h = idx & 3; int ri = idx >> 2; int i = ri % DIN; int r = ri / DIN;
  const bf16* wrow = Wg + ((size_t)(r*DIN + i))*HEADS*OH + h*OH;
  const bf16* alr = al + (size_t)(r*HEADS + h)*OH;
  const bf16* arr = ar + (size_t)(r*HEADS + h)*OH;
  float sl=0.f, sr=0.f;
  for (int o=0;o<OH;o++){ float w=b2f(wrow[o]); sl += w*b2f(alr[o]); sr += w*b2f(arr[o]); }
  wal[idx]=sl; war[idx]=sr;
}

// pack W into MFMA B-fragment order: wpk[((r*KS+ks)*13+nt)*512 + lane*8 + j]
__global__ __launch_bounds__(256) void k_pack(const bf16* Wg, bf16* wpk, int DIN, int KS){
  int idx = blockIdx.x*256 + threadIdx.x;
  int total = NET*KS*13*512;
  if (idx >= total) return;
  int j = idx & 7, lane = (idx>>3) & 63;
  int rem = idx >> 9;
  int nt = rem % 13, rks = rem / 13;
  int ks = rks % KS, r = rks / KS;
  int k = ks*32 + (lane>>4)*8 + j;
  int n = nt*16 + (lane&15);
  bf16 v = f2b(0.f);
  if (k < DIN && n < 200) v = Wg[((size_t)r*DIN + k)*200 + n];
  wpk[idx] = v;
}

// pack pred W (f32 or bf16 source) into fragment order: wpkP[page][ks][ntile][lane][8]
__global__ __launch_bounds__(256) void k_pack_pred(const void* Wsub, const void* Wobj, bf16* wpkP,
                                                    const unsigned* flagp){
  long idx = (long)blockIdx.x*256 + threadIdx.x;
  long total = (long)2*PKS*PNT*512;
  if (idx >= total) return;
  int j = (int)(idx & 7), lane = (int)((idx>>3) & 63);
  long rem = idx >> 9;
  int ntile = (int)(rem % PNT); rem /= PNT;
  int ks = (int)(rem % PKS); int page = (int)(rem / PKS);
  int k = ks*32 + (lane>>4)*8 + j;
  int n = ntile*16 + (lane&15);
  const void* W = page ? Wobj : Wsub;
  bool f32m = flagp[0] != 0u;
  float v = 0.f;
  if (k < 300) v = f32m ? ((const float*)W)[(size_t)k*NUME + n]
                        : b2f(((const bf16*)W)[(size_t)k*NUME + n]);
  wpkP[idx] = f2b(v);
}

// pred A: [page][1024][320] bf16 — page0: obj_emb||orel, page1: sub_emb||srel
__global__ __launch_bounds__(256) void k_prep_pred(const float* x4, const bf16* nSrel, const bf16* nOrel,
                                                    const int* rel, bf16* Apack){
  long idx = (long)blockIdx.x*256 + threadIdx.x;
  if (idx >= (long)2*1024*320) return;
  int j = (int)(idx % 320); long rem = idx/320;
  int row = (int)(rem % 1024); int page = (int)(rem / 1024);
  float v = 0.f;
  if (j < 200) v = x4[((size_t)(page==0 ? 1024+row : row))*DIM + j];
  else if (j < 300){
    const bf16* re = (page==0) ? nOrel : nSrel;
    v = b2f(re[(size_t)rel[row]*DIMR + (j-200)]);
  }
  Apack[idx] = f2b(v);
}

// MFMA pred GEMM: 2048x20000, K=320(pad). grid (79,16,2); block 64Mx256N.
__global__ __launch_bounds__(256) void k_pred_mfma(const bf16* __restrict__ Apack, const bf16* __restrict__ wpkP,
                                                   const bf16* bsub, const bf16* bobj, void* outb,
                                                   const unsigned* flagp){
  constexpr int SR = 320 + 8;
  __shared__ bf16 As[64*SR];
  int page = blockIdx.z;
  int rb = blockIdx.y*64;
  int cb = blockIdx.x*16;
  int t = threadIdx.x;
  const bf16* Ap = Apack + (size_t)page*1024*320;
  for (int c=t; c<64*80; c+=256){
    int m=c/80, j4=c%80;
    *(uint2*)(As + m*SR + j4*4) = *(const uint2*)(Ap + (size_t)(rb+m)*320 + j4*4);
  }
  __syncthreads();
  int lane = t&63, w = t>>6;
  int n_idx = lane&15, quad = lane>>4;
  const short8* wp8 = (const short8*)(wpkP + (size_t)page*PKS*PNT*512);
  f32x4 acc[4][4];
  #pragma unroll
  for (int i=0;i<4;i++)
    #pragma unroll
    for (int mt=0;mt<4;mt++) acc[i][mt] = (f32x4){0.f,0.f,0.f,0.f};
  short8 bz = {0,0,0,0,0,0,0,0};
  for (int ks=0; ks<PKS; ks++){
    short8 bfr[4];
    #pragma unroll
    for (int i=0;i<4;i++){
      int ntile = cb + w + 4*i;
      bfr[i] = (ntile < PNT) ? wp8[((size_t)ks*PNT + ntile)*64 + lane] : bz;
    }
    short8 afr[4];
    #pragma unroll
    for (int mt=0;mt<4;mt++) afr[mt] = *(const short8*)(As + (size_t)(mt*16 + n_idx)*SR + ks*32 + quad*8);
    #pragma unroll
    for (int i=0;i<4;i++)
      #pragma unroll
      for (int mt=0;mt<4;mt++)
        acc[i][mt] = __builtin_amdgcn_mfma_f32_16x16x32_bf16(afr[mt], bfr[i], acc[i][mt], 0, 0, 0);
  }
  bool f32m = flagp[0] != 0u;
  const bf16* bias = page ? bobj : bsub;
  size_t elem_off = (size_t)page*BQ*NUME;
  for (int i=0;i<4;i++){
    int ntile = cb + w + 4*i;
    if (ntile >= PNT) continue;
    int n = ntile*16 + n_idx;
    float bb = b2f(bias[n]);
    #pragma unroll
    for (int mt=0;mt<4;mt++){
      #pragma unroll
      for (int reg=0;reg<4;reg++){
        int m = rb + mt*16 + quad*4 + reg;
        size_t oi = elem_off + (size_t)m*NUME + n;
        float val = acc[i][mt][reg] + bb;
        if (f32m) ((float*)outb)[oi] = val; else ((bf16*)outb)[oi] = f2b(val);
      }
    }
  }
}

__global__ __launch_bounds__(256) void k_bgs(const bf16* bg0, const bf16* bg1, float* bgs0, float* bgs1){
  int j = blockIdx.x*256 + threadIdx.x;
  if (j < DIM){ float s=0.f; for(int r=0;r<NET;r++) s += b2f(bg0[r*DIM+j]); bgs0[j]=s; }
  else if (j < 2*DIM){ int jj=j-DIM; float s=0.f; for(int r=0;r<NET;r++) s += b2f(bg1[r*DIM+jj]); bgs1[jj]=s; }
}

__global__ __launch_bounds__(256) void k_build_x0(const int* nid0, const int* ts_p, const bf16* emb,
                                                  const bf16* tf, const bf16* tp, bf16* x0){
  long idx = (long)blockIdx.x*256 + threadIdx.x;
  if (idx >= (long)N0*DIN0) return;
  int n = idx / DIN0, j = idx % DIN0;
  int nid = nid0[n];
  bf16 v;
  if (j < DIME) v = emb[(size_t)(nid % NUME)*DIME + j];
  else {
    float t = (float)(ts_p[0] - nid / NUME);
    int jj = j - DIME;
    v = f2b(cosf(t * b2f(tf[jj]) + b2f(tp[jj])));
  }
  x0[idx] = v;
}

__global__ __launch_bounds__(256) void k_build_x1(const int* nid0, const int* ts_p, const float* msg0,
                                                  const float* bgs0, const bf16* tf, const bf16* tp, bf16* x1){
  long idx = (long)blockIdx.x*256 + threadIdx.x;
  if (idx >= (long)N1*DIN1) return;
  int n = idx / DIN1, j = idx % DIN1;
  bf16 v;
  if (j < DIM){
    v = f2b(fmaxf((msg0[(size_t)n*DIM + j] + bgs0[j]) * (1.0f/NET), 0.0f));
  } else {
    int nid = nid0[n];
    float t = (float)(ts_p[0] - nid / NUME);
    int jj = j - DIM;
    v = f2b(cosf(t * b2f(tf[jj]) + b2f(tp[jj])));
  }
  x1[idx] = v;
}

template<int DIN>
__global__ __launch_bounds__(256) void k_er(const bf16* __restrict__ x, const float* __restrict__ war,
                                            bf16* __restrict__ er, int nd){
  int idx = blockIdx.x*256 + threadIdx.x;
  if (idx >= NET*nd) return;
  int r = idx / nd, n = idx % nd;
  const ushort4* xr = (const ushort4*)(x + (size_t)n*DIN);
  const float4* w = (const float4*)(war + (size_t)r*DIN*4);
  float a0=0.f,a1=0.f,a2=0.f,a3=0.f;
  #pragma unroll 4
  for (int i=0;i<DIN/4;i++){
    ushort4 xv = xr[i];
    float x0=bs2f(xv.x), x1=bs2f(xv.y), x2=bs2f(xv.z), x3=bs2f(xv.w);
    float4 w0=w[4*i], w1=w[4*i+1], w2=w[4*i+2], w3=w[4*i+3];
    a0 += x0*w0.x + x1*w1.x + x2*w2.x + x3*w3.x;
    a1 += x0*w0.y + x1*w1.y + x2*w2.y + x3*w3.y;
    a2 += x0*w0.z + x1*w1.z + x2*w2.z + x3*w3.z;
    a3 += x0*w0.w + x1*w1.w + x2*w2.w + x3*w3.w;
  }
  bf16* e = er + (size_t)idx*4;
  e[0]=f2b(a0); e[1]=f2b(a1); e[2]=f2b(a2); e[3]=f2b(a3);
}

template<int DIN>
__global__ __launch_bounds__(256) void k_edge(const bf16* __restrict__ x, const float* __restrict__ wal,
                                              const bf16* __restrict__ er,
                                              const int* __restrict__ src, const int* __restrict__ dst,
                                              bf16* abuf, float* z, int nE, int nd){
  int idx = blockIdx.x*256 + threadIdx.x;
  if (idx >= NET*nE) return;
  int r = idx / nE;
  int s = src[idx], d = dst[idx];
  const ushort4* xr = (const ushort4*)(x + (size_t)s*DIN);
  const float4* w = (const float4*)(wal + (size_t)r*DIN*4);
  float a0=0.f,a1=0.f,a2=0.f,a3=0.f;
  #pragma unroll 4
  for (int i=0;i<DIN/4;i++){
    ushort4 xv = xr[i];
    float x0=bs2f(xv.x), x1=bs2f(xv.y), x2=bs2f(xv.z), x3=bs2f(xv.w);
    float4 w0=w[4*i], w1=w[4*i+1], w2=w[4*i+2], w3=w[4*i+3];
    a0 += x0*w0.x + x1*w1.x + x2*w2.x + x3*w3.x;
    a1 += x0*w0.y + x1*w1.y + x2*w2.y + x3*w3.y;
    a2 += x0*w0.z + x1*w1.z + x2*w2.z + x3*w3.z;
    a3 += x0*w0.w + x1*w1.w + x2*w2.w + x3*w3.w;
  }
  float acc[4] = {a0,a1,a2,a3};
  const bf16* ern = er + ((size_t)r*nd + d)*4;
  float* zp = z + ((size_t)r*nd + d)*4;
  bf16* ao = abuf + (size_t)idx*4;
  #pragma unroll
  for (int h=0;h<4;h++){
    float v = acc[h] + b2f(ern[h]);
    v = v>0.f ? v : 0.2f*v;
    float a = expf(fminf(v, 80.f));
    ao[h] = f2b(a);
    atomicAdd(&zp[h], a);
  }
}

// ---- CSR build over destination ids ----------------------------------------
__global__ __launch_bounds__(256) void k_count(const int* __restrict__ dst, long n, unsigned* cnt){
  long i = (long)blockIdx.x*256 + threadIdx.x;
  if (i >= n) return;
  atomicAdd(&cnt[dst[i]], 1u);
}

__global__ __launch_bounds__(256) void k_scan(const unsigned* __restrict__ cnt, unsigned* offs, unsigned* cur, int n){
  __shared__ unsigned part[256];
  __shared__ unsigned tot;
  int t = threadIdx.x;
  int chunk = (n + 255)/256;
  int lo = t*chunk, hi = lo+chunk; if (hi > n) hi = n; if (lo > n) lo = n;
  unsigned s = 0;
  for (int i=lo;i<hi;i++) s += cnt[i];
  part[t] = s;
  __syncthreads();
  if (t==0){
    unsigned r = 0;
    for (int i=0;i<256;i++){ unsigned v = part[i]; part[i] = r; r += v; }
    tot = r;
  }
  __syncthreads();
  unsigned run = part[t];
  for (int i=lo;i<hi;i++){ offs[i]=run; cur[i]=run; run += cnt[i]; }
  if (t==0) offs[n] = tot;
}

__global__ __launch_bounds__(256) void k_fillcsr(const int* __restrict__ dst, long n, unsigned* cur, int* ids){
  long i = (long)blockIdx.x*256 + threadIdx.x;
  if (i >= n) return;
  unsigned pos = atomicAdd(&cur[dst[i]], 1u);
  ids[pos] = (int)i;                    // i == (r-r0)*nE + e, the F row index
}

// ---- MFMA edge-GEMM ---------------------------------------------------------
// Swapped operands: D = W^T x^T so a lane's 4 regs are 4 consecutive n of ONE
// edge row -> 8B vector F stores. mode 0: atomic scatter (fallback).
template<int DIN, int KS>
__global__ __launch_bounds__(256) void k_acc_mfma(const bf16* __restrict__ x, const bf16* __restrict__ wpk,
                                                  const bf16* __restrict__ abuf, const float* __restrict__ z,
                                                  const int* __restrict__ src, const int* __restrict__ dst,
                                                  float* msg, bf16* fbuf, int nE, int nd, int r0, int mode){
  constexpr int KM = KS*32;
  constexpr int SR = KM + 8;          // LDS row stride (bf16): +8 breaks bank aliasing
  __shared__ bf16 xs[64*SR];
  __shared__ float alpha_s[64*4];
  __shared__ int sdst[64], ssrc[64];
  int r = r0 + blockIdx.y;
  int eb = blockIdx.x*64;
  int me = min(64, nE - eb);
  int t = threadIdx.x;
  if (t < 64){
    int v_src=0, v_dst=0;
    if (t < me){ v_src = src[(size_t)r*nE + eb + t]; v_dst = dst[(size_t)r*nE + eb + t]; }
    ssrc[t]=v_src; sdst[t]=v_dst;
  }
  __syncthreads();
  { // alpha per (edge, head)
    int m = t>>2, h = t&3;
    float al = 0.f;
    if (m < me){
      float a = b2f(abuf[((size_t)r*nE + eb + m)*4 + h]);
      float zz = z[((size_t)r*nd + sdst[m])*4 + h];
      al = a / fmaxf(zz, 1e-30f);
    }
    alpha_s[m*4+h] = al;
  }
  // stage x rows (zero-pad cols >= DIN and rows >= me)
  constexpr int CH = KM/4;           // 8-byte chunks per row
  for (int c = t; c < 64*CH; c += 256){
    int m = c / CH, j4 = c % CH;
    uint2 v = make_uint2(0u,0u);
    if (m < me && j4*4 < DIN) v = *(const uint2*)(x + (size_t)ssrc[m]*DIN + j4*4);
    *(uint2*)(xs + m*SR + j4*4) = v;
  }
  __syncthreads();

  int lane = t & 63, w = t >> 6;
  int n_idx = lane & 15, quad = lane >> 4;
  const short8* wpk8 = (const short8*)wpk;
  for (int mt=0; mt<4; mt++){
    short8 a[KS];
    const bf16* abase = xs + (size_t)(mt*16 + n_idx)*SR + quad*8;
    #pragma unroll
    for (int ks=0; ks<KS; ks++) a[ks] = *(const short8*)(abase + ks*32);
    int m = mt*16 + n_idx;              // lane&15 -> edge row (D column)
    for (int nt=w; nt<13; nt+=4){
      const short8* bp = wpk8 + (((size_t)r*KS)*13 + nt)*64 + lane;
      f32x4 acc = {0.f,0.f,0.f,0.f};
      #pragma unroll
      for (int ks=0; ks<KS; ks++){
        short8 b = bp[(size_t)ks*13*64];
        acc = __builtin_amdgcn_mfma_f32_16x16x32_bf16(b, a[ks], acc, 0, 0, 0);  // swapped: D = W^T x^T
      }
      int nbase = nt*16 + quad*4;       // quad*4+reg -> output col n
      if (nbase < 200 && m < me){
        if (mode == 0){
          #pragma unroll
          for (int reg=0; reg<4; reg++){
            int n = nbase + reg;
            int h = n / 50;
            atomicAdd(&msg[(size_t)sdst[m]*200 + n], acc[reg] * alpha_s[m*4+h]);
          }
        } else {
          ushort4 pk;
          { int n=nbase;   pk.x = f2bu(acc[0] * alpha_s[m*4 + n/50]); }
          { int n=nbase+1; pk.y = f2bu(acc[1] * alpha_s[m*4 + n/50]); }
          { int n=nbase+2; pk.z = f2bu(acc[2] * alpha_s[m*4 + n/50]); }
          { int n=nbase+3; pk.w = f2bu(acc[3] * alpha_s[m*4 + n/50]); }
          *(ushort4*)(fbuf + ((size_t)(r - r0)*nE + eb + m)*200 + nbase) = pk;
        }
      }
    }
  }
}

// ---- CSR gather: one wave per destination row, zero atomics ----------------
__global__ __launch_bounds__(256) void k_gather(const bf16* __restrict__ F, const unsigned* __restrict__ offs,
                                                const int* __restrict__ ids, float* __restrict__ msg,
                                                int nd, int accum){
  int w = threadIdx.x >> 6, lane = threadIdx.x & 63;
  int d = blockIdx.x*4 + w;
  if (d >= nd) return;
  unsigned k0 = offs[d], k1 = offs[d+1];
  float a0=0.f, a1=0.f, a2=0.f, a3=0.f;
  for (unsigned k=k0; k<k1; k++){
    int id = ids[k];
    if (lane < 50){
      ushort4 v = *(const ushort4*)(F + (size_t)id*200 + lane*4);
      a0 += bs2f(v.x); a1 += bs2f(v.y); a2 += bs2f(v.z); a3 += bs2f(v.w);
    }
  }
  if (lane < 50){
    float4* out = (float4*)(msg + (size_t)d*200 + lane*4);
    if (accum){ float4 p = *out; a0 += p.x; a1 += p.y; a2 += p.z; a3 += p.w; }
    float4 o; o.x=a0; o.y=a1; o.z=a2; o.w=a3;
    *out = o;
  }
}

__global__ __launch_bounds__(256) void k_hid(const float* msg1, const float* bgs1, const int* root_idx, float* hid){
  long idx = (long)blockIdx.x*256 + threadIdx.x;
  if (idx >= (long)NROWS*HD) return;
  int b = idx / HD, c = idx % HD;
  int s = c / DIM, j = c % DIM;
  int n = root_idx[b*4 + s];
  hid[idx] = fmaxf((msg1[(size_t)n*DIM + j] + bgs1[j]) * (1.0f/NET), 0.0f);
}

__global__ __launch_bounds__(256) void k_ln(const float* xin, const bf16* w, const bf16* b, float* xout){
  int row = blockIdx.x;
  const float* xr = xin + (size_t)row*HD;
  __shared__ float red[16];
  __shared__ float mu_s, rs_s;
  float s=0.f, s2=0.f;
  for (int j=threadIdx.x;j<HD;j+=256){ float v=xr[j]; s+=v; s2+=v*v; }
  for (int off=32; off; off>>=1){ s += __shfl_down(s,off); s2 += __shfl_down(s2,off); }
  int lane = threadIdx.x & 63, wid = threadIdx.x >> 6;
  if (lane==0){ red[wid]=s; red[8+wid]=s2; }
  __syncthreads();
  if (threadIdx.x==0){
    float S = red[0]+red[1]+red[2]+red[3];
    float S2 = red[8]+red[9]+red[10]+red[11];
    float mu = S * (1.0f/HD);
    float var = fmaxf(S2 * (1.0f/HD) - mu*mu, 0.f);
    mu_s = mu; rs_s = rsqrtf(var + 1e-5f);
  }
  __syncthreads();
  float mu = mu_s, rs = rs_s;
  for (int j=threadIdx.x;j<HD;j+=256){
    float v = (xr[j]-mu)*rs;
    xout[(size_t)row*HD + j] = v*b2f(w[j]) + b2f(b[j]);
  }
}

__global__ __launch_bounds__(256) void k_att(const float* xln, const bf16* Wq, const bf16* bq,
                                             const bf16* Wv, const bf16* bv, float* x2){
  __shared__ float xs[HD], qs[HD], vs[HD], att_s[64];
  int b = blockIdx.x, t = threadIdx.x;
  for (int j=t;j<HD;j+=256) xs[j] = xln[(size_t)b*HD + j];
  __syncthreads();
  for (int idx=t; idx<HD; idx+=256){
    int ha = idx/200, srow=(idx%200)/50, o=idx%50;
    const float* xr = xs + srow*200;
    const bf16* wq = Wq + (size_t)ha*DIM*OA + o;
    const bf16* wv = Wv + (size_t)ha*DIM*OA + o;
    float q=0.f, v=0.f;
    for (int e=0;e<DIM;e++){ float xv=xr[e]; q += xv*b2f(wq[(size_t)e*OA]); v += xv*b2f(wv[(size_t)e*OA]); }
    qs[idx] = q + b2f(bq[ha*OA+o]);
    vs[idx] = v + b2f(bv[ha*OA+o]);
  }
  __syncthreads();
  if (t < 64){
    int ha=t>>4, srow=(t>>2)&3, tt=t&3;
    const float* qa = qs + ha*200 + srow*50;
    const float* qb = qs + ha*200 + tt*50;
    float sc=0.f;
    for (int o=0;o<50;o++) sc += qa[o]*qb[o];
    att_s[ha*16 + srow*4 + tt] = sc;
  }
  __syncthreads();
  if (t < 16){
    int ha=t>>2, tt=t&3;
    float m=-1e30f;
    for (int srow=0;srow<4;srow++) m = fmaxf(m, att_s[ha*16+srow*4+tt]);
    float ex[4]; float zz=0.f;
    for (int srow=0;srow<4;srow++){ ex[srow]=expf(att_s[ha*16+srow*4+tt]-m); zz+=ex[srow]; }
    for (int srow=0;srow<4;srow++) att_s[ha*16+srow*4+tt] = ex[srow]/zz;
  }
  __syncthreads();
  for (int idx=t; idx<HD; idx+=256){
    int ha = idx/200, srow=(idx%200)/50, o=idx%50;
    float a=0.f;
    for (int tt=0;tt<4;tt++) a += att_s[ha*16+srow*4+tt]*vs[ha*200+tt*50+o];
    x2[(size_t)b*HD + srow*200 + ha*50 + o] = fmaxf(a, 0.f);
  }
}

__global__ __launch_bounds__(256) void k_d1(const float* x3, const bf16* Wd1, const bf16* bd1, float* x4){
  __shared__ float xs[8*HD];
  int rb = blockIdx.x*8, t = threadIdx.x;
  for (int idx=t; idx<8*HD; idx+=256) xs[idx] = x3[(size_t)rb*HD + idx];
  __syncthreads();
  if (t < DIM){
    float acc[8] = {0,0,0,0,0,0,0,0};
    for (int k=0;k<HD;k++){
      float w = b2f(Wd1[(size_t)k*DIM + t]);
      #pragma unroll
      for (int r=0;r<8;r++) acc[r] += xs[r*HD+k]*w;
    }
    float bb = b2f(bd1[t]);
    for (int r=0;r<8;r++) x4[(size_t)(rb+r)*DIM + t] = fmaxf(acc[r]+bb, 0.f);
  }
}

// scalar fallback pred (used only if workspace too small for MFMA path)
__global__ __launch_bounds__(256) void k_pred(const float* xemb, const bf16* relemb, const int* rel,
                                              const void* W, const bf16* bias, void* outb, size_t elem_off,
                                              const unsigned* flagp){
  __shared__ float As[16*304];
  bool f32m = flagp[0] != 0u;
  int rb = blockIdx.y*16;
  int cb = blockIdx.x*512;
  int t = threadIdx.x;
  for (int idx=t; idx<16*300; idx+=256){
    int r = idx/300, i = idx%300;
    int row = rb + r;
    float v = (i < DIM) ? xemb[(size_t)row*DIM + i]
                        : b2f(relemb[(size_t)rel[row]*DIMR + (i-DIM)]);
    As[r*304+i] = v;
  }
  __syncthreads();
  int c0 = cb + t, c1 = cb + 256 + t;
  bool g0 = c0 < NUME, g1 = c1 < NUME;
  float acc0[16], acc1[16];
  #pragma unroll
  for (int r=0;r<16;r++){ acc0[r]=0.f; acc1[r]=0.f; }
  if (f32m){
    const float* W32 = (const float*)W;
    for (int k=0;k<300;k++){
      float w0 = g0 ? W32[(size_t)k*NUME + c0] : 0.f;
      float w1 = g1 ? W32[(size_t)k*NUME + c1] : 0.f;
      #pragma unroll
      for (int r=0;r<16;r++){ float a = As[r*304+k]; acc0[r] += a*w0; acc1[r] += a*w1; }
    }
  } else {
    const bf16* W16 = (const bf16*)W;
    for (int k=0;k<300;k++){
      float w0 = g0 ? b2f(W16[(size_t)k*NUME + c0]) : 0.f;
      float w1 = g1 ? b2f(W16[(size_t)k*NUME + c1]) : 0.f;
      #pragma unroll
      for (int r=0;r<16;r++){ float a = As[r*304+k]; acc0[r] += a*w0; acc1[r] += a*w1; }
    }
  }
  #pragma unroll
  for (int rr=0; rr<2; rr++){
    int c = rr ? c1 : c0;
    float* acc = rr ? acc1 : acc0;
    if (c < NUME){
      float bb = b2f(bias[c]);
      for (int r=0;r<16;r++){
        size_t oi = elem_off + (size_t)(rb+r)*NUME + c;
        float val = acc[r] + bb;
        if (f32m) ((float*)outb)[oi] = val; else ((bf16*)outb)[oi] = f2b(val);
      }
    }
  }
}

__global__ __launch_bounds__(256) void k_transpose(const void* in, bf16* out, int rows, int cols,
                                                   const unsigned* flagp){
  __shared__ bf16 tile[32][33];
  bool f32m = flagp[0] != 0u;
  int c0 = blockIdx.x*32, r0 = blockIdx.y*32;
  int tx = threadIdx.x % 32, ty = threadIdx.x / 32;
  for (int rr=ty; rr<32; rr+=8){
    int r = r0+rr, c = c0+tx;
    if (r<rows && c<cols){
      size_t i = (size_t)r*cols + c;
      tile[rr][tx] = f32m ? f2b(((const float*)in)[i]) : ((const bf16*)in)[i];
    }
  }
  __syncthreads();
  for (int rr=ty; rr<32; rr+=8){
    int ocol = c0+rr, orow = r0+tx;
    if (ocol<cols && orow<rows) out[(size_t)ocol*rows + orow] = tile[tx][rr];
  }
}

__global__ __launch_bounds__(256) void k_scatter(const int* copy_rows, const int* copy_cols, const int* rel,
                                                 const float* hid, const bf16* csrel, const bf16* corel,
                                                 const bf16* cWsubT, const bf16* cWobjT,
                                                 const bf16* cbsub, const bf16* cbobj,
                                                 void* outb, const unsigned* flagp){
  bool f32m = flagp[0] != 0u;
  int wid = threadIdx.x >> 6, lane = threadIdx.x & 63;
  long k = (long)blockIdx.x*4 + wid;
  if (k >= KK) return;
  int row = copy_rows[k], col = copy_cols[k];
  const float* chrow; const bf16* re; const bf16* wt; float bias_v;
  if (row < BQ){
    chrow = hid + ((size_t)(BQ+row))*HD + 600;
    re = corel + (size_t)rel[row]*DIMR;
    wt = cWsubT + (size_t)col*300;
    bias_v = b2f(cbsub[col]);
  } else {
    int rr = row - BQ;
    chrow = hid + ((size_t)rr)*HD + 600;
    re = csrel + (size_t)rel[rr]*DIMR;
    wt = cWobjT + (size_t)col*300;
    bias_v = b2f(cbobj[col]);
  }
  float s = 0.f;
  for (int i=lane; i<300; i+=64){
    float a = (i < DIM) ? chrow[i] : b2f(re[i-DIM]);
    s += a * b2f(wt[i]);
  }
  for (int off=32; off; off>>=1) s += __shfl_down(s, off);
  if (lane==0){
    size_t oi = (size_t)2*BQ*NUME + (size_t)row*NUME + col;
    float val = s + bias_v;
    if (f32m) ((float*)outb)[oi] = val; else ((bf16*)outb)[oi] = f2b(val);
  }
}

static inline dim3 GS(long n){ return dim3((unsigned)((n + 255)/256)); }

extern "C" void kernel_launch(void* const* d_in, const int* in_sizes, int n_in,
                              void* d_out, int out_size, void* d_ws, size_t ws_size,
                              hipStream_t stream){
  const int* rel       = (const int*)d_in[2];
  const int* ts_p      = (const int*)d_in[3];
  const int* nid0      = (const int*)d_in[4];
  const int* root_idx  = (const int*)d_in[5];
  const int* src0      = (const int*)d_in[6];
  const int* dst0      = (const int*)d_in[7];
  const int* src1      = (const int*)d_in[8];
  const int* dst1      = (const int*)d_in[9];
  const int* copy_rows = (const int*)d_in[10];
  const int* copy_cols = (const int*)d_in[11];
  const void* Wsub  = d_in[35];
  const void* Wobj  = d_in[37];
  const void* cWsub = d_in[41];
  const void* cWobj = d_in[43];

  // ---- workspace layout ----
  char* base = (char*)d_ws;
  size_t off = 0;
  auto alloc = [&](size_t bytes)->char*{
    char* p = base + off; off = (off + bytes + 255) & ~(size_t)255; return p;
  };
  unsigned* flagp = (unsigned*)alloc(256);
  long cvt_total = 0; for (int i=0;i<CVT_NREG;i++) cvt_total += CVT_N[i];
  bf16* normb = (bf16*)alloc((size_t)cvt_total*2);
  bf16* x0    = (bf16*)alloc((size_t)N0*DIN0*2);       // 40.96 MB (reused for cW*T later)
  bf16* x1    = (bf16*)alloc((size_t)N1*DIN1*2);       // 18.24 MB
  float* msg0 = (float*)alloc((size_t)N1*DIM*4);       // 32 MB
  float* wal0 = (float*)alloc((size_t)NET*DIN0*4*4);
  float* war0 = (float*)alloc((size_t)NET*DIN0*4*4);
  float* wal1 = (float*)alloc((size_t)NET*DIN1*4*4);
  float* war1 = (float*)alloc((size_t)NET*DIN1*4*4);
  float* bgs0 = (float*)alloc(DIM*4);
  float* bgs1 = (float*)alloc(DIM*4);
  bf16* wpk0  = (bf16*)alloc((size_t)NET*4*13*512*2);  // 0.91 MB
  bf16* wpk1  = (bf16*)alloc((size_t)NET*8*13*512*2);  // 1.81 MB
  size_t arena = off;
  // phase-1 (GAT layer 0): er0/a0 bf16, z0 f32
  bf16*  er0 = (bf16*)(base + arena);
  bf16*  a0b = (bf16*)((char*)er0 + (size_t)NET*N1*8);
  float* z0  = (float*)((char*)a0b + (size_t)NET*E0*8);
  // phase-2 (layer 1 + tail) — overlays phase-1
  char* A = base + arena;
  bf16*  er1  = (bf16*)A;
  bf16*  a1b  = (bf16*)(A + 1114112);          // er1: 17*8192*8
  float* z1   = (float*)(A + 3290112);         // + a1b: 17*16000*8
  float* msg1 = (float*)(A + 5518336);         // + z1: 17*8192*16
  float* hid  = (float*)(A + 12071936);        // + msg1: 8192*200*4
  float* xln  = (float*)(A + 0);               // overlays er1/a1b/z1/msg1-head (dead by k_ln)
  float* x2   = (float*)(A + 6553600);
  float* x3   = (float*)(A + 13107200);
  float* x4   = (float*)(A + 19660800);
  bf16* cWsubT = (bf16*)x0;
  bf16* cWobjT = (bf16*)((char*)x0 + (size_t)NUME*300*2);

  // ---- tail region (after the largest phase overlay): CSR + F buffers ------
  size_t extent1 = (size_t)NET*N1*8 + (size_t)NET*E0*8 + (size_t)NET*N1*16;  // 24,480,000 (> phase-2 extent)
  size_t tail = (arena + extent1 + 255) & ~(size_t)255;
  size_t cntsz = (((size_t)(N1+1)*4) + 255) & ~(size_t)255;  // sized for max(N1,RNODES)+1
  unsigned* cnt  = (unsigned*)(base + tail);
  unsigned* offs = (unsigned*)(base + tail + cntsz);
  unsigned* cur  = (unsigned*)(base + tail + 2*cntsz);
  size_t ids_sz = (((size_t)NET*E0*4) + 255) & ~(size_t)255;
  int* ids = (int*)(base + tail + 3*cntsz);
  size_t F_off = tail + 3*cntsz + ids_sz;
  bf16* fbuf = (bf16*)(base + F_off);
  size_t fcap = (ws_size > F_off) ? (ws_size - F_off) : 0;
  size_t relF0 = (size_t)E0*200*2, relF1 = (size_t)E1*200*2;
  int nrelc0 = (int)((fcap / relF0 < (size_t)NET) ? (fcap / relF0) : (size_t)NET);
  int nrelc1 = (int)((fcap / relF1 < (size_t)NET) ? (fcap / relF1) : (size_t)NET);
  // pred MFMA buffers alias fbuf (dead after last gather)
  size_t wpkP_sz = (size_t)2*PKS*PNT*512*2;            // 25.6 MB
  size_t Apack_sz = (size_t)2*1024*320*2;              // 1.31 MB
  bf16* wpkP  = (bf16*)(base + F_off);
  bf16* Apack = (bf16*)(base + F_off + wpkP_sz);
  bool predok = fcap >= (wpkP_sz + Apack_sz);

  long cum[CVT_NREG+1]; cum[0]=0;
  for (int i=0;i<CVT_NREG;i++) cum[i+1] = cum[i] + CVT_N[i];
  auto NP = [&](int i)->const bf16*{ return normb + cum[i]; };
  const bf16 *nEmb=NP(0), *nTf=NP(1), *nTp=NP(2), *nWg0=NP(3), *nAl0=NP(4), *nAr0=NP(5), *nBg0=NP(6),
             *nWg1=NP(7), *nAl1=NP(8), *nAr1=NP(9), *nBg1=NP(10), *nLn0w=NP(11), *nLn0b=NP(12),
             *nWq=NP(13), *nBq=NP(14), *nWv=NP(15), *nBv=NP(16), *nLn1w=NP(17), *nLn1b=NP(18),
             *nWd1=NP(19), *nBd1=NP(20), *nSrel=NP(21), *nOrel=NP(22), *nBsub=NP(23), *nBobj=NP(24),
             *nCsrel=NP(25), *nCorel=NP(26), *nCbsub=NP(27), *nCbobj=NP(28);

  // ---- phase 0: dtype detect + normalize + prep ----
  k_detect<<<dim3(1),64,0,stream>>>((const unsigned*)d_in[13], flagp);
  CvtSrcs srcs;
  for (int i=0;i<CVT_NREG;i++) srcs.p[i] = d_in[CVT_DIN[i]];
  CvtMeta meta;
  { int c=0, bc=0;
    for (int i=0;i<CVT_NREG;i++){ meta.cum[i]=c; meta.bcum[i]=bc; c+=CVT_N[i]; bc += (CVT_N[i]+255)/256; }
    meta.cum[CVT_NREG]=c; meta.bcum[CVT_NREG]=bc;
    k_cvt<<<dim3((unsigned)bc),256,0,stream>>>(srcs, meta, normb, flagp);
  }
  k_fill_u32<<<GS((long)NET*N1*4),256,0,stream>>>((unsigned*)z0, 0u, (long)NET*N1*4);
  k_fill_out<<<GS((long)2*BQ*NUME),256,0,stream>>>(d_out, flagp);
  k_prep_w<<<GS(NET*DIN0*4),256,0,stream>>>(nWg0, nAl0, nAr0, wal0, war0, DIN0);
  k_prep_w<<<GS(NET*DIN1*4),256,0,stream>>>(nWg1, nAl1, nAr1, wal1, war1, DIN1);
  k_pack<<<GS((long)NET*4*13*512),256,0,stream>>>(nWg0, wpk0, DIN0, 4);
  k_pack<<<GS((long)NET*8*13*512),256,0,stream>>>(nWg1, wpk1, DIN1, 8);
  k_bgs<<<GS(2*DIM),256,0,stream>>>(nBg0, nBg1, bgs0, bgs1);
  k_build_x0<<<GS((long)N0*DIN0),256,0,stream>>>(nid0, ts_p, nEmb, nTf, nTp, x0);

  // ---- GAT layer 0 ----
  k_er<DIN0><<<GS((long)NET*N1),256,0,stream>>>(x0, war0, er0, N1);
  k_edge<DIN0><<<GS((long)NET*E0),256,0,stream>>>(x0, wal0, er0, src0, dst0, a0b, z0, E0, N1);
  if (nrelc0 >= 1){
    for (int r0=0; r0<NET; r0+=nrelc0){
      int nr = (NET - r0 < nrelc0) ? (NET - r0) : nrelc0;
      long nEd = (long)nr*E0;
      k_fill_u32<<<GS((long)N1+1),256,0,stream>>>(cnt, 0u, (long)N1+1);
      k_count<<<GS(nEd),256,0,stream>>>(dst0 + (size_t)r0*E0, nEd, cnt);
      k_scan<<<dim3(1),256,0,stream>>>(cnt, offs, cur, N1);
      k_fillcsr<<<GS(nEd),256,0,stream>>>(dst0 + (size_t)r0*E0, nEd, cur, ids);
      k_acc_mfma<DIN0,4><<<dim3((E0+63)/64, nr),256,0,stream>>>(x0, wpk0, a0b, z0, src0, dst0,
                                                                 msg0, fbuf, E0, N1, r0, 1);
      k_gather<<<dim3((N1+3)/4),256,0,stream>>>(fbuf, offs, ids, msg0, N1, r0>0 ? 1 : 0);
    }
  } else {
    k_fill_u32<<<GS((long)N1*DIM),256,0,stream>>>((unsigned*)msg0, 0u, (long)N1*DIM);
    k_acc_mfma<DIN0,4><<<dim3((E0+63)/64, NET),256,0,stream>>>(x0, wpk0, a0b, z0, src0, dst0,
                                                                msg0, (bf16*)nullptr, E0, N1, 0, 0);
  }

  // ---- build x1, GAT layer 1 ----
  k_build_x1<<<GS((long)N1*DIN1),256,0,stream>>>(nid0, ts_p, msg0, bgs0, nTf, nTp, x1);
  k_fill_u32<<<GS((long)NET*RNODES*4),256,0,stream>>>((unsigned*)z1, 0u, (long)NET*RNODES*4);
  k_er<DIN1><<<GS((long)NET*RNODES),256,0,stream>>>(x1, war1, er1, RNODES);
  k_edge<DIN1><<<GS((long)NET*E1),256,0,stream>>>(x1, wal1, er1, src1, dst1, a1b, z1, E1, RNODES);
  if (nrelc1 >= 1){
    for (int r0=0; r0<NET; r0+=nrelc1){
      int nr = (NET - r0 < nrelc1) ? (NET - r0) : nrelc1;
      long nEd = (long)nr*E1;
      k_fill_u32<<<GS((long)RNODES+1),256,0,stream>>>(cnt, 0u, (long)RNODES+1);
      k_count<<<GS(nEd),256,0,stream>>>(dst1 + (size_t)r0*E1, nEd, cnt);
      k_scan<<<dim3(1),256,0,stream>>>(cnt, offs, cur, RNODES);
      k_fillcsr<<<GS(nEd),256,0,stream>>>(dst1 + (size_t)r0*E1, nEd, cur, ids);
      k_acc_mfma<DIN1,8><<<dim3((E1+63)/64, nr),256,0,stream>>>(x1, wpk1, a1b, z1, src1, dst1,
                                                                 msg1, fbuf, E1, RNODES, r0, 1);
      k_gather<<<dim3((RNODES+3)/4),256,0,stream>>>(fbuf, offs, ids, msg1, RNODES, r0>0 ? 1 : 0);
    }
  } else {
    k_fill_u32<<<GS((long)RNODES*DIM),256,0,stream>>>((unsigned*)msg1, 0u, (long)RNODES*DIM);
    k_acc_mfma<DIN1,8><<<dim3((E1+63)/64, NET),256,0,stream>>>(x1, wpk1, a1b, z1, src1, dst1,
                                                                msg1, (bf16*)nullptr, E1, RNODES, 0, 0);
  }

  // ---- pred W pack (aliases fbuf — fbuf dead after last gather) ----
  if (predok)
    k_pack_pred<<<GS((long)2*PKS*PNT*512),256,0,stream>>>(Wsub, Wobj, wpkP, flagp);

  // ---- gather hid, copy-head scatter ----
  k_hid<<<GS((long)NROWS*HD),256,0,stream>>>(msg1, bgs1, root_idx, hid);
  k_transpose<<<dim3(625,10),256,0,stream>>>(cWsub, cWsubT, 300, NUME, flagp);
  k_transpose<<<dim3(625,10),256,0,stream>>>(cWobj, cWobjT, 300, NUME, flagp);
  k_scatter<<<dim3((KK+3)/4),256,0,stream>>>(copy_rows, copy_cols, rel, hid, nCsrel, nCorel,
                                             cWsubT, cWobjT, nCbsub, nCbobj, d_out, flagp);

  // ---- attention tail ----
  k_ln<<<dim3(NROWS),256,0,stream>>>(hid, nLn0w, nLn0b, xln);
  k_att<<<dim3(NROWS),256,0,stream>>>(xln, nWq, nBq, nWv, nBv, x2);
  k_ln<<<dim3(NROWS),256,0,stream>>>(x2, nLn1w, nLn1b, x3);
  k_d1<<<dim3(NROWS/8),256,0,stream>>>(x3, nWd1, nBd1, x4);

  // ---- final predictions ----
  if (predok){
    k_prep_pred<<<GS((long)2*1024*320),256,0,stream>>>(x4, nSrel, nOrel, rel, Apack);
    k_pred_mfma<<<dim3(79,16,2),256,0,stream>>>(Apack, wpkP, nBsub, nBobj, d_out, flagp);
  } else {
    k_pred<<<dim3(40,64),256,0,stream>>>(x4 + (size_t)BQ*DIM, nOrel, rel, Wsub, nBsub, d_out, 0, flagp);
    k_pred<<<dim3(40,64),256,0,stream>>>(x4,                  nSrel, rel, Wobj, nBobj, d_out, (size_t)BQ*NUME, flagp);
  }
  (void)in_sizes; (void)n_in; (void)out_size; (void)ws_size;
}

// Round 3
// 2304.933 us; speedup vs baseline: 1.9122x; 1.0598x over previous
//
#include <hip/hip_runtime.h>
#include <hip/hip_bf16.h>
#include <math.h>

typedef __hip_bfloat16 bf16;
typedef __attribute__((ext_vector_type(8))) short short8;
typedef __attribute__((ext_vector_type(4))) float f32x4;

#define BQ 1024
#define NUME 20000
#define NET 17
#define DIMT 28
#define DIME 100
#define DIM 200
#define HEADS 4
#define OH 50
#define N0 160000
#define N1 40000
#define RNODES 8192
#define E0 60000
#define E1 16000
#define KK 500000
#define DIMR 100
#define HATT 4
#define OA 50
#define DIN0 128
#define DIN1 228
#define HD 800
#define NROWS 2048
#define PKS 10
#define PNT 1250
#define TABW 136   // 17 relations * (4 wal + 4 war)

__device__ __forceinline__ float b2f(bf16 v){ return __bfloat162float(v); }
__device__ __forceinline__ bf16 f2b(float v){ return __float2bfloat16(v); }
__device__ __forceinline__ float bs2f(unsigned short u){ return __uint_as_float((unsigned)u << 16); }
__device__ __forceinline__ unsigned short f2bu(float v){ bf16 t = f2b(v); return *reinterpret_cast<unsigned short*>(&t); }

// ---- dtype normalization ----------------------------------------------------
static constexpr int CVT_NREG = 29;
static constexpr int CVT_N[CVT_NREG] = {
  2000000, 28, 28, 435200, 3400, 3400, 3400, 775200, 3400, 3400, 3400,
  800, 800, 40000, 200, 40000, 200, 800, 800, 160000, 200, 800, 800,
  20000, 20000, 800, 800, 20000, 20000
};
static constexpr int CVT_DIN[CVT_NREG] = {
  12,13,14,15,16,17,18,19,20,21,22,23,24,25,26,27,28,29,30,31,32,33,34,36,38,39,40,42,44
};
struct CvtSrcs { const void* p[CVT_NREG]; };
struct CvtMeta { int cum[CVT_NREG+1]; int bcum[CVT_NREG+1]; };

__global__ __launch_bounds__(64) void k_detect(const unsigned* tfw, unsigned* flag){
  if (threadIdx.x == 0) flag[0] = ((tfw[0] & 0xFFFFu) == 0u) ? 1u : 0u;
}

__global__ __launch_bounds__(256) void k_cvt(CvtSrcs srcs, CvtMeta meta, bf16* dst, const unsigned* flagp){
  int b = blockIdx.x;
  int r = 0;
  while (meta.bcum[r+1] <= b) r++;
  int i = (b - meta.bcum[r])*256 + threadIdx.x;
  int n = meta.cum[r+1] - meta.cum[r];
  if (i >= n) return;
  bool f32m = flagp[0] != 0u;
  bf16 v;
  if (f32m) v = f2b(((const float*)srcs.p[r])[i]);
  else      v = ((const bf16*)srcs.p[r])[i];
  dst[meta.cum[r] + i] = v;
}

__global__ __launch_bounds__(256) void k_fill_u32(unsigned* p, unsigned v, long n){
  long i = (long)blockIdx.x*256 + threadIdx.x;
  if (i < n) p[i] = v;
}

__global__ __launch_bounds__(256) void k_fill_out(void* outb, const unsigned* flagp){
  bool f32m = flagp[0] != 0u;
  long nwords = f32m ? (long)2*BQ*NUME : (long)BQ*NUME;
  long i = (long)blockIdx.x*256 + threadIdx.x;
  if (i >= nwords) return;
  unsigned* p = (unsigned*)((char*)outb + (size_t)2*BQ*NUME * (f32m ? 4 : 2));
  p[i] = f32m ? 0xC2C80000u : 0xC2C8C2C8u;
}

__global__ __launch_bounds__(256) void k_prep_w(const bf16* Wg, const bf16* al, const bf16* ar,
                                                float* wal, float* war, int DIN){
  int idx = blockIdx.x*256 + threadIdx.x;
  int total = NET*DIN*4;
  if (idx >= total) return;
  int h = idx & 3; int ri = idx >> 2; int i = ri % DIN; int r = ri / DIN;
  const bf16* wrow = Wg + ((size_t)(r*DIN + i))*HEADS*OH + h*OH;
  const bf16* alr = al + (size_t)(r*HEADS + h)*OH;
  const bf16* arr = ar + (size_t)(r*HEADS + h)*OH;
  float sl=0.f, sr=0.f;
  for (int o=0;o<OH;o++){ float w=b2f(wrow[o]); sl += w*b2f(alr[o]); sr += w*b2f(arr[o]); }
  wal[idx]=sl; war[idx]=sr;
}

// pack W into MFMA B-fragment order: wpk[((r*KS+ks)*13+nt)*512 + lane*8 + j]
__global__ __launch_bounds__(256) void k_pack(const bf16* Wg, bf16* wpk, int DIN, int KS){
  int idx = blockIdx.x*256 + threadIdx.x;
  int total = NET*KS*13*512;
  if (idx >= total) return;
  int j = idx & 7, lane = (idx>>3) & 63;
  int rem = idx >> 9;
  int nt = rem % 13, rks = rem / 13;
  int ks = rks % KS, r = rks / KS;
  int k = ks*32 + (lane>>4)*8 + j;
  int n = nt*16 + (lane&15);
  bf16 v = f2b(0.f);
  if (k < DIN && n < 200) v = Wg[((size_t)r*DIN + k)*200 + n];
  wpk[idx] = v;
}

// pack [wal|war] (f32, layout ((r*DIN+i)*4+h)) into fragment order [ks][nt(9)][lane][8]
__global__ __launch_bounds__(256) void k_pack_walr(const float* wal, const float* war, bf16* wpkE,
                                                   int DIN, int KS){
  int idx = blockIdx.x*256 + threadIdx.x;
  int total = KS*9*512;
  if (idx >= total) return;
  int j = idx & 7, lane = (idx>>3) & 63;
  int rem = idx >> 9;
  int nt = rem % 9, ks = rem / 9;
  int k = ks*32 + (lane>>4)*8 + j;
  int c = nt*16 + (lane&15);
  float v = 0.f;
  if (k < DIN && c < TABW){
    int r = c >> 3, q = c & 7;
    const float* wsrc = (q < 4) ? wal : war;
    v = wsrc[((size_t)r*DIN + k)*4 + (q & 3)];
  }
  wpkE[idx] = f2b(v);
}

// node-relation table GEMM: tab[m][c] = x[m] . walr[:,c]  (M x TABW, f32 out)
template<int DIN, int KS>
__global__ __launch_bounds__(256) void k_elr(const bf16* __restrict__ x, const bf16* __restrict__ wpkE,
                                             float* __restrict__ tab){
  constexpr int KM = KS*32;
  constexpr int SR = KM + 8;
  __shared__ bf16 xs[64*SR];
  int rb = blockIdx.x*64;
  int t = threadIdx.x;
  constexpr int CH = KM/4;
  for (int c = t; c < 64*CH; c += 256){
    int m = c / CH, j4 = c % CH;
    uint2 v = make_uint2(0u,0u);
    if (j4*4 < DIN) v = *(const uint2*)(x + (size_t)(rb+m)*DIN + j4*4);
    *(uint2*)(xs + m*SR + j4*4) = v;
  }
  __syncthreads();
  int lane = t & 63, w = t >> 6;
  int n_idx = lane & 15, quad = lane >> 4;
  const short8* wp8 = (const short8*)wpkE;
  for (int mt=0; mt<4; mt++){
    short8 a[KS];
    const bf16* ab = xs + (size_t)(mt*16 + n_idx)*SR + quad*8;
    #pragma unroll
    for (int ks=0; ks<KS; ks++) a[ks] = *(const short8*)(ab + ks*32);
    int m = rb + mt*16 + n_idx;
    for (int nt=w; nt<9; nt+=4){
      const short8* bp = wp8 + (size_t)nt*64 + lane;
      f32x4 acc = {0.f,0.f,0.f,0.f};
      #pragma unroll
      for (int ks=0; ks<KS; ks++){
        short8 b = bp[(size_t)ks*9*64];
        acc = __builtin_amdgcn_mfma_f32_16x16x32_bf16(b, a[ks], acc, 0, 0, 0);
      }
      int nbase = nt*16 + quad*4;
      if (nbase < TABW){
        float4 o; o.x=acc[0]; o.y=acc[1]; o.z=acc[2]; o.w=acc[3];
        *(float4*)(tab + (size_t)m*TABW + nbase) = o;
      }
    }
  }
}

// per-edge attention logits from the table: el = tab[s][r*8+h], er = tab[d][r*8+4+h]
__global__ __launch_bounds__(256) void k_edge_lite(const float* __restrict__ tab,
                                                   const int* __restrict__ src, const int* __restrict__ dst,
                                                   bf16* abuf, float* z, int nE, int nd){
  int idx = blockIdx.x*256 + threadIdx.x;
  if (idx >= NET*nE) return;
  int r = idx / nE;
  int s = src[idx], d = dst[idx];
  float4 el = *(const float4*)(tab + (size_t)s*TABW + r*8);
  float4 er = *(const float4*)(tab + (size_t)d*TABW + r*8 + 4);
  float ev[4] = {el.x+er.x, el.y+er.y, el.z+er.z, el.w+er.w};
  float* zp = z + ((size_t)r*nd + d)*4;
  bf16* ao = abuf + (size_t)idx*4;
  #pragma unroll
  for (int h=0;h<4;h++){
    float v = ev[h];
    v = v>0.f ? v : 0.2f*v;
    float a = expf(fminf(v, 80.f));
    ao[h] = f2b(a);
    atomicAdd(&zp[h], a);
  }
}

// ---- legacy fallbacks (used only if workspace too small for the table) ------
template<int DIN>
__global__ __launch_bounds__(256) void k_er(const bf16* __restrict__ x, const float* __restrict__ war,
                                            bf16* __restrict__ er, int nd){
  int idx = blockIdx.x*256 + threadIdx.x;
  if (idx >= NET*nd) return;
  int r = idx / nd, n = idx % nd;
  const ushort4* xr = (const ushort4*)(x + (size_t)n*DIN);
  const float4* w = (const float4*)(war + (size_t)r*DIN*4);
  float a0=0.f,a1=0.f,a2=0.f,a3=0.f;
  #pragma unroll 4
  for (int i=0;i<DIN/4;i++){
    ushort4 xv = xr[i];
    float x0=bs2f(xv.x), x1=bs2f(xv.y), x2=bs2f(xv.z), x3=bs2f(xv.w);
    float4 w0=w[4*i], w1=w[4*i+1], w2=w[4*i+2], w3=w[4*i+3];
    a0 += x0*w0.x + x1*w1.x + x2*w2.x + x3*w3.x;
    a1 += x0*w0.y + x1*w1.y + x2*w2.y + x3*w3.y;
    a2 += x0*w0.z + x1*w1.z + x2*w2.z + x3*w3.z;
    a3 += x0*w0.w + x1*w1.w + x2*w2.w + x3*w3.w;
  }
  bf16* e = er + (size_t)idx*4;
  e[0]=f2b(a0); e[1]=f2b(a1); e[2]=f2b(a2); e[3]=f2b(a3);
}

template<int DIN>
__global__ __launch_bounds__(256) void k_edge(const bf16* __restrict__ x, const float* __restrict__ wal,
                                              const bf16* __restrict__ er,
                                              const int* __restrict__ src, const int* __restrict__ dst,
                                              bf16* abuf, float* z, int nE, int nd){
  int idx = blockIdx.x*256 + threadIdx.x;
  if (idx >= NET*nE) return;
  int r = idx / nE;
  int s = src[idx], d = dst[idx];
  const ushort4* xr = (const ushort4*)(x + (size_t)s*DIN);
  const float4* w = (const float4*)(wal + (size_t)r*DIN*4);
  float a0=0.f,a1=0.f,a2=0.f,a3=0.f;
  #pragma unroll 4
  for (int i=0;i<DIN/4;i++){
    ushort4 xv = xr[i];
    float x0=bs2f(xv.x), x1=bs2f(xv.y), x2=bs2f(xv.z), x3=bs2f(xv.w);
    float4 w0=w[4*i], w1=w[4*i+1], w2=w[4*i+2], w3=w[4*i+3];
    a0 += x0*w0.x + x1*w1.x + x2*w2.x + x3*w3.x;
    a1 += x0*w0.y + x1*w1.y + x2*w2.y + x3*w3.y;
    a2 += x0*w0.z + x1*w1.z + x2*w2.z + x3*w3.z;
    a3 += x0*w0.w + x1*w1.w + x2*w2.w + x3*w3.w;
  }
  float acc[4] = {a0,a1,a2,a3};
  const bf16* ern = er + ((size_t)r*nd + d)*4;
  float* zp = z + ((size_t)r*nd + d)*4;
  bf16* ao = abuf + (size_t)idx*4;
  #pragma unroll
  for (int h=0;h<4;h++){
    float v = acc[h] + b2f(ern[h]);
    v = v>0.f ? v : 0.2f*v;
    float a = expf(fminf(v, 80.f));
    ao[h] = f2b(a);
    atomicAdd(&zp[h], a);
  }
}

// ---- CSR build over destination ids ----------------------------------------
__global__ __launch_bounds__(256) void k_count(const int* __restrict__ dst, long n, unsigned* cnt){
  long i = (long)blockIdx.x*256 + threadIdx.x;
  if (i >= n) return;
  atomicAdd(&cnt[dst[i]], 1u);
}

__global__ __launch_bounds__(256) void k_scan(const unsigned* __restrict__ cnt, unsigned* offs, unsigned* cur, int n){
  __shared__ unsigned part[256];
  __shared__ unsigned tot;
  int t = threadIdx.x;
  int chunk = (n + 255)/256;
  int lo = t*chunk, hi = lo+chunk; if (hi > n) hi = n; if (lo > n) lo = n;
  unsigned s = 0;
  for (int i=lo;i<hi;i++) s += cnt[i];
  part[t] = s;
  __syncthreads();
  if (t==0){
    unsigned r = 0;
    for (int i=0;i<256;i++){ unsigned v = part[i]; part[i] = r; r += v; }
    tot = r;
  }
  __syncthreads();
  unsigned run = part[t];
  for (int i=lo;i<hi;i++){ offs[i]=run; cur[i]=run; run += cnt[i]; }
  if (t==0) offs[n] = tot;
}

// records each edge's CSR slot (posar) — F rows are stored dst-sorted
__global__ __launch_bounds__(256) void k_fillcsr(const int* __restrict__ dst, long n, unsigned* cur, int* posar){
  long i = (long)blockIdx.x*256 + threadIdx.x;
  if (i >= n) return;
  unsigned pos = atomicAdd(&cur[dst[i]], 1u);
  posar[i] = (int)pos;
}

// ---- MFMA edge-GEMM ---------------------------------------------------------
// mode 1: write alpha*fs row to fbuf at the edge's CSR slot (dst-sorted order)
// mode 0: atomic scatter into msg (fallback)
template<int DIN, int KS>
__global__ __launch_bounds__(256) void k_acc_mfma(const bf16* __restrict__ x, const bf16* __restrict__ wpk,
                                                  const bf16* __restrict__ abuf, const float* __restrict__ z,
                                                  const int* __restrict__ src, const int* __restrict__ dst,
                                                  const int* __restrict__ posar,
                                                  float* msg, bf16* fbuf, int nE, int nd, int r0, int mode){
  constexpr int KM = KS*32;
  constexpr int SR = KM + 8;
  __shared__ bf16 xs[64*SR];
  __shared__ float alpha_s[64*4];
  __shared__ int sdst[64], ssrc[64], spos[64];
  int r = r0 + blockIdx.y;
  int eb = blockIdx.x*64;
  int me = min(64, nE - eb);
  int t = threadIdx.x;
  if (t < 64){
    int v_src=0, v_dst=0, v_pos=0;
    if (t < me){
      v_src = src[(size_t)r*nE + eb + t];
      v_dst = dst[(size_t)r*nE + eb + t];
      if (posar) v_pos = posar[(size_t)(r - r0)*nE + eb + t];
    }
    ssrc[t]=v_src; sdst[t]=v_dst; spos[t]=v_pos;
  }
  __syncthreads();
  { // alpha per (edge, head)
    int m = t>>2, h = t&3;
    float al = 0.f;
    if (m < me){
      float a = b2f(abuf[((size_t)r*nE + eb + m)*4 + h]);
      float zz = z[((size_t)r*nd + sdst[m])*4 + h];
      al = a / fmaxf(zz, 1e-30f);
    }
    alpha_s[m*4+h] = al;
  }
  constexpr int CH = KM/4;
  for (int c = t; c < 64*CH; c += 256){
    int m = c / CH, j4 = c % CH;
    uint2 v = make_uint2(0u,0u);
    if (m < me && j4*4 < DIN) v = *(const uint2*)(x + (size_t)ssrc[m]*DIN + j4*4);
    *(uint2*)(xs + m*SR + j4*4) = v;
  }
  __syncthreads();

  int lane = t & 63, w = t >> 6;
  int n_idx = lane & 15, quad = lane >> 4;
  const short8* wpk8 = (const short8*)wpk;
  for (int mt=0; mt<4; mt++){
    short8 a[KS];
    const bf16* abase = xs + (size_t)(mt*16 + n_idx)*SR + quad*8;
    #pragma unroll
    for (int ks=0; ks<KS; ks++) a[ks] = *(const short8*)(abase + ks*32);
    int m = mt*16 + n_idx;              // edge row within block
    for (int nt=w; nt<13; nt+=4){
      const short8* bp = wpk8 + (((size_t)r*KS)*13 + nt)*64 + lane;
      f32x4 acc = {0.f,0.f,0.f,0.f};
      #pragma unroll
      for (int ks=0; ks<KS; ks++){
        short8 b = bp[(size_t)ks*13*64];
        acc = __builtin_amdgcn_mfma_f32_16x16x32_bf16(b, a[ks], acc, 0, 0, 0);  // D = W^T x^T
      }
      int nbase = nt*16 + quad*4;
      if (nbase < 200 && m < me){
        if (mode == 0){
          #pragma unroll
          for (int reg=0; reg<4; reg++){
            int n = nbase + reg;
            atomicAdd(&msg[(size_t)sdst[m]*200 + n], acc[reg] * alpha_s[m*4 + n/50]);
          }
        } else {
          ushort4 pk;
          { int n=nbase;   pk.x = f2bu(acc[0] * alpha_s[m*4 + n/50]); }
          { int n=nbase+1; pk.y = f2bu(acc[1] * alpha_s[m*4 + n/50]); }
          { int n=nbase+2; pk.z = f2bu(acc[2] * alpha_s[m*4 + n/50]); }
          { int n=nbase+3; pk.w = f2bu(acc[3] * alpha_s[m*4 + n/50]); }
          *(ushort4*)(fbuf + (size_t)spos[m]*200 + nbase) = pk;
        }
      }
    }
  }
}

// ---- CSR gather: F rows are dst-sorted -> contiguous streaming reads --------
__global__ __launch_bounds__(256) void k_gather_seq(const bf16* __restrict__ F, const unsigned* __restrict__ offs,
                                                    float* __restrict__ msg, int nd, int accum){
  int w = threadIdx.x >> 6, lane = threadIdx.x & 63;
  int d = blockIdx.x*4 + w;
  if (d >= nd) return;
  unsigned k0 = offs[d], k1 = offs[d+1];
  if (lane < 50){
    float a0=0.f, a1=0.f, a2=0.f, a3=0.f;
    for (unsigned k=k0; k<k1; k++){
      ushort4 v = *(const ushort4*)(F + (size_t)k*200 + lane*4);
      a0 += bs2f(v.x); a1 += bs2f(v.y); a2 += bs2f(v.z); a3 += bs2f(v.w);
    }
    float4* out = (float4*)(msg + (size_t)d*200 + lane*4);
    if (accum){ float4 p = *out; a0 += p.x; a1 += p.y; a2 += p.z; a3 += p.w; }
    float4 o; o.x=a0; o.y=a1; o.z=a2; o.w=a3;
    *out = o;
  }
}

__global__ __launch_bounds__(256) void k_bgs(const bf16* bg0, const bf16* bg1, float* bgs0, float* bgs1){
  int j = blockIdx.x*256 + threadIdx.x;
  if (j < DIM){ float s=0.f; for(int r=0;r<NET;r++) s += b2f(bg0[r*DIM+j]); bgs0[j]=s; }
  else if (j < 2*DIM){ int jj=j-DIM; float s=0.f; for(int r=0;r<NET;r++) s += b2f(bg1[r*DIM+jj]); bgs1[jj]=s; }
}

__global__ __launch_bounds__(256) void k_build_x0(const int* nid0, const int* ts_p, const bf16* emb,
                                                  const bf16* tf, const bf16* tp, bf16* x0){
  long idx = (long)blockIdx.x*256 + threadIdx.x;
  if (idx >= (long)N0*DIN0) return;
  int n = idx / DIN0, j = idx % DIN0;
  int nid = nid0[n];
  bf16 v;
  if (j < DIME) v = emb[(size_t)(nid % NUME)*DIME + j];
  else {
    float t = (float)(ts_p[0] - nid / NUME);
    int jj = j - DIME;
    v = f2b(cosf(t * b2f(tf[jj]) + b2f(tp[jj])));
  }
  x0[idx] = v;
}

__global__ __launch_bounds__(256) void k_build_x1(const int* nid0, const int* ts_p, const float* msg0,
                                                  const float* bgs0, const bf16* tf, const bf16* tp, bf16* x1){
  long idx = (long)blockIdx.x*256 + threadIdx.x;
  if (idx >= (long)N1*DIN1) return;
  int n = idx / DIN1, j = idx % DIN1;
  bf16 v;
  if (j < DIM){
    v = f2b(fmaxf((msg0[(size_t)n*DIM + j] + bgs0[j]) * (1.0f/NET), 0.0f));
  } else {
    int nid = nid0[n];
    float t = (float)(ts_p[0] - nid / NUME);
    int jj = j - DIM;
    v = f2b(cosf(t * b2f(tf[jj]) + b2f(tp[jj])));
  }
  x1[idx] = v;
}

__global__ __launch_bounds__(256) void k_hid(const float* msg1, const float* bgs1, const int* root_idx, float* hid){
  long idx = (long)blockIdx.x*256 + threadIdx.x;
  if (idx >= (long)NROWS*HD) return;
  int b = idx / HD, c = idx % HD;
  int s = c / DIM, j = c % DIM;
  int n = root_idx[b*4 + s];
  hid[idx] = fmaxf((msg1[(size_t)n*DIM + j] + bgs1[j]) * (1.0f/NET), 0.0f);
}

// fused: ln0 -> q/v -> attention -> relu -> ln1 -> x3 (one row per block)
__global__ __launch_bounds__(256) void k_att_ln(const float* __restrict__ hid,
                                                const bf16* ln0w, const bf16* ln0b,
                                                const bf16* Wq, const bf16* bq,
                                                const bf16* Wv, const bf16* bv,
                                                const bf16* ln1w, const bf16* ln1b,
                                                float* __restrict__ x3){
  __shared__ float xs[HD], qs[HD], vs[HD], att_s[64], red[16];
  __shared__ float mu_s, rs_s;
  int b = blockIdx.x, t = threadIdx.x;
  int lane = t & 63, wid = t >> 6;
  const float* xr = hid + (size_t)b*HD;
  // LN0
  float s=0.f, s2=0.f;
  for (int j=t;j<HD;j+=256){ float v=xr[j]; s+=v; s2+=v*v; }
  for (int off=32; off; off>>=1){ s += __shfl_down(s,off); s2 += __shfl_down(s2,off); }
  if (lane==0){ red[wid]=s; red[8+wid]=s2; }
  __syncthreads();
  if (t==0){
    float S = red[0]+red[1]+red[2]+red[3];
    float S2 = red[8]+red[9]+red[10]+red[11];
    float mu = S * (1.0f/HD);
    float var = fmaxf(S2 * (1.0f/HD) - mu*mu, 0.f);
    mu_s = mu; rs_s = rsqrtf(var + 1e-5f);
  }
  __syncthreads();
  { float mu=mu_s, rs=rs_s;
    for (int j=t;j<HD;j+=256) xs[j] = (xr[j]-mu)*rs*b2f(ln0w[j]) + b2f(ln0b[j]); }
  __syncthreads();
  // q/v projections
  for (int idx=t; idx<HD; idx+=256){
    int ha = idx/200, srow=(idx%200)/50, o=idx%50;
    const float* xrow = xs + srow*200;
    const bf16* wq = Wq + (size_t)ha*DIM*OA + o;
    const bf16* wv = Wv + (size_t)ha*DIM*OA + o;
    float q=0.f, v=0.f;
    for (int e=0;e<DIM;e++){ float xv=xrow[e]; q += xv*b2f(wq[(size_t)e*OA]); v += xv*b2f(wv[(size_t)e*OA]); }
    qs[idx] = q + b2f(bq[ha*OA+o]);
    vs[idx] = v + b2f(bv[ha*OA+o]);
  }
  __syncthreads();
  if (t < 64){
    int ha=t>>4, srow=(t>>2)&3, tt=t&3;
    const float* qa = qs + ha*200 + srow*50;
    const float* qb = qs + ha*200 + tt*50;
    float sc=0.f;
    for (int o=0;o<50;o++) sc += qa[o]*qb[o];
    att_s[ha*16 + srow*4 + tt] = sc;
  }
  __syncthreads();
  if (t < 16){
    int ha=t>>2, tt=t&3;
    float m=-1e30f;
    for (int srow=0;srow<4;srow++) m = fmaxf(m, att_s[ha*16+srow*4+tt]);
    float ex[4]; float zz=0.f;
    for (int srow=0;srow<4;srow++){ ex[srow]=expf(att_s[ha*16+srow*4+tt]-m); zz+=ex[srow]; }
    for (int srow=0;srow<4;srow++) att_s[ha*16+srow*4+tt] = ex[srow]/zz;
  }
  __syncthreads();
  // attention output + relu -> overwrite xs (x2 row)
  for (int idx=t; idx<HD; idx+=256){
    int ha = idx/200, srow=(idx%200)/50, o=idx%50;
    float a=0.f;
    for (int tt=0;tt<4;tt++) a += att_s[ha*16+srow*4+tt]*vs[ha*200+tt*50+o];
    xs[srow*200 + ha*50 + o] = fmaxf(a, 0.f);
  }
  __syncthreads();
  // LN1
  s=0.f; s2=0.f;
  for (int j=t;j<HD;j+=256){ float v=xs[j]; s+=v; s2+=v*v; }
  for (int off=32; off; off>>=1){ s += __shfl_down(s,off); s2 += __shfl_down(s2,off); }
  if (lane==0){ red[wid]=s; red[8+wid]=s2; }
  __syncthreads();
  if (t==0){
    float S = red[0]+red[1]+red[2]+red[3];
    float S2 = red[8]+red[9]+red[10]+red[11];
    float mu = S * (1.0f/HD);
    float var = fmaxf(S2 * (1.0f/HD) - mu*mu, 0.f);
    mu_s = mu; rs_s = rsqrtf(var + 1e-5f);
  }
  __syncthreads();
  { float mu=mu_s, rs=rs_s;
    for (int j=t;j<HD;j+=256) x3[(size_t)b*HD + j] = (xs[j]-mu)*rs*b2f(ln1w[j]) + b2f(ln1b[j]); }
}

__global__ __launch_bounds__(256) void k_d1(const float* x3, const bf16* Wd1, const bf16* bd1, float* x4){
  __shared__ float xs[8*HD];
  int rb = blockIdx.x*8, t = threadIdx.x;
  for (int idx=t; idx<8*HD; idx+=256) xs[idx] = x3[(size_t)rb*HD + idx];
  __syncthreads();
  if (t < DIM){
    float acc[8] = {0,0,0,0,0,0,0,0};
    for (int k=0;k<HD;k++){
      float w = b2f(Wd1[(size_t)k*DIM + t]);
      #pragma unroll
      for (int r=0;r<8;r++) acc[r] += xs[r*HD+k]*w;
    }
    float bb = b2f(bd1[t]);
    for (int r=0;r<8;r++) x4[(size_t)(rb+r)*DIM + t] = fmaxf(acc[r]+bb, 0.f);
  }
}

// pack pred W (f32 or bf16 source) into fragment order
__global__ __launch_bounds__(256) void k_pack_pred(const void* Wsub, const void* Wobj, bf16* wpkP,
                                                    const unsigned* flagp){
  long idx = (long)blockIdx.x*256 + threadIdx.x;
  long total = (long)2*PKS*PNT*512;
  if (idx >= total) return;
  int j = (int)(idx & 7), lane = (int)((idx>>3) & 63);
  long rem = idx >> 9;
  int ntile = (int)(rem % PNT); rem /= PNT;
  int ks = (int)(rem % PKS); int page = (int)(rem / PKS);
  int k = ks*32 + (lane>>4)*8 + j;
  int n = ntile*16 + (lane&15);
  const void* W = page ? Wobj : Wsub;
  bool f32m = flagp[0] != 0u;
  float v = 0.f;
  if (k < 300) v = f32m ? ((const float*)W)[(size_t)k*NUME + n]
                        : b2f(((const bf16*)W)[(size_t)k*NUME + n]);
  wpkP[idx] = f2b(v);
}

__global__ __launch_bounds__(256) void k_prep_pred(const float* x4, const bf16* nSrel, const bf16* nOrel,
                                                    const int* rel, bf16* Apack){
  long idx = (long)blockIdx.x*256 + threadIdx.x;
  if (idx >= (long)2*1024*320) return;
  int j = (int)(idx % 320); long rem = idx/320;
  int row = (int)(rem % 1024); int page = (int)(rem / 1024);
  float v = 0.f;
  if (j < 200) v = x4[((size_t)(page==0 ? 1024+row : row))*DIM + j];
  else if (j < 300){
    const bf16* re = (page==0) ? nOrel : nSrel;
    v = b2f(re[(size_t)rel[row]*DIMR + (j-200)]);
  }
  Apack[idx] = f2b(v);
}

__global__ __launch_bounds__(256) void k_pred_mfma(const bf16* __restrict__ Apack, const bf16* __restrict__ wpkP,
                                                   const bf16* bsub, const bf16* bobj, void* outb,
                                                   const unsigned* flagp){
  constexpr int SR = 320 + 8;
  __shared__ bf16 As[64*SR];
  int page = blockIdx.z;
  int rb = blockIdx.y*64;
  int cb = blockIdx.x*16;
  int t = threadIdx.x;
  const bf16* Ap = Apack + (size_t)page*1024*320;
  for (int c=t; c<64*80; c+=256){
    int m=c/80, j4=c%80;
    *(uint2*)(As + m*SR + j4*4) = *(const uint2*)(Ap + (size_t)(rb+m)*320 + j4*4);
  }
  __syncthreads();
  int lane = t&63, w = t>>6;
  int n_idx = lane&15, quad = lane>>4;
  const short8* wp8 = (const short8*)(wpkP + (size_t)page*PKS*PNT*512);
  f32x4 acc[4][4];
  #pragma unroll
  for (int i=0;i<4;i++)
    #pragma unroll
    for (int mt=0;mt<4;mt++) acc[i][mt] = (f32x4){0.f,0.f,0.f,0.f};
  short8 bz = {0,0,0,0,0,0,0,0};
  for (int ks=0; ks<PKS; ks++){
    short8 bfr[4];
    #pragma unroll
    for (int i=0;i<4;i++){
      int ntile = cb + w + 4*i;
      bfr[i] = (ntile < PNT) ? wp8[((size_t)ks*PNT + ntile)*64 + lane] : bz;
    }
    short8 afr[4];
    #pragma unroll
    for (int mt=0;mt<4;mt++) afr[mt] = *(const short8*)(As + (size_t)(mt*16 + n_idx)*SR + ks*32 + quad*8);
    #pragma unroll
    for (int i=0;i<4;i++)
      #pragma unroll
      for (int mt=0;mt<4;mt++)
        acc[i][mt] = __builtin_amdgcn_mfma_f32_16x16x32_bf16(afr[mt], bfr[i], acc[i][mt], 0, 0, 0);
  }
  bool f32m = flagp[0] != 0u;
  const bf16* bias = page ? bobj : bsub;
  size_t elem_off = (size_t)page*BQ*NUME;
  for (int i=0;i<4;i++){
    int ntile = cb + w + 4*i;
    if (ntile >= PNT) continue;
    int n = ntile*16 + n_idx;
    float bb = b2f(bias[n]);
    #pragma unroll
    for (int mt=0;mt<4;mt++){
      #pragma unroll
      for (int reg=0;reg<4;reg++){
        int m = rb + mt*16 + quad*4 + reg;
        size_t oi = elem_off + (size_t)m*NUME + n;
        float val = acc[i][mt][reg] + bb;
        if (f32m) ((float*)outb)[oi] = val; else ((bf16*)outb)[oi] = f2b(val);
      }
    }
  }
}

// scalar fallback pred
__global__ __launch_bounds__(256) void k_pred(const float* xemb, const bf16* relemb, const int* rel,
                                              const void* W, const bf16* bias, void* outb, size_t elem_off,
                                              const unsigned* flagp){
  __shared__ float As[16*304];
  bool f32m = flagp[0] != 0u;
  int rb = blockIdx.y*16;
  int cb = blockIdx.x*512;
  int t = threadIdx.x;
  for (int idx=t; idx<16*300; idx+=256){
    int r = idx/300, i = idx%300;
    int row = rb + r;
    float v = (i < DIM) ? xemb[(size_t)row*DIM + i]
                        : b2f(relemb[(size_t)rel[row]*DIMR + (i-DIM)]);
    As[r*304+i] = v;
  }
  __syncthreads();
  int c0 = cb + t, c1 = cb + 256 + t;
  bool g0 = c0 < NUME, g1 = c1 < NUME;
  float acc0[16], acc1[16];
  #pragma unroll
  for (int r=0;r<16;r++){ acc0[r]=0.f; acc1[r]=0.f; }
  if (f32m){
    const float* W32 = (const float*)W;
    for (int k=0;k<300;k++){
      float w0 = g0 ? W32[(size_t)k*NUME + c0] : 0.f;
      float w1 = g1 ? W32[(size_t)k*NUME + c1] : 0.f;
      #pragma unroll
      for (int r=0;r<16;r++){ float a = As[r*304+k]; acc0[r] += a*w0; acc1[r] += a*w1; }
    }
  } else {
    const bf16* W16 = (const bf16*)W;
    for (int k=0;k<300;k++){
      float w0 = g0 ? b2f(W16[(size_t)k*NUME + c0]) : 0.f;
      float w1 = g1 ? b2f(W16[(size_t)k*NUME + c1]) : 0.f;
      #pragma unroll
      for (int r=0;r<16;r++){ float a = As[r*304+k]; acc0[r] += a*w0; acc1[r] += a*w1; }
    }
  }
  #pragma unroll
  for (int rr=0; rr<2; rr++){
    int c = rr ? c1 : c0;
    float* acc = rr ? acc1 : acc0;
    if (c < NUME){
      float bb = b2f(bias[c]);
      for (int r=0;r<16;r++){
        size_t oi = elem_off + (size_t)(rb+r)*NUME + c;
        float val = acc[r] + bb;
        if (f32m) ((float*)outb)[oi] = val; else ((bf16*)outb)[oi] = f2b(val);
      }
    }
  }
}

__global__ __launch_bounds__(256) void k_transpose(const void* in, bf16* out, int rows, int cols,
                                                   const unsigned* flagp){
  __shared__ bf16 tile[32][33];
  bool f32m = flagp[0] != 0u;
  int c0 = blockIdx.x*32, r0 = blockIdx.y*32;
  int tx = threadIdx.x % 32, ty = threadIdx.x / 32;
  for (int rr=ty; rr<32; rr+=8){
    int r = r0+rr, c = c0+tx;
    if (r<rows && c<cols){
      size_t i = (size_t)r*cols + c;
      tile[rr][tx] = f32m ? f2b(((const float*)in)[i]) : ((const bf16*)in)[i];
    }
  }
  __syncthreads();
  for (int rr=ty; rr<32; rr+=8){
    int ocol = c0+rr, orow = r0+tx;
    if (ocol<cols && orow<rows) out[(size_t)ocol*rows + orow] = tile[tx][rr];
  }
}

__global__ __launch_bounds__(256) void k_scatter(const int* copy_rows, const int* copy_cols, const int* rel,
                                                 const float* hid, const bf16* csrel, const bf16* corel,
                                                 const bf16* cWsubT, const bf16* cWobjT,
                                                 const bf16* cbsub, const bf16* cbobj,
                                                 void* outb, const unsigned* flagp){
  bool f32m = flagp[0] != 0u;
  int wid = threadIdx.x >> 6, lane = threadIdx.x & 63;
  long k = (long)blockIdx.x*4 + wid;
  if (k >= KK) return;
  int row = copy_rows[k], col = copy_cols[k];
  const float* chrow; const bf16* re; const bf16* wt; float bias_v;
  if (row < BQ){
    chrow = hid + ((size_t)(BQ+row))*HD + 600;
    re = corel + (size_t)rel[row]*DIMR;
    wt = cWsubT + (size_t)col*300;
    bias_v = b2f(cbsub[col]);
  } else {
    int rr = row - BQ;
    chrow = hid + ((size_t)rr)*HD + 600;
    re = csrel + (size_t)rel[rr]*DIMR;
    wt = cWobjT + (size_t)col*300;
    bias_v = b2f(cbobj[col]);
  }
  float s = 0.f;
  for (int i=lane; i<300; i+=64){
    float a = (i < DIM) ? chrow[i] : b2f(re[i-DIM]);
    s += a * b2f(wt[i]);
  }
  for (int off=32; off; off>>=1) s += __shfl_down(s, off);
  if (lane==0){
    size_t oi = (size_t)2*BQ*NUME + (size_t)row*NUME + col;
    float val = s + bias_v;
    if (f32m) ((float*)outb)[oi] = val; else ((bf16*)outb)[oi] = f2b(val);
  }
}

static inline dim3 GS(long n){ return dim3((unsigned)((n + 255)/256)); }

extern "C" void kernel_launch(void* const* d_in, const int* in_sizes, int n_in,
                              void* d_out, int out_size, void* d_ws, size_t ws_size,
                              hipStream_t stream){
  const int* rel       = (const int*)d_in[2];
  const int* ts_p      = (const int*)d_in[3];
  const int* nid0      = (const int*)d_in[4];
  const int* root_idx  = (const int*)d_in[5];
  const int* src0      = (const int*)d_in[6];
  const int* dst0      = (const int*)d_in[7];
  const int* src1      = (const int*)d_in[8];
  const int* dst1      = (const int*)d_in[9];
  const int* copy_rows = (const int*)d_in[10];
  const int* copy_cols = (const int*)d_in[11];
  const void* Wsub  = d_in[35];
  const void* Wobj  = d_in[37];
  const void* cWsub = d_in[41];
  const void* cWobj = d_in[43];

  // ---- workspace layout ----
  char* base = (char*)d_ws;
  size_t off = 0;
  auto alloc = [&](size_t bytes)->char*{
    char* p = base + off; off = (off + bytes + 255) & ~(size_t)255; return p;
  };
  unsigned* flagp = (unsigned*)alloc(256);
  long cvt_total = 0; for (int i=0;i<CVT_NREG;i++) cvt_total += CVT_N[i];
  bf16* normb = (bf16*)alloc((size_t)cvt_total*2);
  bf16* x0    = (bf16*)alloc((size_t)N0*DIN0*2);
  bf16* x1    = (bf16*)alloc((size_t)N1*DIN1*2);
  float* msg0 = (float*)alloc((size_t)N1*DIM*4);
  float* wal0 = (float*)alloc((size_t)NET*DIN0*4*4);
  float* war0 = (float*)alloc((size_t)NET*DIN0*4*4);
  float* wal1 = (float*)alloc((size_t)NET*DIN1*4*4);
  float* war1 = (float*)alloc((size_t)NET*DIN1*4*4);
  float* bgs0 = (float*)alloc(DIM*4);
  float* bgs1 = (float*)alloc(DIM*4);
  bf16* wpk0  = (bf16*)alloc((size_t)NET*4*13*512*2);
  bf16* wpk1  = (bf16*)alloc((size_t)NET*8*13*512*2);
  bf16* wpkE0 = (bf16*)alloc((size_t)4*9*512*2);
  bf16* wpkE1 = (bf16*)alloc((size_t)8*9*512*2);
  size_t arena = off;
  // phase-1 (GAT layer 0)
  char* P1 = base + arena;
  bf16*  a0b = (bf16*)P1;                                   // NET*E0*8 = 8,160,000
  float* z0  = (float*)(P1 + (size_t)NET*E0*8);             // NET*N1*16 = 10,880,000
  size_t ext1 = (size_t)NET*E0*8 + (size_t)NET*N1*16;
  // phase-2 (layer 1 + tail) — overlays phase-1
  char* A = base + arena;
  bf16*  a1b  = (bf16*)A;                                   // NET*E1*8 = 2,176,000
  float* z1   = (float*)(A + (size_t)NET*E1*8);             // NET*RNODES*16 = 2,228,224
  float* msg1 = (float*)(A + (size_t)NET*E1*8 + (size_t)NET*RNODES*16);
  size_t msg1_off = (size_t)NET*E1*8 + (size_t)NET*RNODES*16;
  float* hid  = (float*)(A + msg1_off + (size_t)RNODES*DIM*4);
  size_t hid_off = msg1_off + (size_t)RNODES*DIM*4;
  float* x3   = (float*)(A + hid_off + (size_t)NROWS*HD*4);
  size_t x3_off = hid_off + (size_t)NROWS*HD*4;
  float* x4   = (float*)(A + x3_off + (size_t)NROWS*HD*4);
  size_t ext2 = x3_off + (size_t)NROWS*HD*4 + (size_t)NROWS*DIM*4;
  bf16* cWsubT = (bf16*)x0;
  bf16* cWobjT = (bf16*)((char*)x0 + (size_t)NUME*300*2);

  // ---- tail region: CSR + F buffers ----
  size_t extmax = ext1 > ext2 ? ext1 : ext2;
  size_t tail = (arena + extmax + 255) & ~(size_t)255;
  size_t cntsz = (((size_t)(N1+1)*4) + 255) & ~(size_t)255;
  unsigned* cnt  = (unsigned*)(base + tail);
  unsigned* offs = (unsigned*)(base + tail + cntsz);
  unsigned* cur  = (unsigned*)(base + tail + 2*cntsz);
  size_t posar_sz = (((size_t)NET*E0*4) + 255) & ~(size_t)255;
  int* posar = (int*)(base + tail + 3*cntsz);
  size_t F_off = tail + 3*cntsz + posar_sz;
  bf16* fbuf = (bf16*)(base + F_off);
  size_t fcap = (ws_size > F_off) ? (ws_size - F_off) : 0;
  size_t relF0 = (size_t)E0*200*2, relF1 = (size_t)E1*200*2;
  int nrelc0 = (int)((fcap / relF0 < (size_t)NET) ? (fcap / relF0) : (size_t)NET);
  int nrelc1 = (int)((fcap / relF1 < (size_t)NET) ? (fcap / relF1) : (size_t)NET);
  // node-relation tables alias fbuf (dead before fbuf writes begin)
  float* tab0 = (float*)fbuf;
  float* tab1 = (float*)fbuf;
  bool elrok0 = fcap >= (size_t)N0*TABW*4;
  bool elrok1 = fcap >= (size_t)N1*TABW*4;
  // legacy er scratch (fallback only): aliases dead x1 (L0) / x0 (L1)
  bf16* er0f = (bf16*)x1;
  bf16* er1f = (bf16*)x0;
  // pred MFMA buffers alias fbuf (dead after last gather)
  size_t wpkP_sz = (size_t)2*PKS*PNT*512*2;
  size_t Apack_sz = (size_t)2*1024*320*2;
  bf16* wpkP  = (bf16*)(base + F_off);
  bf16* Apack = (bf16*)(base + F_off + wpkP_sz);
  bool predok = fcap >= (wpkP_sz + Apack_sz);

  long cum[CVT_NREG+1]; cum[0]=0;
  for (int i=0;i<CVT_NREG;i++) cum[i+1] = cum[i] + CVT_N[i];
  auto NP = [&](int i)->const bf16*{ return normb + cum[i]; };
  const bf16 *nEmb=NP(0), *nTf=NP(1), *nTp=NP(2), *nWg0=NP(3), *nAl0=NP(4), *nAr0=NP(5), *nBg0=NP(6),
             *nWg1=NP(7), *nAl1=NP(8), *nAr1=NP(9), *nBg1=NP(10), *nLn0w=NP(11), *nLn0b=NP(12),
             *nWq=NP(13), *nBq=NP(14), *nWv=NP(15), *nBv=NP(16), *nLn1w=NP(17), *nLn1b=NP(18),
             *nWd1=NP(19), *nBd1=NP(20), *nSrel=NP(21), *nOrel=NP(22), *nBsub=NP(23), *nBobj=NP(24),
             *nCsrel=NP(25), *nCorel=NP(26), *nCbsub=NP(27), *nCbobj=NP(28);

  // ---- phase 0 ----
  k_detect<<<dim3(1),64,0,stream>>>((const unsigned*)d_in[13], flagp);
  CvtSrcs srcs;
  for (int i=0;i<CVT_NREG;i++) srcs.p[i] = d_in[CVT_DIN[i]];
  CvtMeta meta;
  { int c=0, bc=0;
    for (int i=0;i<CVT_NREG;i++){ meta.cum[i]=c; meta.bcum[i]=bc; c+=CVT_N[i]; bc += (CVT_N[i]+255)/256; }
    meta.cum[CVT_NREG]=c; meta.bcum[CVT_NREG]=bc;
    k_cvt<<<dim3((unsigned)bc),256,0,stream>>>(srcs, meta, normb, flagp);
  }
  k_fill_u32<<<GS((long)NET*N1*4),256,0,stream>>>((unsigned*)z0, 0u, (long)NET*N1*4);
  k_fill_out<<<GS((long)2*BQ*NUME),256,0,stream>>>(d_out, flagp);
  k_prep_w<<<GS(NET*DIN0*4),256,0,stream>>>(nWg0, nAl0, nAr0, wal0, war0, DIN0);
  k_prep_w<<<GS(NET*DIN1*4),256,0,stream>>>(nWg1, nAl1, nAr1, wal1, war1, DIN1);
  k_pack<<<GS((long)NET*4*13*512),256,0,stream>>>(nWg0, wpk0, DIN0, 4);
  k_pack<<<GS((long)NET*8*13*512),256,0,stream>>>(nWg1, wpk1, DIN1, 8);
  k_pack_walr<<<GS((long)4*9*512),256,0,stream>>>(wal0, war0, wpkE0, DIN0, 4);
  k_pack_walr<<<GS((long)8*9*512),256,0,stream>>>(wal1, war1, wpkE1, DIN1, 8);
  k_bgs<<<GS(2*DIM),256,0,stream>>>(nBg0, nBg1, bgs0, bgs1);
  k_build_x0<<<GS((long)N0*DIN0),256,0,stream>>>(nid0, ts_p, nEmb, nTf, nTp, x0);

  // ---- GAT layer 0: edge logits ----
  if (elrok0){
    k_elr<DIN0,4><<<dim3(N0/64),256,0,stream>>>(x0, wpkE0, tab0);
    k_edge_lite<<<GS((long)NET*E0),256,0,stream>>>(tab0, src0, dst0, a0b, z0, E0, N1);
  } else {
    k_er<DIN0><<<GS((long)NET*N1),256,0,stream>>>(x0, war0, er0f, N1);
    k_edge<DIN0><<<GS((long)NET*E0),256,0,stream>>>(x0, wal0, er0f, src0, dst0, a0b, z0, E0, N1);
  }
  // ---- GAT layer 0: message accumulate ----
  if (nrelc0 >= 1){
    for (int r0=0; r0<NET; r0+=nrelc0){
      int nr = (NET - r0 < nrelc0) ? (NET - r0) : nrelc0;
      long nEd = (long)nr*E0;
      k_fill_u32<<<GS((long)N1+1),256,0,stream>>>(cnt, 0u, (long)N1+1);
      k_count<<<GS(nEd),256,0,stream>>>(dst0 + (size_t)r0*E0, nEd, cnt);
      k_scan<<<dim3(1),256,0,stream>>>(cnt, offs, cur, N1);
      k_fillcsr<<<GS(nEd),256,0,stream>>>(dst0 + (size_t)r0*E0, nEd, cur, posar);
      k_acc_mfma<DIN0,4><<<dim3((E0+63)/64, nr),256,0,stream>>>(x0, wpk0, a0b, z0, src0, dst0, posar,
                                                                 msg0, fbuf, E0, N1, r0, 1);
      k_gather_seq<<<dim3((N1+3)/4),256,0,stream>>>(fbuf, offs, msg0, N1, r0>0 ? 1 : 0);
    }
  } else {
    k_fill_u32<<<GS((long)N1*DIM),256,0,stream>>>((unsigned*)msg0, 0u, (long)N1*DIM);
    k_acc_mfma<DIN0,4><<<dim3((E0+63)/64, NET),256,0,stream>>>(x0, wpk0, a0b, z0, src0, dst0, (int*)nullptr,
                                                                msg0, (bf16*)nullptr, E0, N1, 0, 0);
  }

  // ---- build x1, GAT layer 1 ----
  k_build_x1<<<GS((long)N1*DIN1),256,0,stream>>>(nid0, ts_p, msg0, bgs0, nTf, nTp, x1);
  k_fill_u32<<<GS((long)NET*RNODES*4),256,0,stream>>>((unsigned*)z1, 0u, (long)NET*RNODES*4);
  if (elrok1){
    k_elr<DIN1,8><<<dim3(N1/64),256,0,stream>>>(x1, wpkE1, tab1);
    k_edge_lite<<<GS((long)NET*E1),256,0,stream>>>(tab1, src1, dst1, a1b, z1, E1, RNODES);
  } else {
    k_er<DIN1><<<GS((long)NET*RNODES),256,0,stream>>>(x1, war1, er1f, RNODES);
    k_edge<DIN1><<<GS((long)NET*E1),256,0,stream>>>(x1, wal1, er1f, src1, dst1, a1b, z1, E1, RNODES);
  }
  if (nrelc1 >= 1){
    for (int r0=0; r0<NET; r0+=nrelc1){
      int nr = (NET - r0 < nrelc1) ? (NET - r0) : nrelc1;
      long nEd = (long)nr*E1;
      k_fill_u32<<<GS((long)RNODES+1),256,0,stream>>>(cnt, 0u, (long)RNODES+1);
      k_count<<<GS(nEd),256,0,stream>>>(dst1 + (size_t)r0*E1, nEd, cnt);
      k_scan<<<dim3(1),256,0,stream>>>(cnt, offs, cur, RNODES);
      k_fillcsr<<<GS(nEd),256,0,stream>>>(dst1 + (size_t)r0*E1, nEd, cur, posar);
      k_acc_mfma<DIN1,8><<<dim3((E1+63)/64, nr),256,0,stream>>>(x1, wpk1, a1b, z1, src1, dst1, posar,
                                                                 msg1, fbuf, E1, RNODES, r0, 1);
      k_gather_seq<<<dim3((RNODES+3)/4),256,0,stream>>>(fbuf, offs, msg1, RNODES, r0>0 ? 1 : 0);
    }
  } else {
    k_fill_u32<<<GS((long)RNODES*DIM),256,0,stream>>>((unsigned*)msg1, 0u, (long)RNODES*DIM);
    k_acc_mfma<DIN1,8><<<dim3((E1+63)/64, NET),256,0,stream>>>(x1, wpk1, a1b, z1, src1, dst1, (int*)nullptr,
                                                                msg1, (bf16*)nullptr, E1, RNODES, 0, 0);
  }

  // ---- pred W pack (aliases fbuf — dead after last gather) ----
  if (predok)
    k_pack_pred<<<GS((long)2*PKS*PNT*512),256,0,stream>>>(Wsub, Wobj, wpkP, flagp);

  // ---- gather hid, copy-head scatter ----
  k_hid<<<GS((long)NROWS*HD),256,0,stream>>>(msg1, bgs1, root_idx, hid);
  k_transpose<<<dim3(625,10),256,0,stream>>>(cWsub, cWsubT, 300, NUME, flagp);
  k_transpose<<<dim3(625,10),256,0,stream>>>(cWobj, cWobjT, 300, NUME, flagp);
  k_scatter<<<dim3((KK+3)/4),256,0,stream>>>(copy_rows, copy_cols, rel, hid, nCsrel, nCorel,
                                             cWsubT, cWobjT, nCbsub, nCbobj, d_out, flagp);

  // ---- fused attention tail ----
  k_att_ln<<<dim3(NROWS),256,0,stream>>>(hid, nLn0w, nLn0b, nWq, nBq, nWv, nBv, nLn1w, nLn1b, x3);
  k_d1<<<dim3(NROWS/8),256,0,stream>>>(x3, nWd1, nBd1, x4);

  // ---- final predictions ----
  if (predok){
    k_prep_pred<<<GS((long)2*1024*320),256,0,stream>>>(x4, nSrel, nOrel, rel, Apack);
    k_pred_mfma<<<dim3(79,16,2),256,0,stream>>>(Apack, wpkP, nBsub, nBobj, d_out, flagp);
  } else {
    k_pred<<<dim3(40,64),256,0,stream>>>(x4 + (size_t)BQ*DIM, nOrel, rel, Wsub, nBsub, d_out, 0, flagp);
    k_pred<<<dim3(40,64),256,0,stream>>>(x4,                  nSrel, rel, Wobj, nBobj, d_out, (size_t)BQ*NUME, flagp);
  }
  (void)in_sizes; (void)n_in; (void)out_size; (void)ws_size;
}

// Round 4
// 2279.049 us; speedup vs baseline: 1.9339x; 1.0114x over previous
//
#include <hip/hip_runtime.h>
#include <hip/hip_bf16.h>
#include <math.h>

typedef __hip_bfloat16 bf16;
typedef __attribute__((ext_vector_type(8))) short short8;
typedef __attribute__((ext_vector_type(4))) float f32x4;

#define BQ 1024
#define NUME 20000
#define NET 17
#define DIMT 28
#define DIME 100
#define DIM 200
#define HEADS 4
#define OH 50
#define N0 160000
#define N1 40000
#define RNODES 8192
#define E0 60000
#define E1 16000
#define KK 500000
#define DIMR 100
#define HATT 4
#define OA 50
#define DIN0 128
#define DIN1 228
#define HD 800
#define NROWS 2048
#define PKS 10
#define PNT 1250
#define TABW 136   // 17 relations * (4 wal + 4 war)
#define E0PAD 60032
#define E1PAD 16000

__device__ __forceinline__ float b2f(bf16 v){ return __bfloat162float(v); }
__device__ __forceinline__ bf16 f2b(float v){ return __float2bfloat16(v); }
__device__ __forceinline__ float bs2f(unsigned short u){ return __uint_as_float((unsigned)u << 16); }
__device__ __forceinline__ unsigned short f2bu(float v){ bf16 t = f2b(v); return *reinterpret_cast<unsigned short*>(&t); }

// ---- dtype normalization ----------------------------------------------------
static constexpr int CVT_NREG = 29;
static constexpr int CVT_N[CVT_NREG] = {
  2000000, 28, 28, 435200, 3400, 3400, 3400, 775200, 3400, 3400, 3400,
  800, 800, 40000, 200, 40000, 200, 800, 800, 160000, 200, 800, 800,
  20000, 20000, 800, 800, 20000, 20000
};
static constexpr int CVT_DIN[CVT_NREG] = {
  12,13,14,15,16,17,18,19,20,21,22,23,24,25,26,27,28,29,30,31,32,33,34,36,38,39,40,42,44
};
struct CvtSrcs { const void* p[CVT_NREG]; };
struct CvtMeta { int cum[CVT_NREG+1]; int bcum[CVT_NREG+1]; };

__global__ __launch_bounds__(64) void k_detect(const unsigned* tfw, unsigned* flag){
  if (threadIdx.x == 0) flag[0] = ((tfw[0] & 0xFFFFu) == 0u) ? 1u : 0u;
}

__global__ __launch_bounds__(256) void k_cvt(CvtSrcs srcs, CvtMeta meta, bf16* dst, const unsigned* flagp){
  int b = blockIdx.x;
  int r = 0;
  while (meta.bcum[r+1] <= b) r++;
  int i = (b - meta.bcum[r])*256 + threadIdx.x;
  int n = meta.cum[r+1] - meta.cum[r];
  if (i >= n) return;
  bool f32m = flagp[0] != 0u;
  bf16 v;
  if (f32m) v = f2b(((const float*)srcs.p[r])[i]);
  else      v = ((const bf16*)srcs.p[r])[i];
  dst[meta.cum[r] + i] = v;
}

__global__ __launch_bounds__(256) void k_fill_u32(unsigned* p, unsigned v, long n){
  long i = (long)blockIdx.x*256 + threadIdx.x;
  if (i < n) p[i] = v;
}

__global__ __launch_bounds__(256) void k_fill_out(void* outb, const unsigned* flagp){
  bool f32m = flagp[0] != 0u;
  long nwords = f32m ? (long)2*BQ*NUME : (long)BQ*NUME;
  long i = (long)blockIdx.x*256 + threadIdx.x;
  if (i >= nwords) return;
  unsigned* p = (unsigned*)((char*)outb + (size_t)2*BQ*NUME * (f32m ? 4 : 2));
  p[i] = f32m ? 0xC2C80000u : 0xC2C8C2C8u;
}

__global__ __launch_bounds__(256) void k_prep_w(const bf16* Wg, const bf16* al, const bf16* ar,
                                                float* wal, float* war, int DIN){
  int idx = blockIdx.x*256 + threadIdx.x;
  int total = NET*DIN*4;
  if (idx >= total) return;
  int h = idx & 3; int ri = idx >> 2; int i = ri % DIN; int r = ri / DIN;
  const bf16* wrow = Wg + ((size_t)(r*DIN + i))*HEADS*OH + h*OH;
  const bf16* alr = al + (size_t)(r*HEADS + h)*OH;
  const bf16* arr = ar + (size_t)(r*HEADS + h)*OH;
  float sl=0.f, sr=0.f;
  for (int o=0;o<OH;o++){ float w=b2f(wrow[o]); sl += w*b2f(alr[o]); sr += w*b2f(arr[o]); }
  wal[idx]=sl; war[idx]=sr;
}

// pack W into MFMA B-fragment order: wpk[((r*KS+ks)*13+nt)*512 + lane*8 + j]
__global__ __launch_bounds__(256) void k_pack(const bf16* Wg, bf16* wpk, int DIN, int KS){
  int idx = blockIdx.x*256 + threadIdx.x;
  int total = NET*KS*13*512;
  if (idx >= total) return;
  int j = idx & 7, lane = (idx>>3) & 63;
  int rem = idx >> 9;
  int nt = rem % 13, rks = rem / 13;
  int ks = rks % KS, r = rks / KS;
  int k = ks*32 + (lane>>4)*8 + j;
  int n = nt*16 + (lane&15);
  bf16 v = f2b(0.f);
  if (k < DIN && n < 200) v = Wg[((size_t)r*DIN + k)*200 + n];
  wpk[idx] = v;
}

// pack [wal|war] into fragment order [ks][nt(9)][lane][8]
__global__ __launch_bounds__(256) void k_pack_walr(const float* wal, const float* war, bf16* wpkE,
                                                   int DIN, int KS){
  int idx = blockIdx.x*256 + threadIdx.x;
  int total = KS*9*512;
  if (idx >= total) return;
  int j = idx & 7, lane = (idx>>3) & 63;
  int rem = idx >> 9;
  int nt = rem % 9, ks = rem / 9;
  int k = ks*32 + (lane>>4)*8 + j;
  int c = nt*16 + (lane&15);
  float v = 0.f;
  if (k < DIN && c < TABW){
    int r = c >> 3, q = c & 7;
    const float* wsrc = (q < 4) ? wal : war;
    v = wsrc[((size_t)r*DIN + k)*4 + (q & 3)];
  }
  wpkE[idx] = f2b(v);
}

// node-relation table GEMM: tab[m][c] = x[m] . walr[:,c]
template<int DIN, int KS>
__global__ __launch_bounds__(256) void k_elr(const bf16* __restrict__ x, const bf16* __restrict__ wpkE,
                                             float* __restrict__ tab){
  constexpr int KM = KS*32;
  constexpr int SR = KM + 8;
  __shared__ bf16 xs[64*SR];
  int rb = blockIdx.x*64;
  int t = threadIdx.x;
  constexpr int CH = KM/4;
  for (int c = t; c < 64*CH; c += 256){
    int m = c / CH, j4 = c % CH;
    uint2 v = make_uint2(0u,0u);
    if (j4*4 < DIN) v = *(const uint2*)(x + (size_t)(rb+m)*DIN + j4*4);
    *(uint2*)(xs + m*SR + j4*4) = v;
  }
  __syncthreads();
  int lane = t & 63, w = t >> 6;
  int n_idx = lane & 15, quad = lane >> 4;
  const short8* wp8 = (const short8*)wpkE;
  for (int mt=0; mt<4; mt++){
    short8 a[KS];
    const bf16* ab = xs + (size_t)(mt*16 + n_idx)*SR + quad*8;
    #pragma unroll
    for (int ks=0; ks<KS; ks++) a[ks] = *(const short8*)(ab + ks*32);
    int m = rb + mt*16 + n_idx;
    for (int nt=w; nt<9; nt+=4){
      const short8* bp = wp8 + (size_t)nt*64 + lane;
      f32x4 acc = {0.f,0.f,0.f,0.f};
      #pragma unroll
      for (int ks=0; ks<KS; ks++){
        short8 b = bp[(size_t)ks*9*64];
        acc = __builtin_amdgcn_mfma_f32_16x16x32_bf16(b, a[ks], acc, 0, 0, 0);
      }
      int nbase = nt*16 + quad*4;
      if (nbase < TABW){
        float4 o; o.x=acc[0]; o.y=acc[1]; o.z=acc[2]; o.w=acc[3];
        *(float4*)(tab + (size_t)m*TABW + nbase) = o;
      }
    }
  }
}

__global__ __launch_bounds__(256) void k_edge_lite(const float* __restrict__ tab,
                                                   const int* __restrict__ src, const int* __restrict__ dst,
                                                   bf16* abuf, float* z, int nE, int nd){
  int idx = blockIdx.x*256 + threadIdx.x;
  if (idx >= NET*nE) return;
  int r = idx / nE;
  int s = src[idx], d = dst[idx];
  float4 el = *(const float4*)(tab + (size_t)s*TABW + r*8);
  float4 er = *(const float4*)(tab + (size_t)d*TABW + r*8 + 4);
  float ev[4] = {el.x+er.x, el.y+er.y, el.z+er.z, el.w+er.w};
  float* zp = z + ((size_t)r*nd + d)*4;
  bf16* ao = abuf + (size_t)idx*4;
  #pragma unroll
  for (int h=0;h<4;h++){
    float v = ev[h];
    v = v>0.f ? v : 0.2f*v;
    float a = expf(fminf(v, 80.f));
    ao[h] = f2b(a);
    atomicAdd(&zp[h], a);
  }
}

// ---- legacy fallbacks (workspace-tight only) --------------------------------
template<int DIN>
__global__ __launch_bounds__(256) void k_er(const bf16* __restrict__ x, const float* __restrict__ war,
                                            bf16* __restrict__ er, int nd){
  int idx = blockIdx.x*256 + threadIdx.x;
  if (idx >= NET*nd) return;
  int r = idx / nd, n = idx % nd;
  const ushort4* xr = (const ushort4*)(x + (size_t)n*DIN);
  const float4* w = (const float4*)(war + (size_t)r*DIN*4);
  float a0=0.f,a1=0.f,a2=0.f,a3=0.f;
  #pragma unroll 4
  for (int i=0;i<DIN/4;i++){
    ushort4 xv = xr[i];
    float x0=bs2f(xv.x), x1=bs2f(xv.y), x2=bs2f(xv.z), x3=bs2f(xv.w);
    float4 w0=w[4*i], w1=w[4*i+1], w2=w[4*i+2], w3=w[4*i+3];
    a0 += x0*w0.x + x1*w1.x + x2*w2.x + x3*w3.x;
    a1 += x0*w0.y + x1*w1.y + x2*w2.y + x3*w3.y;
    a2 += x0*w0.z + x1*w1.z + x2*w2.z + x3*w3.z;
    a3 += x0*w0.w + x1*w1.w + x2*w2.w + x3*w3.w;
  }
  bf16* e = er + (size_t)idx*4;
  e[0]=f2b(a0); e[1]=f2b(a1); e[2]=f2b(a2); e[3]=f2b(a3);
}

template<int DIN>
__global__ __launch_bounds__(256) void k_edge(const bf16* __restrict__ x, const float* __restrict__ wal,
                                              const bf16* __restrict__ er,
                                              const int* __restrict__ src, const int* __restrict__ dst,
                                              bf16* abuf, float* z, int nE, int nd){
  int idx = blockIdx.x*256 + threadIdx.x;
  if (idx >= NET*nE) return;
  int r = idx / nE;
  int s = src[idx], d = dst[idx];
  const ushort4* xr = (const ushort4*)(x + (size_t)s*DIN);
  const float4* w = (const float4*)(wal + (size_t)r*DIN*4);
  float a0=0.f,a1=0.f,a2=0.f,a3=0.f;
  #pragma unroll 4
  for (int i=0;i<DIN/4;i++){
    ushort4 xv = xr[i];
    float x0=bs2f(xv.x), x1=bs2f(xv.y), x2=bs2f(xv.z), x3=bs2f(xv.w);
    float4 w0=w[4*i], w1=w[4*i+1], w2=w[4*i+2], w3=w[4*i+3];
    a0 += x0*w0.x + x1*w1.x + x2*w2.x + x3*w3.x;
    a1 += x0*w0.y + x1*w1.y + x2*w2.y + x3*w3.y;
    a2 += x0*w0.z + x1*w1.z + x2*w2.z + x3*w3.z;
    a3 += x0*w0.w + x1*w1.w + x2*w2.w + x3*w3.w;
  }
  float acc[4] = {a0,a1,a2,a3};
  const bf16* ern = er + ((size_t)r*nd + d)*4;
  float* zp = z + ((size_t)r*nd + d)*4;
  bf16* ao = abuf + (size_t)idx*4;
  #pragma unroll
  for (int h=0;h<4;h++){
    float v = acc[h] + b2f(ern[h]);
    v = v>0.f ? v : 0.2f*v;
    float a = expf(fminf(v, 80.f));
    ao[h] = f2b(a);
    atomicAdd(&zp[h], a);
  }
}

// ---- per-relation dst-sorted CSR -------------------------------------------
__global__ __launch_bounds__(256) void k_count2(const int* __restrict__ dst, int nE, int nd, unsigned* cnt){
  int i = blockIdx.x*256 + threadIdx.x;
  if (i >= NET*nE) return;
  int r = i / nE; int d = dst[i];
  atomicAdd(&cnt[(size_t)r*nd + d], 1u);
}

// one block per relation; slot base = r*nEpad (static); offs has nd+1 entries per relation
__global__ __launch_bounds__(256) void k_scan2(const unsigned* __restrict__ cnt, unsigned* offs, unsigned* cur,
                                               int nd, int nE, int nEpad){
  __shared__ unsigned part[256];
  int r = blockIdx.x, t = threadIdx.x;
  unsigned base = (unsigned)(r*nEpad);
  const unsigned* c = cnt + (size_t)r*nd;
  unsigned* o  = offs + (size_t)r*(nd+1);
  unsigned* cu = cur  + (size_t)r*(nd+1);
  int chunk = (nd + 255)/256;
  int lo = t*chunk, hi = lo+chunk; if (hi > nd) hi = nd; if (lo > nd) lo = nd;
  unsigned s = 0;
  for (int i=lo;i<hi;i++) s += c[i];
  part[t] = s;
  __syncthreads();
  if (t==0){ unsigned run=0; for (int i=0;i<256;i++){ unsigned v=part[i]; part[i]=run; run+=v; } }
  __syncthreads();
  unsigned run = base + part[t];
  for (int i=lo;i<hi;i++){ o[i]=run; cu[i]=run; run += c[i]; }
  if (t==0) o[nd] = base + (unsigned)nE;
}

__global__ __launch_bounds__(256) void k_fillcsr2(const int* __restrict__ dst, int nE, int nd,
                                                  unsigned* cur, int* ids){
  int i = blockIdx.x*256 + threadIdx.x;
  if (i >= NET*nE) return;
  int r = i / nE, e = i - r*nE;
  int d = dst[i];
  unsigned pos = atomicAdd(&cur[(size_t)r*(nd+1) + d], 1u);
  ids[pos] = e;                       // global slot pos -> local edge index
}

// ---- MFMA edge-GEMM ---------------------------------------------------------
// mode 1: block (bx,r) covers sorted slots [bx*64, ..) of relation r; writes
// alpha*fs rows to fbuf at CONTIGUOUS slots (dst-sorted). mode 0: atomic scatter.
template<int DIN, int KS>
__global__ __launch_bounds__(256) void k_acc_mfma(const bf16* __restrict__ x, const bf16* __restrict__ wpk,
                                                  const bf16* __restrict__ abuf, const float* __restrict__ z,
                                                  const int* __restrict__ src, const int* __restrict__ dst,
                                                  const int* __restrict__ ids,
                                                  float* msg, bf16* fbuf, int nE, int nEpad, int nd, int mode){
  constexpr int KM = KS*32;
  constexpr int SR = KM + 8;
  __shared__ bf16 xs[64*SR];
  __shared__ float alpha_s[64*4];
  __shared__ int sdst[64], ssrc[64], sE[64];
  int r = blockIdx.y;
  int ls0 = blockIdx.x*64;
  int me = min(64, nE - ls0);
  int t = threadIdx.x;
  if (t < 64){
    int e = ls0 + t, vs=0, vd=0;
    if (t < me){
      if (mode == 1) e = ids[(size_t)r*nEpad + ls0 + t];
      vs = src[(size_t)r*nE + e];
      vd = dst[(size_t)r*nE + e];
    }
    sE[t]=e; ssrc[t]=vs; sdst[t]=vd;
  }
  __syncthreads();
  { // alpha per (edge, head)
    int m = t>>2, h = t&3;
    float al = 0.f;
    if (m < me){
      float a = b2f(abuf[((size_t)r*nE + sE[m])*4 + h]);
      float zz = z[((size_t)r*nd + sdst[m])*4 + h];
      al = a / fmaxf(zz, 1e-30f);
    }
    alpha_s[m*4+h] = al;
  }
  constexpr int CH = KM/4;
  for (int c = t; c < 64*CH; c += 256){
    int m = c / CH, j4 = c % CH;
    uint2 v = make_uint2(0u,0u);
    if (m < me && j4*4 < DIN) v = *(const uint2*)(x + (size_t)ssrc[m]*DIN + j4*4);
    *(uint2*)(xs + m*SR + j4*4) = v;
  }
  __syncthreads();

  int lane = t & 63, w = t >> 6;
  int n_idx = lane & 15, quad = lane >> 4;
  const short8* wpk8 = (const short8*)wpk;
  for (int mt=0; mt<4; mt++){
    short8 a[KS];
    const bf16* abase = xs + (size_t)(mt*16 + n_idx)*SR + quad*8;
    #pragma unroll
    for (int ks=0; ks<KS; ks++) a[ks] = *(const short8*)(abase + ks*32);
    int m = mt*16 + n_idx;              // edge row within block
    for (int nt=w; nt<13; nt+=4){
      const short8* bp = wpk8 + (((size_t)r*KS)*13 + nt)*64 + lane;
      f32x4 acc = {0.f,0.f,0.f,0.f};
      #pragma unroll
      for (int ks=0; ks<KS; ks++){
        short8 b = bp[(size_t)ks*13*64];
        acc = __builtin_amdgcn_mfma_f32_16x16x32_bf16(b, a[ks], acc, 0, 0, 0);  // D = W^T x^T
      }
      int nbase = nt*16 + quad*4;
      if (nbase < 200 && m < me){
        if (mode == 0){
          #pragma unroll
          for (int reg=0; reg<4; reg++){
            int n = nbase + reg;
            atomicAdd(&msg[(size_t)sdst[m]*200 + n], acc[reg] * alpha_s[m*4 + n/50]);
          }
        } else {
          ushort4 pk;
          { int n=nbase;   pk.x = f2bu(acc[0] * alpha_s[m*4 + n/50]); }
          { int n=nbase+1; pk.y = f2bu(acc[1] * alpha_s[m*4 + n/50]); }
          { int n=nbase+2; pk.z = f2bu(acc[2] * alpha_s[m*4 + n/50]); }
          { int n=nbase+3; pk.w = f2bu(acc[3] * alpha_s[m*4 + n/50]); }
          *(ushort4*)(fbuf + ((size_t)r*nEpad + ls0 + m)*200 + nbase) = pk;
        }
      }
    }
  }
}

// ---- gather: per dst, 17 contiguous slot runs; msg written once -------------
__global__ __launch_bounds__(256) void k_gather2(const bf16* __restrict__ F, const unsigned* __restrict__ offs,
                                                 float* __restrict__ msg, int nd){
  int w = threadIdx.x >> 6, lane = threadIdx.x & 63;
  int d = blockIdx.x*4 + w;
  if (d >= nd) return;
  if (lane < 50){
    float a0=0.f, a1=0.f, a2=0.f, a3=0.f;
    for (int r=0; r<NET; r++){
      unsigned k0 = offs[(size_t)r*(nd+1) + d];
      unsigned k1 = offs[(size_t)r*(nd+1) + d + 1];
      for (unsigned k=k0; k<k1; k++){
        ushort4 v = *(const ushort4*)(F + (size_t)k*200 + lane*4);
        a0 += bs2f(v.x); a1 += bs2f(v.y); a2 += bs2f(v.z); a3 += bs2f(v.w);
      }
    }
    float4 o; o.x=a0; o.y=a1; o.z=a2; o.w=a3;
    *(float4*)(msg + (size_t)d*200 + lane*4) = o;
  }
}

__global__ __launch_bounds__(256) void k_bgs(const bf16* bg0, const bf16* bg1, float* bgs0, float* bgs1){
  int j = blockIdx.x*256 + threadIdx.x;
  if (j < DIM){ float s=0.f; for(int r=0;r<NET;r++) s += b2f(bg0[r*DIM+j]); bgs0[j]=s; }
  else if (j < 2*DIM){ int jj=j-DIM; float s=0.f; for(int r=0;r<NET;r++) s += b2f(bg1[r*DIM+jj]); bgs1[jj]=s; }
}

__global__ __launch_bounds__(256) void k_build_x0(const int* nid0, const int* ts_p, const bf16* emb,
                                                  const bf16* tf, const bf16* tp, bf16* x0){
  long idx = (long)blockIdx.x*256 + threadIdx.x;
  if (idx >= (long)N0*DIN0) return;
  int n = idx / DIN0, j = idx % DIN0;
  int nid = nid0[n];
  bf16 v;
  if (j < DIME) v = emb[(size_t)(nid % NUME)*DIME + j];
  else {
    float t = (float)(ts_p[0] - nid / NUME);
    int jj = j - DIME;
    v = f2b(cosf(t * b2f(tf[jj]) + b2f(tp[jj])));
  }
  x0[idx] = v;
}

__global__ __launch_bounds__(256) void k_build_x1(const int* nid0, const int* ts_p, const float* msg0,
                                                  const float* bgs0, const bf16* tf, const bf16* tp, bf16* x1){
  long idx = (long)blockIdx.x*256 + threadIdx.x;
  if (idx >= (long)N1*DIN1) return;
  int n = idx / DIN1, j = idx % DIN1;
  bf16 v;
  if (j < DIM){
    v = f2b(fmaxf((msg0[(size_t)n*DIM + j] + bgs0[j]) * (1.0f/NET), 0.0f));
  } else {
    int nid = nid0[n];
    float t = (float)(ts_p[0] - nid / NUME);
    int jj = j - DIM;
    v = f2b(cosf(t * b2f(tf[jj]) + b2f(tp[jj])));
  }
  x1[idx] = v;
}

__global__ __launch_bounds__(256) void k_hid(const float* msg1, const float* bgs1, const int* root_idx, float* hid){
  long idx = (long)blockIdx.x*256 + threadIdx.x;
  if (idx >= (long)NROWS*HD) return;
  int b = idx / HD, c = idx % HD;
  int s = c / DIM, j = c % DIM;
  int n = root_idx[b*4 + s];
  hid[idx] = fmaxf((msg1[(size_t)n*DIM + j] + bgs1[j]) * (1.0f/NET), 0.0f);
}

// fused: ln0 -> q/v -> attention -> relu -> ln1 -> x3 (one row per block)
__global__ __launch_bounds__(256) void k_att_ln(const float* __restrict__ hid,
                                                const bf16* ln0w, const bf16* ln0b,
                                                const bf16* Wq, const bf16* bq,
                                                const bf16* Wv, const bf16* bv,
                                                const bf16* ln1w, const bf16* ln1b,
                                                float* __restrict__ x3){
  __shared__ float xs[HD], qs[HD], vs[HD], att_s[64], red[16];
  __shared__ float mu_s, rs_s;
  int b = blockIdx.x, t = threadIdx.x;
  int lane = t & 63, wid = t >> 6;
  const float* xr = hid + (size_t)b*HD;
  float s=0.f, s2=0.f;
  for (int j=t;j<HD;j+=256){ float v=xr[j]; s+=v; s2+=v*v; }
  for (int off=32; off; off>>=1){ s += __shfl_down(s,off); s2 += __shfl_down(s2,off); }
  if (lane==0){ red[wid]=s; red[8+wid]=s2; }
  __syncthreads();
  if (t==0){
    float S = red[0]+red[1]+red[2]+red[3];
    float S2 = red[8]+red[9]+red[10]+red[11];
    float mu = S * (1.0f/HD);
    float var = fmaxf(S2 * (1.0f/HD) - mu*mu, 0.f);
    mu_s = mu; rs_s = rsqrtf(var + 1e-5f);
  }
  __syncthreads();
  { float mu=mu_s, rs=rs_s;
    for (int j=t;j<HD;j+=256) xs[j] = (xr[j]-mu)*rs*b2f(ln0w[j]) + b2f(ln0b[j]); }
  __syncthreads();
  for (int idx=t; idx<HD; idx+=256){
    int ha = idx/200, srow=(idx%200)/50, o=idx%50;
    const float* xrow = xs + srow*200;
    const bf16* wq = Wq + (size_t)ha*DIM*OA + o;
    const bf16* wv = Wv + (size_t)ha*DIM*OA + o;
    float q=0.f, v=0.f;
    for (int e=0;e<DIM;e++){ float xv=xrow[e]; q += xv*b2f(wq[(size_t)e*OA]); v += xv*b2f(wv[(size_t)e*OA]); }
    qs[idx] = q + b2f(bq[ha*OA+o]);
    vs[idx] = v + b2f(bv[ha*OA+o]);
  }
  __syncthreads();
  if (t < 64){
    int ha=t>>4, srow=(t>>2)&3, tt=t&3;
    const float* qa = qs + ha*200 + srow*50;
    const float* qb = qs + ha*200 + tt*50;
    float sc=0.f;
    for (int o=0;o<50;o++) sc += qa[o]*qb[o];
    att_s[ha*16 + srow*4 + tt] = sc;
  }
  __syncthreads();
  if (t < 16){
    int ha=t>>2, tt=t&3;
    float m=-1e30f;
    for (int srow=0;srow<4;srow++) m = fmaxf(m, att_s[ha*16+srow*4+tt]);
    float ex[4]; float zz=0.f;
    for (int srow=0;srow<4;srow++){ ex[srow]=expf(att_s[ha*16+srow*4+tt]-m); zz+=ex[srow]; }
    for (int srow=0;srow<4;srow++) att_s[ha*16+srow*4+tt] = ex[srow]/zz;
  }
  __syncthreads();
  for (int idx=t; idx<HD; idx+=256){
    int ha = idx/200, srow=(idx%200)/50, o=idx%50;
    float a=0.f;
    for (int tt=0;tt<4;tt++) a += att_s[ha*16+srow*4+tt]*vs[ha*200+tt*50+o];
    xs[srow*200 + ha*50 + o] = fmaxf(a, 0.f);
  }
  __syncthreads();
  s=0.f; s2=0.f;
  for (int j=t;j<HD;j+=256){ float v=xs[j]; s+=v; s2+=v*v; }
  for (int off=32; off; off>>=1){ s += __shfl_down(s,off); s2 += __shfl_down(s2,off); }
  if (lane==0){ red[wid]=s; red[8+wid]=s2; }
  __syncthreads();
  if (t==0){
    float S = red[0]+red[1]+red[2]+red[3];
    float S2 = red[8]+red[9]+red[10]+red[11];
    float mu = S * (1.0f/HD);
    float var = fmaxf(S2 * (1.0f/HD) - mu*mu, 0.f);
    mu_s = mu; rs_s = rsqrtf(var + 1e-5f);
  }
  __syncthreads();
  { float mu=mu_s, rs=rs_s;
    for (int j=t;j<HD;j+=256) x3[(size_t)b*HD + j] = (xs[j]-mu)*rs*b2f(ln1w[j]) + b2f(ln1b[j]); }
}

__global__ __launch_bounds__(256) void k_d1(const float* x3, const bf16* Wd1, const bf16* bd1, float* x4){
  __shared__ float xs[8*HD];
  int rb = blockIdx.x*8, t = threadIdx.x;
  for (int idx=t; idx<8*HD; idx+=256) xs[idx] = x3[(size_t)rb*HD + idx];
  __syncthreads();
  if (t < DIM){
    float acc[8] = {0,0,0,0,0,0,0,0};
    for (int k=0;k<HD;k++){
      float w = b2f(Wd1[(size_t)k*DIM + t]);
      #pragma unroll
      for (int r=0;r<8;r++) acc[r] += xs[r*HD+k]*w;
    }
    float bb = b2f(bd1[t]);
    for (int r=0;r<8;r++) x4[(size_t)(rb+r)*DIM + t] = fmaxf(acc[r]+bb, 0.f);
  }
}

__global__ __launch_bounds__(256) void k_pack_pred(const void* Wsub, const void* Wobj, bf16* wpkP,
                                                    const unsigned* flagp){
  long idx = (long)blockIdx.x*256 + threadIdx.x;
  long total = (long)2*PKS*PNT*512;
  if (idx >= total) return;
  int j = (int)(idx & 7), lane = (int)((idx>>3) & 63);
  long rem = idx >> 9;
  int ntile = (int)(rem % PNT); rem /= PNT;
  int ks = (int)(rem % PKS); int page = (int)(rem / PKS);
  int k = ks*32 + (lane>>4)*8 + j;
  int n = ntile*16 + (lane&15);
  const void* W = page ? Wobj : Wsub;
  bool f32m = flagp[0] != 0u;
  float v = 0.f;
  if (k < 300) v = f32m ? ((const float*)W)[(size_t)k*NUME + n]
                        : b2f(((const bf16*)W)[(size_t)k*NUME + n]);
  wpkP[idx] = f2b(v);
}

__global__ __launch_bounds__(256) void k_prep_pred(const float* x4, const bf16* nSrel, const bf16* nOrel,
                                                    const int* rel, bf16* Apack){
  long idx = (long)blockIdx.x*256 + threadIdx.x;
  if (idx >= (long)2*1024*320) return;
  int j = (int)(idx % 320); long rem = idx/320;
  int row = (int)(rem % 1024); int page = (int)(rem / 1024);
  float v = 0.f;
  if (j < 200) v = x4[((size_t)(page==0 ? 1024+row : row))*DIM + j];
  else if (j < 300){
    const bf16* re = (page==0) ? nOrel : nSrel;
    v = b2f(re[(size_t)rel[row]*DIMR + (j-200)]);
  }
  Apack[idx] = f2b(v);
}

__global__ __launch_bounds__(256) void k_pred_mfma(const bf16* __restrict__ Apack, const bf16* __restrict__ wpkP,
                                                   const bf16* bsub, const bf16* bobj, void* outb,
                                                   const unsigned* flagp){
  constexpr int SR = 320 + 8;
  __shared__ bf16 As[64*SR];
  int page = blockIdx.z;
  int rb = blockIdx.y*64;
  int cb = blockIdx.x*16;
  int t = threadIdx.x;
  const bf16* Ap = Apack + (size_t)page*1024*320;
  for (int c=t; c<64*80; c+=256){
    int m=c/80, j4=c%80;
    *(uint2*)(As + m*SR + j4*4) = *(const uint2*)(Ap + (size_t)(rb+m)*320 + j4*4);
  }
  __syncthreads();
  int lane = t&63, w = t>>6;
  int n_idx = lane&15, quad = lane>>4;
  const short8* wp8 = (const short8*)(wpkP + (size_t)page*PKS*PNT*512);
  f32x4 acc[4][4];
  #pragma unroll
  for (int i=0;i<4;i++)
    #pragma unroll
    for (int mt=0;mt<4;mt++) acc[i][mt] = (f32x4){0.f,0.f,0.f,0.f};
  short8 bz = {0,0,0,0,0,0,0,0};
  for (int ks=0; ks<PKS; ks++){
    short8 bfr[4];
    #pragma unroll
    for (int i=0;i<4;i++){
      int ntile = cb + w + 4*i;
      bfr[i] = (ntile < PNT) ? wp8[((size_t)ks*PNT + ntile)*64 + lane] : bz;
    }
    short8 afr[4];
    #pragma unroll
    for (int mt=0;mt<4;mt++) afr[mt] = *(const short8*)(As + (size_t)(mt*16 + n_idx)*SR + ks*32 + quad*8);
    #pragma unroll
    for (int i=0;i<4;i++)
      #pragma unroll
      for (int mt=0;mt<4;mt++)
        acc[i][mt] = __builtin_amdgcn_mfma_f32_16x16x32_bf16(afr[mt], bfr[i], acc[i][mt], 0, 0, 0);
  }
  bool f32m = flagp[0] != 0u;
  const bf16* bias = page ? bobj : bsub;
  size_t elem_off = (size_t)page*BQ*NUME;
  for (int i=0;i<4;i++){
    int ntile = cb + w + 4*i;
    if (ntile >= PNT) continue;
    int n = ntile*16 + n_idx;
    float bb = b2f(bias[n]);
    #pragma unroll
    for (int mt=0;mt<4;mt++){
      #pragma unroll
      for (int reg=0;reg<4;reg++){
        int m = rb + mt*16 + quad*4 + reg;
        size_t oi = elem_off + (size_t)m*NUME + n;
        float val = acc[i][mt][reg] + bb;
        if (f32m) ((float*)outb)[oi] = val; else ((bf16*)outb)[oi] = f2b(val);
      }
    }
  }
}

// scalar fallback pred
__global__ __launch_bounds__(256) void k_pred(const float* xemb, const bf16* relemb, const int* rel,
                                              const void* W, const bf16* bias, void* outb, size_t elem_off,
                                              const unsigned* flagp){
  __shared__ float As[16*304];
  bool f32m = flagp[0] != 0u;
  int rb = blockIdx.y*16;
  int cb = blockIdx.x*512;
  int t = threadIdx.x;
  for (int idx=t; idx<16*300; idx+=256){
    int r = idx/300, i = idx%300;
    int row = rb + r;
    float v = (i < DIM) ? xemb[(size_t)row*DIM + i]
                        : b2f(relemb[(size_t)rel[row]*DIMR + (i-DIM)]);
    As[r*304+i] = v;
  }
  __syncthreads();
  int c0 = cb + t, c1 = cb + 256 + t;
  bool g0 = c0 < NUME, g1 = c1 < NUME;
  float acc0[16], acc1[16];
  #pragma unroll
  for (int r=0;r<16;r++){ acc0[r]=0.f; acc1[r]=0.f; }
  if (f32m){
    const float* W32 = (const float*)W;
    for (int k=0;k<300;k++){
      float w0 = g0 ? W32[(size_t)k*NUME + c0] : 0.f;
      float w1 = g1 ? W32[(size_t)k*NUME + c1] : 0.f;
      #pragma unroll
      for (int r=0;r<16;r++){ float a = As[r*304+k]; acc0[r] += a*w0; acc1[r] += a*w1; }
    }
  } else {
    const bf16* W16 = (const bf16*)W;
    for (int k=0;k<300;k++){
      float w0 = g0 ? b2f(W16[(size_t)k*NUME + c0]) : 0.f;
      float w1 = g1 ? b2f(W16[(size_t)k*NUME + c1]) : 0.f;
      #pragma unroll
      for (int r=0;r<16;r++){ float a = As[r*304+k]; acc0[r] += a*w0; acc1[r] += a*w1; }
    }
  }
  #pragma unroll
  for (int rr=0; rr<2; rr++){
    int c = rr ? c1 : c0;
    float* acc = rr ? acc1 : acc0;
    if (c < NUME){
      float bb = b2f(bias[c]);
      for (int r=0;r<16;r++){
        size_t oi = elem_off + (size_t)(rb+r)*NUME + c;
        float val = acc[r] + bb;
        if (f32m) ((float*)outb)[oi] = val; else ((bf16*)outb)[oi] = f2b(val);
      }
    }
  }
}

__global__ __launch_bounds__(256) void k_transpose(const void* in, bf16* out, int rows, int cols,
                                                   const unsigned* flagp){
  __shared__ bf16 tile[32][33];
  bool f32m = flagp[0] != 0u;
  int c0 = blockIdx.x*32, r0 = blockIdx.y*32;
  int tx = threadIdx.x % 32, ty = threadIdx.x / 32;
  for (int rr=ty; rr<32; rr+=8){
    int r = r0+rr, c = c0+tx;
    if (r<rows && c<cols){
      size_t i = (size_t)r*cols + c;
      tile[rr][tx] = f32m ? f2b(((const float*)in)[i]) : ((const bf16*)in)[i];
    }
  }
  __syncthreads();
  for (int rr=ty; rr<32; rr+=8){
    int ocol = c0+rr, orow = r0+tx;
    if (ocol<cols && orow<rows) out[(size_t)ocol*rows + orow] = tile[tx][rr];
  }
}

__global__ __launch_bounds__(256) void k_scatter(const int* copy_rows, const int* copy_cols, const int* rel,
                                                 const float* hid, const bf16* csrel, const bf16* corel,
                                                 const bf16* cWsubT, const bf16* cWobjT,
                                                 const bf16* cbsub, const bf16* cbobj,
                                                 void* outb, const unsigned* flagp){
  bool f32m = flagp[0] != 0u;
  int wid = threadIdx.x >> 6, lane = threadIdx.x & 63;
  long k = (long)blockIdx.x*4 + wid;
  if (k >= KK) return;
  int row = copy_rows[k], col = copy_cols[k];
  const float* chrow; const bf16* re; const bf16* wt; float bias_v;
  if (row < BQ){
    chrow = hid + ((size_t)(BQ+row))*HD + 600;
    re = corel + (size_t)rel[row]*DIMR;
    wt = cWsubT + (size_t)col*300;
    bias_v = b2f(cbsub[col]);
  } else {
    int rr = row - BQ;
    chrow = hid + ((size_t)rr)*HD + 600;
    re = csrel + (size_t)rel[rr]*DIMR;
    wt = cWobjT + (size_t)col*300;
    bias_v = b2f(cbobj[col]);
  }
  float s = 0.f;
  for (int i=lane; i<300; i+=64){
    float a = (i < DIM) ? chrow[i] : b2f(re[i-DIM]);
    s += a * b2f(wt[i]);
  }
  for (int off=32; off; off>>=1) s += __shfl_down(s, off);
  if (lane==0){
    size_t oi = (size_t)2*BQ*NUME + (size_t)row*NUME + col;
    float val = s + bias_v;
    if (f32m) ((float*)outb)[oi] = val; else ((bf16*)outb)[oi] = f2b(val);
  }
}

static inline dim3 GS(long n){ return dim3((unsigned)((n + 255)/256)); }

extern "C" void kernel_launch(void* const* d_in, const int* in_sizes, int n_in,
                              void* d_out, int out_size, void* d_ws, size_t ws_size,
                              hipStream_t stream){
  const int* rel       = (const int*)d_in[2];
  const int* ts_p      = (const int*)d_in[3];
  const int* nid0      = (const int*)d_in[4];
  const int* root_idx  = (const int*)d_in[5];
  const int* src0      = (const int*)d_in[6];
  const int* dst0      = (const int*)d_in[7];
  const int* src1      = (const int*)d_in[8];
  const int* dst1      = (const int*)d_in[9];
  const int* copy_rows = (const int*)d_in[10];
  const int* copy_cols = (const int*)d_in[11];
  const void* Wsub  = d_in[35];
  const void* Wobj  = d_in[37];
  const void* cWsub = d_in[41];
  const void* cWobj = d_in[43];

  // ---- workspace layout ----
  char* base = (char*)d_ws;
  size_t off = 0;
  auto alloc = [&](size_t bytes)->char*{
    char* p = base + off; off = (off + bytes + 255) & ~(size_t)255; return p;
  };
  unsigned* flagp = (unsigned*)alloc(256);
  long cvt_total = 0; for (int i=0;i<CVT_NREG;i++) cvt_total += CVT_N[i];
  bf16* normb = (bf16*)alloc((size_t)cvt_total*2);
  bf16* x0    = (bf16*)alloc((size_t)N0*DIN0*2);
  bf16* x1    = (bf16*)alloc((size_t)N1*DIN1*2);
  float* msg0 = (float*)alloc((size_t)N1*DIM*4);
  float* wal0 = (float*)alloc((size_t)NET*DIN0*4*4);
  float* war0 = (float*)alloc((size_t)NET*DIN0*4*4);
  float* wal1 = (float*)alloc((size_t)NET*DIN1*4*4);
  float* war1 = (float*)alloc((size_t)NET*DIN1*4*4);
  float* bgs0 = (float*)alloc(DIM*4);
  float* bgs1 = (float*)alloc(DIM*4);
  bf16* wpk0  = (bf16*)alloc((size_t)NET*4*13*512*2);
  bf16* wpk1  = (bf16*)alloc((size_t)NET*8*13*512*2);
  bf16* wpkE0 = (bf16*)alloc((size_t)4*9*512*2);
  bf16* wpkE1 = (bf16*)alloc((size_t)8*9*512*2);
  size_t arena = off;
  // phase-1 (GAT layer 0)
  char* P1 = base + arena;
  bf16*  a0b = (bf16*)P1;                                   // NET*E0*8
  float* z0  = (float*)(P1 + (size_t)NET*E0*8);             // NET*N1*16
  size_t ext1 = (size_t)NET*E0*8 + (size_t)NET*N1*16;
  // phase-2 (layer 1 + tail) — overlays phase-1
  char* A = base + arena;
  bf16*  a1b  = (bf16*)A;
  float* z1   = (float*)(A + (size_t)NET*E1*8);
  size_t msg1_off = (size_t)NET*E1*8 + (size_t)NET*RNODES*16;
  float* msg1 = (float*)(A + msg1_off);
  size_t hid_off = msg1_off + (size_t)RNODES*DIM*4;
  float* hid  = (float*)(A + hid_off);
  size_t x3_off = hid_off + (size_t)NROWS*HD*4;
  float* x3   = (float*)(A + x3_off);
  float* x4   = (float*)(A + x3_off + (size_t)NROWS*HD*4);
  size_t ext2 = x3_off + (size_t)NROWS*HD*4 + (size_t)NROWS*DIM*4;
  bf16* cWsubT = (bf16*)x0;
  bf16* cWobjT = (bf16*)((char*)x0 + (size_t)NUME*300*2);

  // ---- tail region: CSR + F buffers ----
  size_t extmax = ext1 > ext2 ? ext1 : ext2;
  size_t tail = (arena + extmax + 255) & ~(size_t)255;
  size_t cnt_sz  = (((size_t)NET*N1*4) + 255) & ~(size_t)255;
  size_t offs_sz = (((size_t)NET*(N1+1)*4) + 255) & ~(size_t)255;
  size_t ids_sz  = (((size_t)NET*E0PAD*4) + 255) & ~(size_t)255;
  unsigned* cnt  = (unsigned*)(base + tail);
  unsigned* offs = (unsigned*)(base + tail + cnt_sz);
  unsigned* cur  = (unsigned*)(base + tail + cnt_sz + offs_sz);
  int* ids = (int*)(base + tail + cnt_sz + 2*offs_sz);
  size_t F_off = tail + cnt_sz + 2*offs_sz + ids_sz;
  bf16* fbuf = (bf16*)(base + F_off);
  size_t fcap = (ws_size > F_off) ? (ws_size - F_off) : 0;
  bool sortok0 = fcap >= (size_t)NET*E0PAD*400;
  bool sortok1 = fcap >= (size_t)NET*E1PAD*400;
  // node-relation tables alias fbuf (dead before fbuf writes begin)
  float* tab0 = (float*)fbuf;
  float* tab1 = (float*)fbuf;
  bool elrok0 = fcap >= (size_t)N0*TABW*4;
  bool elrok1 = fcap >= (size_t)N1*TABW*4;
  // legacy er scratch (fallback only)
  bf16* er0f = (bf16*)x1;
  bf16* er1f = (bf16*)x0;
  // pred MFMA buffers alias fbuf (dead after last gather)
  size_t wpkP_sz = (size_t)2*PKS*PNT*512*2;
  size_t Apack_sz = (size_t)2*1024*320*2;
  bf16* wpkP  = (bf16*)(base + F_off);
  bf16* Apack = (bf16*)(base + F_off + wpkP_sz);
  bool predok = fcap >= (wpkP_sz + Apack_sz);

  long cum[CVT_NREG+1]; cum[0]=0;
  for (int i=0;i<CVT_NREG;i++) cum[i+1] = cum[i] + CVT_N[i];
  auto NP = [&](int i)->const bf16*{ return normb + cum[i]; };
  const bf16 *nEmb=NP(0), *nTf=NP(1), *nTp=NP(2), *nWg0=NP(3), *nAl0=NP(4), *nAr0=NP(5), *nBg0=NP(6),
             *nWg1=NP(7), *nAl1=NP(8), *nAr1=NP(9), *nBg1=NP(10), *nLn0w=NP(11), *nLn0b=NP(12),
             *nWq=NP(13), *nBq=NP(14), *nWv=NP(15), *nBv=NP(16), *nLn1w=NP(17), *nLn1b=NP(18),
             *nWd1=NP(19), *nBd1=NP(20), *nSrel=NP(21), *nOrel=NP(22), *nBsub=NP(23), *nBobj=NP(24),
             *nCsrel=NP(25), *nCorel=NP(26), *nCbsub=NP(27), *nCbobj=NP(28);

  // ---- phase 0 ----
  k_detect<<<dim3(1),64,0,stream>>>((const unsigned*)d_in[13], flagp);
  CvtSrcs srcs;
  for (int i=0;i<CVT_NREG;i++) srcs.p[i] = d_in[CVT_DIN[i]];
  CvtMeta meta;
  { int c=0, bc=0;
    for (int i=0;i<CVT_NREG;i++){ meta.cum[i]=c; meta.bcum[i]=bc; c+=CVT_N[i]; bc += (CVT_N[i]+255)/256; }
    meta.cum[CVT_NREG]=c; meta.bcum[CVT_NREG]=bc;
    k_cvt<<<dim3((unsigned)bc),256,0,stream>>>(srcs, meta, normb, flagp);
  }
  k_fill_u32<<<GS((long)NET*N1*4),256,0,stream>>>((unsigned*)z0, 0u, (long)NET*N1*4);
  k_fill_out<<<GS((long)2*BQ*NUME),256,0,stream>>>(d_out, flagp);
  k_prep_w<<<GS(NET*DIN0*4),256,0,stream>>>(nWg0, nAl0, nAr0, wal0, war0, DIN0);
  k_prep_w<<<GS(NET*DIN1*4),256,0,stream>>>(nWg1, nAl1, nAr1, wal1, war1, DIN1);
  k_pack<<<GS((long)NET*4*13*512),256,0,stream>>>(nWg0, wpk0, DIN0, 4);
  k_pack<<<GS((long)NET*8*13*512),256,0,stream>>>(nWg1, wpk1, DIN1, 8);
  k_pack_walr<<<GS((long)4*9*512),256,0,stream>>>(wal0, war0, wpkE0, DIN0, 4);
  k_pack_walr<<<GS((long)8*9*512),256,0,stream>>>(wal1, war1, wpkE1, DIN1, 8);
  k_bgs<<<GS(2*DIM),256,0,stream>>>(nBg0, nBg1, bgs0, bgs1);
  k_build_x0<<<GS((long)N0*DIN0),256,0,stream>>>(nid0, ts_p, nEmb, nTf, nTp, x0);

  // ---- GAT layer 0: edge logits ----
  if (elrok0){
    k_elr<DIN0,4><<<dim3(N0/64),256,0,stream>>>(x0, wpkE0, tab0);
    k_edge_lite<<<GS((long)NET*E0),256,0,stream>>>(tab0, src0, dst0, a0b, z0, E0, N1);
  } else {
    k_er<DIN0><<<GS((long)NET*N1),256,0,stream>>>(x0, war0, er0f, N1);
    k_edge<DIN0><<<GS((long)NET*E0),256,0,stream>>>(x0, wal0, er0f, src0, dst0, a0b, z0, E0, N1);
  }
  // ---- GAT layer 0: message accumulate ----
  if (sortok0){
    k_fill_u32<<<GS((long)NET*N1),256,0,stream>>>(cnt, 0u, (long)NET*N1);
    k_count2<<<GS((long)NET*E0),256,0,stream>>>(dst0, E0, N1, cnt);
    k_scan2<<<dim3(NET),256,0,stream>>>(cnt, offs, cur, N1, E0, E0PAD);
    k_fillcsr2<<<GS((long)NET*E0),256,0,stream>>>(dst0, E0, N1, cur, ids);
    k_acc_mfma<DIN0,4><<<dim3((E0+63)/64, NET),256,0,stream>>>(x0, wpk0, a0b, z0, src0, dst0, ids,
                                                                msg0, fbuf, E0, E0PAD, N1, 1);
    k_gather2<<<dim3((N1+3)/4),256,0,stream>>>(fbuf, offs, msg0, N1);
  } else {
    k_fill_u32<<<GS((long)N1*DIM),256,0,stream>>>((unsigned*)msg0, 0u, (long)N1*DIM);
    k_acc_mfma<DIN0,4><<<dim3((E0+63)/64, NET),256,0,stream>>>(x0, wpk0, a0b, z0, src0, dst0, (int*)nullptr,
                                                                msg0, (bf16*)nullptr, E0, E0, N1, 0);
  }

  // ---- build x1, GAT layer 1 ----
  k_build_x1<<<GS((long)N1*DIN1),256,0,stream>>>(nid0, ts_p, msg0, bgs0, nTf, nTp, x1);
  k_fill_u32<<<GS((long)NET*RNODES*4),256,0,stream>>>((unsigned*)z1, 0u, (long)NET*RNODES*4);
  if (elrok1){
    k_elr<DIN1,8><<<dim3(N1/64),256,0,stream>>>(x1, wpkE1, tab1);
    k_edge_lite<<<GS((long)NET*E1),256,0,stream>>>(tab1, src1, dst1, a1b, z1, E1, RNODES);
  } else {
    k_er<DIN1><<<GS((long)NET*RNODES),256,0,stream>>>(x1, war1, er1f, RNODES);
    k_edge<DIN1><<<GS((long)NET*E1),256,0,stream>>>(x1, wal1, er1f, src1, dst1, a1b, z1, E1, RNODES);
  }
  if (sortok1){
    k_fill_u32<<<GS((long)NET*RNODES),256,0,stream>>>(cnt, 0u, (long)NET*RNODES);
    k_count2<<<GS((long)NET*E1),256,0,stream>>>(dst1, E1, RNODES, cnt);
    k_scan2<<<dim3(NET),256,0,stream>>>(cnt, offs, cur, RNODES, E1, E1PAD);
    k_fillcsr2<<<GS((long)NET*E1),256,0,stream>>>(dst1, E1, RNODES, cur, ids);
    k_acc_mfma<DIN1,8><<<dim3((E1+63)/64, NET),256,0,stream>>>(x1, wpk1, a1b, z1, src1, dst1, ids,
                                                                msg1, fbuf, E1, E1PAD, RNODES, 1);
    k_gather2<<<dim3((RNODES+3)/4),256,0,stream>>>(fbuf, offs, msg1, RNODES);
  } else {
    k_fill_u32<<<GS((long)RNODES*DIM),256,0,stream>>>((unsigned*)msg1, 0u, (long)RNODES*DIM);
    k_acc_mfma<DIN1,8><<<dim3((E1+63)/64, NET),256,0,stream>>>(x1, wpk1, a1b, z1, src1, dst1, (int*)nullptr,
                                                                msg1, (bf16*)nullptr, E1, E1, RNODES, 0);
  }

  // ---- pred W pack (aliases fbuf — dead after last gather) ----
  if (predok)
    k_pack_pred<<<GS((long)2*PKS*PNT*512),256,0,stream>>>(Wsub, Wobj, wpkP, flagp);

  // ---- gather hid, copy-head scatter ----
  k_hid<<<GS((long)NROWS*HD),256,0,stream>>>(msg1, bgs1, root_idx, hid);
  k_transpose<<<dim3(625,10),256,0,stream>>>(cWsub, cWsubT, 300, NUME, flagp);
  k_transpose<<<dim3(625,10),256,0,stream>>>(cWobj, cWobjT, 300, NUME, flagp);
  k_scatter<<<dim3((KK+3)/4),256,0,stream>>>(copy_rows, copy_cols, rel, hid, nCsrel, nCorel,
                                             cWsubT, cWobjT, nCbsub, nCbobj, d_out, flagp);

  // ---- fused attention tail ----
  k_att_ln<<<dim3(NROWS),256,0,stream>>>(hid, nLn0w, nLn0b, nWq, nBq, nWv, nBv, nLn1w, nLn1b, x3);
  k_d1<<<dim3(NROWS/8),256,0,stream>>>(x3, nWd1, nBd1, x4);

  // ---- final predictions ----
  if (predok){
    k_prep_pred<<<GS((long)2*1024*320),256,0,stream>>>(x4, nSrel, nOrel, rel, Apack);
    k_pred_mfma<<<dim3(79,16,2),256,0,stream>>>(Apack, wpkP, nBsub, nBobj, d_out, flagp);
  } else {
    k_pred<<<dim3(40,64),256,0,stream>>>(x4 + (size_t)BQ*DIM, nOrel, rel, Wsub, nBsub, d_out, 0, flagp);
    k_pred<<<dim3(40,64),256,0,stream>>>(x4,                  nSrel, rel, Wobj, nBobj, d_out, (size_t)BQ*NUME, flagp);
  }
  (void)in_sizes; (void)n_in; (void)out_size; (void)ws_size;
}

// Round 6
// 2143.673 us; speedup vs baseline: 2.0561x; 1.0632x over previous
//
#include <hip/hip_runtime.h>
#include <hip/hip_bf16.h>
#include <math.h>

typedef __hip_bfloat16 bf16;
typedef __attribute__((ext_vector_type(8))) short short8;
typedef __attribute__((ext_vector_type(4))) float f32x4;

#define BQ 1024
#define NUME 20000
#define NET 17
#define DIMT 28
#define DIME 100
#define DIM 200
#define HEADS 4
#define OH 50
#define N0 160000
#define N1 40000
#define RNODES 8192
#define E0 60000
#define E1 16000
#define KK 500000
#define DIMR 100
#define HATT 4
#define OA 50
#define DIN0 128
#define DIN1 228
#define HD 800
#define NROWS 2048
#define PKS 10
#define PNT 1250
#define TABW 136   // 17 relations * (4 wal + 4 war)
#define E0PAD 60032
#define E1PAD 16000

__device__ __forceinline__ float b2f(bf16 v){ return __bfloat162float(v); }
__device__ __forceinline__ bf16 f2b(float v){ return __float2bfloat16(v); }
__device__ __forceinline__ float bs2f(unsigned short u){ return __uint_as_float((unsigned)u << 16); }
__device__ __forceinline__ unsigned short f2bu(float v){ bf16 t = f2b(v); return *reinterpret_cast<unsigned short*>(&t); }

// ---- dtype normalization ----------------------------------------------------
static constexpr int CVT_NREG = 29;
static constexpr int CVT_N[CVT_NREG] = {
  2000000, 28, 28, 435200, 3400, 3400, 3400, 775200, 3400, 3400, 3400,
  800, 800, 40000, 200, 40000, 200, 800, 800, 160000, 200, 800, 800,
  20000, 20000, 800, 800, 20000, 20000
};
static constexpr int CVT_DIN[CVT_NREG] = {
  12,13,14,15,16,17,18,19,20,21,22,23,24,25,26,27,28,29,30,31,32,33,34,36,38,39,40,42,44
};
struct CvtSrcs { const void* p[CVT_NREG]; };
struct CvtMeta { int cum[CVT_NREG+1]; int bcum[CVT_NREG+1]; };

__global__ __launch_bounds__(64) void k_detect(const unsigned* tfw, unsigned* flag){
  if (threadIdx.x == 0) flag[0] = ((tfw[0] & 0xFFFFu) == 0u) ? 1u : 0u;
}

__global__ __launch_bounds__(256) void k_cvt(CvtSrcs srcs, CvtMeta meta, bf16* dst, const unsigned* flagp){
  int b = blockIdx.x;
  int r = 0;
  while (meta.bcum[r+1] <= b) r++;
  int i = (b - meta.bcum[r])*256 + threadIdx.x;
  int n = meta.cum[r+1] - meta.cum[r];
  if (i >= n) return;
  bool f32m = flagp[0] != 0u;
  bf16 v;
  if (f32m) v = f2b(((const float*)srcs.p[r])[i]);
  else      v = ((const bf16*)srcs.p[r])[i];
  dst[meta.cum[r] + i] = v;
}

__global__ __launch_bounds__(256) void k_fill_u32(unsigned* p, unsigned v, long n){
  long i = (long)blockIdx.x*256 + threadIdx.x;
  if (i < n) p[i] = v;
}

__global__ __launch_bounds__(256) void k_fill_out(void* outb, const unsigned* flagp){
  bool f32m = flagp[0] != 0u;
  long nwords = f32m ? (long)2*BQ*NUME : (long)BQ*NUME;
  long i = (long)blockIdx.x*256 + threadIdx.x;
  if (i >= nwords) return;
  unsigned* p = (unsigned*)((char*)outb + (size_t)2*BQ*NUME * (f32m ? 4 : 2));
  p[i] = f32m ? 0xC2C80000u : 0xC2C8C2C8u;
}

__global__ __launch_bounds__(256) void k_prep_w(const bf16* Wg, const bf16* al, const bf16* ar,
                                                float* wal, float* war, int DIN){
  int idx = blockIdx.x*256 + threadIdx.x;
  int total = NET*DIN*4;
  if (idx >= total) return;
  int h = idx & 3; int ri = idx >> 2; int i = ri % DIN; int r = ri / DIN;
  const bf16* wrow = Wg + ((size_t)(r*DIN + i))*HEADS*OH + h*OH;
  const bf16* alr = al + (size_t)(r*HEADS + h)*OH;
  const bf16* arr = ar + (size_t)(r*HEADS + h)*OH;
  float sl=0.f, sr=0.f;
  for (int o=0;o<OH;o++){ float w=b2f(wrow[o]); sl += w*b2f(alr[o]); sr += w*b2f(arr[o]); }
  wal[idx]=sl; war[idx]=sr;
}

// pack W into MFMA B-fragment order: wpk[((r*KS+ks)*13+nt)*512 + lane*8 + j]
__global__ __launch_bounds__(256) void k_pack(const bf16* Wg, bf16* wpk, int DIN, int KS){
  int idx = blockIdx.x*256 + threadIdx.x;
  int total = NET*KS*13*512;
  if (idx >= total) return;
  int j = idx & 7, lane = (idx>>3) & 63;
  int rem = idx >> 9;
  int nt = rem % 13, rks = rem / 13;
  int ks = rks % KS, r = rks / KS;
  int k = ks*32 + (lane>>4)*8 + j;
  int n = nt*16 + (lane&15);
  bf16 v = f2b(0.f);
  if (k < DIN && n < 200) v = Wg[((size_t)r*DIN + k)*200 + n];
  wpk[idx] = v;
}

// pack [wal|war] into fragment order [ks][nt(9)][lane][8]
__global__ __launch_bounds__(256) void k_pack_walr(const float* wal, const float* war, bf16* wpkE,
                                                   int DIN, int KS){
  int idx = blockIdx.x*256 + threadIdx.x;
  int total = KS*9*512;
  if (idx >= total) return;
  int j = idx & 7, lane = (idx>>3) & 63;
  int rem = idx >> 9;
  int nt = rem % 9, ks = rem / 9;
  int k = ks*32 + (lane>>4)*8 + j;
  int c = nt*16 + (lane&15);
  float v = 0.f;
  if (k < DIN && c < TABW){
    int r = c >> 3, q = c & 7;
    const float* wsrc = (q < 4) ? wal : war;
    v = wsrc[((size_t)r*DIN + k)*4 + (q & 3)];
  }
  wpkE[idx] = f2b(v);
}

// pack q|v weights: B[k][n] (K=200 pad 256, N=200 per gy): gy0=Wq, gy1=Wv; n=ha*50+o
__global__ __launch_bounds__(256) void k_pack_qv(const bf16* Wq, const bf16* Wv, bf16* wpkQV){
  int idx = blockIdx.x*256 + threadIdx.x;
  int total = 2*8*13*512;
  if (idx >= total) return;
  int j = idx & 7, lane = (idx>>3) & 63;
  int rem = idx >> 9;
  int nt = rem % 13; rem /= 13;
  int ks = rem % 8; int gy = rem / 8;
  int k = ks*32 + (lane>>4)*8 + j;
  int n = nt*16 + (lane&15);
  bf16 v = f2b(0.f);
  if (k < 200 && n < 200){
    const bf16* W = gy ? Wv : Wq;
    v = W[(size_t)(n/50)*10000 + (size_t)k*50 + (n%50)];
  }
  wpkQV[idx] = v;
}

// pack Wd1: B[k][n] (K=800 pad 896, N=200)
__global__ __launch_bounds__(256) void k_pack_d1(const bf16* Wd1, bf16* wpkD1){
  int idx = blockIdx.x*256 + threadIdx.x;
  int total = 28*13*512;
  if (idx >= total) return;
  int j = idx & 7, lane = (idx>>3) & 63;
  int rem = idx >> 9;
  int nt = rem % 13; int ks = rem / 13;
  int k = ks*32 + (lane>>4)*8 + j;
  int n = nt*16 + (lane&15);
  bf16 v = f2b(0.f);
  if (k < 800 && n < 200) v = Wd1[(size_t)k*200 + n];
  wpkD1[idx] = v;
}

// node-relation table GEMM: tab[m][c] = x[m] . walr[:,c]
template<int DIN, int KS>
__global__ __launch_bounds__(256) void k_elr(const bf16* __restrict__ x, const bf16* __restrict__ wpkE,
                                             float* __restrict__ tab){
  constexpr int KM = KS*32;
  constexpr int SR = KM + 8;
  __shared__ bf16 xs[64*SR];
  int rb = blockIdx.x*64;
  int t = threadIdx.x;
  constexpr int CH = KM/4;
  for (int c = t; c < 64*CH; c += 256){
    int m = c / CH, j4 = c % CH;
    uint2 v = make_uint2(0u,0u);
    if (j4*4 < DIN) v = *(const uint2*)(x + (size_t)(rb+m)*DIN + j4*4);
    *(uint2*)(xs + m*SR + j4*4) = v;
  }
  __syncthreads();
  int lane = t & 63, w = t >> 6;
  int n_idx = lane & 15, quad = lane >> 4;
  const short8* wp8 = (const short8*)wpkE;
  for (int mt=0; mt<4; mt++){
    short8 a[KS];
    const bf16* ab = xs + (size_t)(mt*16 + n_idx)*SR + quad*8;
    #pragma unroll
    for (int ks=0; ks<KS; ks++) a[ks] = *(const short8*)(ab + ks*32);
    int m = rb + mt*16 + n_idx;
    for (int nt=w; nt<9; nt+=4){
      const short8* bp = wp8 + (size_t)nt*64 + lane;
      f32x4 acc = {0.f,0.f,0.f,0.f};
      #pragma unroll
      for (int ks=0; ks<KS; ks++){
        short8 b = bp[(size_t)ks*9*64];
        acc = __builtin_amdgcn_mfma_f32_16x16x32_bf16(b, a[ks], acc, 0, 0, 0);
      }
      int nbase = nt*16 + quad*4;
      if (nbase < TABW){
        float4 o; o.x=acc[0]; o.y=acc[1]; o.z=acc[2]; o.w=acc[3];
        *(float4*)(tab + (size_t)m*TABW + nbase) = o;
      }
    }
  }
}

__global__ __launch_bounds__(256) void k_edge_lite(const float* __restrict__ tab,
                                                   const int* __restrict__ src, const int* __restrict__ dst,
                                                   bf16* abuf, float* z, int nE, int nd){
  int idx = blockIdx.x*256 + threadIdx.x;
  if (idx >= NET*nE) return;
  int r = idx / nE;
  int s = src[idx], d = dst[idx];
  float4 el = *(const float4*)(tab + (size_t)s*TABW + r*8);
  float4 er = *(const float4*)(tab + (size_t)d*TABW + r*8 + 4);
  float ev[4] = {el.x+er.x, el.y+er.y, el.z+er.z, el.w+er.w};
  float* zp = z + ((size_t)r*nd + d)*4;
  bf16* ao = abuf + (size_t)idx*4;
  #pragma unroll
  for (int h=0;h<4;h++){
    float v = ev[h];
    v = v>0.f ? v : 0.2f*v;
    float a = expf(fminf(v, 80.f));
    ao[h] = f2b(a);
    atomicAdd(&zp[h], a);
  }
}

// ---- legacy fallbacks (workspace-tight only) --------------------------------
template<int DIN>
__global__ __launch_bounds__(256) void k_er(const bf16* __restrict__ x, const float* __restrict__ war,
                                            bf16* __restrict__ er, int nd){
  int idx = blockIdx.x*256 + threadIdx.x;
  if (idx >= NET*nd) return;
  int r = idx / nd, n = idx % nd;
  const ushort4* xr = (const ushort4*)(x + (size_t)n*DIN);
  const float4* w = (const float4*)(war + (size_t)r*DIN*4);
  float a0=0.f,a1=0.f,a2=0.f,a3=0.f;
  #pragma unroll 4
  for (int i=0;i<DIN/4;i++){
    ushort4 xv = xr[i];
    float x0=bs2f(xv.x), x1=bs2f(xv.y), x2=bs2f(xv.z), x3=bs2f(xv.w);
    float4 w0=w[4*i], w1=w[4*i+1], w2=w[4*i+2], w3=w[4*i+3];
    a0 += x0*w0.x + x1*w1.x + x2*w2.x + x3*w3.x;
    a1 += x0*w0.y + x1*w1.y + x2*w2.y + x3*w3.y;
    a2 += x0*w0.z + x1*w1.z + x2*w2.z + x3*w3.z;
    a3 += x0*w0.w + x1*w1.w + x2*w2.w + x3*w3.w;
  }
  bf16* e = er + (size_t)idx*4;
  e[0]=f2b(a0); e[1]=f2b(a1); e[2]=f2b(a2); e[3]=f2b(a3);
}

template<int DIN>
__global__ __launch_bounds__(256) void k_edge(const bf16* __restrict__ x, const float* __restrict__ wal,
                                              const bf16* __restrict__ er,
                                              const int* __restrict__ src, const int* __restrict__ dst,
                                              bf16* abuf, float* z, int nE, int nd){
  int idx = blockIdx.x*256 + threadIdx.x;
  if (idx >= NET*nE) return;
  int r = idx / nE;
  int s = src[idx], d = dst[idx];
  const ushort4* xr = (const ushort4*)(x + (size_t)s*DIN);
  const float4* w = (const float4*)(wal + (size_t)r*DIN*4);
  float a0=0.f,a1=0.f,a2=0.f,a3=0.f;
  #pragma unroll 4
  for (int i=0;i<DIN/4;i++){
    ushort4 xv = xr[i];
    float x0=bs2f(xv.x), x1=bs2f(xv.y), x2=bs2f(xv.z), x3=bs2f(xv.w);
    float4 w0=w[4*i], w1=w[4*i+1], w2=w[4*i+2], w3=w[4*i+3];
    a0 += x0*w0.x + x1*w1.x + x2*w2.x + x3*w3.x;
    a1 += x0*w0.y + x1*w1.y + x2*w2.y + x3*w3.y;
    a2 += x0*w0.z + x1*w1.z + x2*w2.z + x3*w3.z;
    a3 += x0*w0.w + x1*w1.w + x2*w2.w + x3*w3.w;
  }
  float acc[4] = {a0,a1,a2,a3};
  const bf16* ern = er + ((size_t)r*nd + d)*4;
  float* zp = z + ((size_t)r*nd + d)*4;
  bf16* ao = abuf + (size_t)idx*4;
  #pragma unroll
  for (int h=0;h<4;h++){
    float v = acc[h] + b2f(ern[h]);
    v = v>0.f ? v : 0.2f*v;
    float a = expf(fminf(v, 80.f));
    ao[h] = f2b(a);
    atomicAdd(&zp[h], a);
  }
}

// ---- per-relation dst-sorted CSR -------------------------------------------
__global__ __launch_bounds__(256) void k_count2(const int* __restrict__ dst, int nE, int nd, unsigned* cnt){
  int i = blockIdx.x*256 + threadIdx.x;
  if (i >= NET*nE) return;
  int r = i / nE; int d = dst[i];
  atomicAdd(&cnt[(size_t)r*nd + d], 1u);
}

__global__ __launch_bounds__(256) void k_scan2(const unsigned* __restrict__ cnt, unsigned* offs, unsigned* cur,
                                               int nd, int nE, int nEpad){
  __shared__ unsigned part[256];
  int r = blockIdx.x, t = threadIdx.x;
  unsigned base = (unsigned)(r*nEpad);
  const unsigned* c = cnt + (size_t)r*nd;
  unsigned* o  = offs + (size_t)r*(nd+1);
  unsigned* cu = cur  + (size_t)r*(nd+1);
  int chunk = (nd + 255)/256;
  int lo = t*chunk, hi = lo+chunk; if (hi > nd) hi = nd; if (lo > nd) lo = nd;
  unsigned s = 0;
  for (int i=lo;i<hi;i++) s += c[i];
  part[t] = s;
  __syncthreads();
  if (t==0){ unsigned run=0; for (int i=0;i<256;i++){ unsigned v=part[i]; part[i]=run; run+=v; } }
  __syncthreads();
  unsigned run = base + part[t];
  for (int i=lo;i<hi;i++){ o[i]=run; cu[i]=run; run += c[i]; }
  if (t==0) o[nd] = base + (unsigned)nE;
}

__global__ __launch_bounds__(256) void k_fillcsr2(const int* __restrict__ dst, int nE, int nd,
                                                  unsigned* cur, int* ids){
  int i = blockIdx.x*256 + threadIdx.x;
  if (i >= NET*nE) return;
  int r = i / nE, e = i - r*nE;
  int d = dst[i];
  unsigned pos = atomicAdd(&cur[(size_t)r*(nd+1) + d], 1u);
  ids[pos] = e;
}

// ---- MFMA edge-GEMM ---------------------------------------------------------
// mode 1: block (bx,r) covers sorted slots; F rows staged per-mt in LDS then
// written as one contiguous coalesced span. mode 0: atomic scatter.
template<int DIN, int KS>
__global__ __launch_bounds__(256) void k_acc_mfma(const bf16* __restrict__ x, const bf16* __restrict__ wpk,
                                                  const bf16* __restrict__ abuf, const float* __restrict__ z,
                                                  const int* __restrict__ src, const int* __restrict__ dst,
                                                  const int* __restrict__ ids,
                                                  float* msg, bf16* fbuf, int nE, int nEpad, int nd, int mode){
  constexpr int KM = KS*32;
  constexpr int SR = KM + 8;
  __shared__ bf16 xs[64*SR];
  __shared__ bf16 fs[16*208];
  __shared__ float alpha_s[64*4];
  __shared__ int sdst[64], ssrc[64], sE[64];
  int r = blockIdx.y;
  int ls0 = blockIdx.x*64;
  int me = min(64, nE - ls0);
  int t = threadIdx.x;
  if (t < 64){
    int e = ls0 + t, vs=0, vd=0;
    if (t < me){
      if (mode == 1) e = ids[(size_t)r*nEpad + ls0 + t];
      vs = src[(size_t)r*nE + e];
      vd = dst[(size_t)r*nE + e];
    }
    sE[t]=e; ssrc[t]=vs; sdst[t]=vd;
  }
  __syncthreads();
  { // alpha per (edge, head)
    int m = t>>2, h = t&3;
    float al = 0.f;
    if (m < me){
      float a = b2f(abuf[((size_t)r*nE + sE[m])*4 + h]);
      float zz = z[((size_t)r*nd + sdst[m])*4 + h];
      al = a / fmaxf(zz, 1e-30f);
    }
    alpha_s[m*4+h] = al;
  }
  constexpr int CH = KM/4;
  for (int c = t; c < 64*CH; c += 256){
    int m = c / CH, j4 = c % CH;
    uint2 v = make_uint2(0u,0u);
    if (m < me && j4*4 < DIN) v = *(const uint2*)(x + (size_t)ssrc[m]*DIN + j4*4);
    *(uint2*)(xs + m*SR + j4*4) = v;
  }
  __syncthreads();

  int lane = t & 63, w = t >> 6;
  int n_idx = lane & 15, quad = lane >> 4;
  const short8* wpk8 = (const short8*)wpk;
  for (int mt=0; mt<4; mt++){
    short8 a[KS];
    const bf16* abase = xs + (size_t)(mt*16 + n_idx)*SR + quad*8;
    #pragma unroll
    for (int ks=0; ks<KS; ks++) a[ks] = *(const short8*)(abase + ks*32);
    int m = mt*16 + n_idx;              // edge row within block
    for (int nt=w; nt<13; nt+=4){
      const short8* bp = wpk8 + (((size_t)r*KS)*13 + nt)*64 + lane;
      f32x4 acc = {0.f,0.f,0.f,0.f};
      #pragma unroll
      for (int ks=0; ks<KS; ks++){
        short8 b = bp[(size_t)ks*13*64];
        acc = __builtin_amdgcn_mfma_f32_16x16x32_bf16(b, a[ks], acc, 0, 0, 0);  // D = W^T x^T
      }
      int nbase = nt*16 + quad*4;
      if (nbase < 200 && m < me){
        if (mode == 0){
          #pragma unroll
          for (int reg=0; reg<4; reg++){
            int n = nbase + reg;
            atomicAdd(&msg[(size_t)sdst[m]*200 + n], acc[reg] * alpha_s[m*4 + n/50]);
          }
        } else {
          ushort4 pk;
          { int n=nbase;   pk.x = f2bu(acc[0] * alpha_s[m*4 + n/50]); }
          { int n=nbase+1; pk.y = f2bu(acc[1] * alpha_s[m*4 + n/50]); }
          { int n=nbase+2; pk.z = f2bu(acc[2] * alpha_s[m*4 + n/50]); }
          { int n=nbase+3; pk.w = f2bu(acc[3] * alpha_s[m*4 + n/50]); }
          *(ushort4*)(fs + (size_t)n_idx*208 + nbase) = pk;
        }
      }
    }
    if (mode == 1){
      __syncthreads();
      // 400 work items, 256 threads: MUST grid-stride (round-5 bug: `if (t<400)`)
      for (int ii=t; ii<400; ii+=256){
        int rw = ii/25, cc = ii%25;
        *(uint4*)(fbuf + ((size_t)r*nEpad + ls0 + mt*16 + rw)*200 + cc*8) =
            *(const uint4*)(fs + (size_t)rw*208 + cc*8);
      }
      __syncthreads();
    }
  }
}

// ---- gather: per dst, 17 contiguous slot runs; msg written once -------------
__global__ __launch_bounds__(256) void k_gather2(const bf16* __restrict__ F, const unsigned* __restrict__ offs,
                                                 float* __restrict__ msg, int nd){
  int w = threadIdx.x >> 6, lane = threadIdx.x & 63;
  int d = blockIdx.x*4 + w;
  if (d >= nd) return;
  if (lane < 50){
    float a0=0.f, a1=0.f, a2=0.f, a3=0.f;
    for (int r=0; r<NET; r++){
      unsigned k0 = offs[(size_t)r*(nd+1) + d];
      unsigned k1 = offs[(size_t)r*(nd+1) + d + 1];
      for (unsigned k=k0; k<k1; k++){
        ushort4 v = *(const ushort4*)(F + (size_t)k*200 + lane*4);
        a0 += bs2f(v.x); a1 += bs2f(v.y); a2 += bs2f(v.z); a3 += bs2f(v.w);
      }
    }
    float4 o; o.x=a0; o.y=a1; o.z=a2; o.w=a3;
    *(float4*)(msg + (size_t)d*200 + lane*4) = o;
  }
}

__global__ __launch_bounds__(256) void k_bgs(const bf16* bg0, const bf16* bg1, float* bgs0, float* bgs1){
  int j = blockIdx.x*256 + threadIdx.x;
  if (j < DIM){ float s=0.f; for(int r=0;r<NET;r++) s += b2f(bg0[r*DIM+j]); bgs0[j]=s; }
  else if (j < 2*DIM){ int jj=j-DIM; float s=0.f; for(int r=0;r<NET;r++) s += b2f(bg1[r*DIM+jj]); bgs1[jj]=s; }
}

__global__ __launch_bounds__(256) void k_build_x0(const int* nid0, const int* ts_p, const bf16* emb,
                                                  const bf16* tf, const bf16* tp, bf16* x0){
  long idx = (long)blockIdx.x*256 + threadIdx.x;
  if (idx >= (long)N0*DIN0) return;
  int n = idx / DIN0, j = idx % DIN0;
  int nid = nid0[n];
  bf16 v;
  if (j < DIME) v = emb[(size_t)(nid % NUME)*DIME + j];
  else {
    float t = (float)(ts_p[0] - nid / NUME);
    int jj = j - DIME;
    v = f2b(cosf(t * b2f(tf[jj]) + b2f(tp[jj])));
  }
  x0[idx] = v;
}

__global__ __launch_bounds__(256) void k_build_x1(const int* nid0, const int* ts_p, const float* msg0,
                                                  const float* bgs0, const bf16* tf, const bf16* tp, bf16* x1){
  long idx = (long)blockIdx.x*256 + threadIdx.x;
  if (idx >= (long)N1*DIN1) return;
  int n = idx / DIN1, j = idx % DIN1;
  bf16 v;
  if (j < DIM){
    v = f2b(fmaxf((msg0[(size_t)n*DIM + j] + bgs0[j]) * (1.0f/NET), 0.0f));
  } else {
    int nid = nid0[n];
    float t = (float)(ts_p[0] - nid / NUME);
    int jj = j - DIM;
    v = f2b(cosf(t * b2f(tf[jj]) + b2f(tp[jj])));
  }
  x1[idx] = v;
}

__global__ __launch_bounds__(256) void k_hid(const float* msg1, const float* bgs1, const int* root_idx, float* hid){
  long idx = (long)blockIdx.x*256 + threadIdx.x;
  if (idx >= (long)NROWS*HD) return;
  int b = idx / HD, c = idx % HD;
  int s = c / DIM, j = c % DIM;
  int n = root_idx[b*4 + s];
  hid[idx] = fmaxf((msg1[(size_t)n*DIM + j] + bgs1[j]) * (1.0f/NET), 0.0f);
}

// ln0 -> bf16 rows for the qv GEMM
__global__ __launch_bounds__(256) void k_ln_bf16(const float* xin, const bf16* w, const bf16* b, bf16* xout){
  int row = blockIdx.x;
  const float* xr = xin + (size_t)row*HD;
  __shared__ float red[16];
  __shared__ float mu_s, rs_s;
  float s=0.f, s2=0.f;
  for (int j=threadIdx.x;j<HD;j+=256){ float v=xr[j]; s+=v; s2+=v*v; }
  for (int off=32; off; off>>=1){ s += __shfl_down(s,off); s2 += __shfl_down(s2,off); }
  int lane = threadIdx.x & 63, wid = threadIdx.x >> 6;
  if (lane==0){ red[wid]=s; red[8+wid]=s2; }
  __syncthreads();
  if (threadIdx.x==0){
    float S = red[0]+red[1]+red[2]+red[3];
    float S2 = red[8]+red[9]+red[10]+red[11];
    float mu = S * (1.0f/HD);
    float var = fmaxf(S2 * (1.0f/HD) - mu*mu, 0.f);
    mu_s = mu; rs_s = rsqrtf(var + 1e-5f);
  }
  __syncthreads();
  float mu = mu_s, rs = rs_s;
  for (int j=threadIdx.x;j<HD;j+=256){
    float v = (xr[j]-mu)*rs;
    xout[(size_t)row*HD + j] = f2b(v*b2f(w[j]) + b2f(b[j]));
  }
}

// q|v GEMM: (8192 x 200) @ (200 x 200 per gy) + bias -> qv f32 [row][gy*200+n]
__global__ __launch_bounds__(256) void k_qv_mfma(const bf16* __restrict__ xlnb, const bf16* __restrict__ wpkQV,
                                                 const bf16* bq, const bf16* bv, float* __restrict__ qv){
  constexpr int SR = 136;
  __shared__ bf16 xs[64*SR];
  int rb = blockIdx.x*64;
  int gy = blockIdx.y;
  int t = threadIdx.x;
  int lane = t&63, w = t>>6;
  int n_idx = lane&15, quad = lane>>4;
  f32x4 acc[4][4];
  #pragma unroll
  for (int i=0;i<4;i++)
    #pragma unroll
    for (int mt=0;mt<4;mt++) acc[i][mt] = (f32x4){0.f,0.f,0.f,0.f};
  const short8* wp8 = (const short8*)(wpkQV + (size_t)gy*8*13*512);
  short8 bz = {0,0,0,0,0,0,0,0};
  for (int c=0;c<2;c++){
    for (int ci=t; ci<64*32; ci+=256){
      int m = ci>>5, j4 = ci&31;
      int gcol = c*128 + j4*4;
      uint2 v = make_uint2(0u,0u);
      if (gcol < 200) v = *(const uint2*)(xlnb + (size_t)(rb+m)*200 + gcol);
      *(uint2*)(xs + m*SR + j4*4) = v;
    }
    __syncthreads();
    for (int ks=0; ks<4; ks++){
      short8 bfr[4];
      #pragma unroll
      for (int i=0;i<4;i++){
        int nt = w + 4*i;
        bfr[i] = (nt < 13) ? wp8[(((size_t)(c*4+ks))*13 + nt)*64 + lane] : bz;
      }
      short8 afr[4];
      #pragma unroll
      for (int mt=0;mt<4;mt++) afr[mt] = *(const short8*)(xs + (size_t)(mt*16+n_idx)*SR + ks*32 + quad*8);
      #pragma unroll
      for (int i=0;i<4;i++)
        #pragma unroll
        for (int mt=0;mt<4;mt++)
          acc[i][mt] = __builtin_amdgcn_mfma_f32_16x16x32_bf16(afr[mt], bfr[i], acc[i][mt], 0, 0, 0);
    }
    __syncthreads();
  }
  const bf16* bias = gy ? bv : bq;
  for (int i=0;i<4;i++){
    int nt = w + 4*i;
    if (nt >= 13) continue;
    int n = nt*16 + n_idx;
    if (n >= 200) continue;
    float bb = b2f(bias[n]);
    #pragma unroll
    for (int mt=0;mt<4;mt++){
      #pragma unroll
      for (int reg=0;reg<4;reg++){
        int m = rb + mt*16 + quad*4 + reg;
        qv[(size_t)m*400 + gy*200 + n] = acc[i][mt][reg] + bb;
      }
    }
  }
}

// attention core: scores -> softmax -> PV -> relu -> ln1 -> bf16 x3
__global__ __launch_bounds__(256) void k_att2(const float* __restrict__ qv,
                                              const bf16* ln1w, const bf16* ln1b,
                                              bf16* __restrict__ x3b){
  __shared__ float qs[HD], vs[HD], xs2[HD], att_s[64], red[16];
  __shared__ float mu_s, rs_s;
  int b = blockIdx.x, t = threadIdx.x;
  int lane = t & 63, wid = t >> 6;
  for (int idx=t; idx<1600; idx+=256){
    int s = idx/400, c = idx%400;
    float v = qv[((size_t)(b*4+s))*400 + c];
    if (c < 200) qs[s*200+c] = v; else vs[s*200 + c-200] = v;
  }
  __syncthreads();
  if (t < 64){
    int ha=t>>4, srow=(t>>2)&3, tt=t&3;
    const float* qa = qs + srow*200 + ha*50;
    const float* qb = qs + tt*200 + ha*50;
    float sc=0.f;
    for (int o=0;o<50;o++) sc += qa[o]*qb[o];
    att_s[ha*16 + srow*4 + tt] = sc;
  }
  __syncthreads();
  if (t < 16){
    int ha=t>>2, tt=t&3;
    float m=-1e30f;
    for (int srow=0;srow<4;srow++) m = fmaxf(m, att_s[ha*16+srow*4+tt]);
    float ex[4]; float zz=0.f;
    for (int srow=0;srow<4;srow++){ ex[srow]=expf(att_s[ha*16+srow*4+tt]-m); zz+=ex[srow]; }
    for (int srow=0;srow<4;srow++) att_s[ha*16+srow*4+tt] = ex[srow]/zz;
  }
  __syncthreads();
  for (int idx=t; idx<HD; idx+=256){
    int srow = idx/200, ha = (idx%200)/50, o = idx%50;
    float a=0.f;
    for (int tt=0;tt<4;tt++) a += att_s[ha*16+srow*4+tt]*vs[tt*200+ha*50+o];
    xs2[idx] = fmaxf(a, 0.f);
  }
  __syncthreads();
  float s=0.f, s2=0.f;
  for (int j=t;j<HD;j+=256){ float v=xs2[j]; s+=v; s2+=v*v; }
  for (int off=32; off; off>>=1){ s += __shfl_down(s,off); s2 += __shfl_down(s2,off); }
  if (lane==0){ red[wid]=s; red[8+wid]=s2; }
  __syncthreads();
  if (t==0){
    float S = red[0]+red[1]+red[2]+red[3];
    float S2 = red[8]+red[9]+red[10]+red[11];
    float mu = S * (1.0f/HD);
    float var = fmaxf(S2 * (1.0f/HD) - mu*mu, 0.f);
    mu_s = mu; rs_s = rsqrtf(var + 1e-5f);
  }
  __syncthreads();
  { float mu=mu_s, rs=rs_s;
    for (int j=t;j<HD;j+=256) x3b[(size_t)b*HD + j] = f2b((xs2[j]-mu)*rs*b2f(ln1w[j]) + b2f(ln1b[j])); }
}

// d1 GEMM: (2048 x 800) @ (800 x 200) + bias, relu -> bf16 x4
__global__ __launch_bounds__(256) void k_d1_mfma(const bf16* __restrict__ x3b, const bf16* __restrict__ wpkD1,
                                                 const bf16* bd1, bf16* __restrict__ x4b){
  constexpr int SR = 136;
  __shared__ bf16 xs[64*SR];
  int rb = blockIdx.x*64;
  int t = threadIdx.x;
  int lane = t&63, w = t>>6;
  int n_idx = lane&15, quad = lane>>4;
  f32x4 acc[4][4];
  #pragma unroll
  for (int i=0;i<4;i++)
    #pragma unroll
    for (int mt=0;mt<4;mt++) acc[i][mt] = (f32x4){0.f,0.f,0.f,0.f};
  const short8* wp8 = (const short8*)wpkD1;
  short8 bz = {0,0,0,0,0,0,0,0};
  for (int c=0;c<7;c++){
    for (int ci=t; ci<64*32; ci+=256){
      int m = ci>>5, j4 = ci&31;
      int gcol = c*128 + j4*4;
      uint2 v = make_uint2(0u,0u);
      if (gcol < 800) v = *(const uint2*)(x3b + (size_t)(rb+m)*800 + gcol);
      *(uint2*)(xs + m*SR + j4*4) = v;
    }
    __syncthreads();
    for (int ks=0; ks<4; ks++){
      short8 bfr[4];
      #pragma unroll
      for (int i=0;i<4;i++){
        int nt = w + 4*i;
        bfr[i] = (nt < 13) ? wp8[(((size_t)(c*4+ks))*13 + nt)*64 + lane] : bz;
      }
      short8 afr[4];
      #pragma unroll
      for (int mt=0;mt<4;mt++) afr[mt] = *(const short8*)(xs + (size_t)(mt*16+n_idx)*SR + ks*32 + quad*8);
      #pragma unroll
      for (int i=0;i<4;i++)
        #pragma unroll
        for (int mt=0;mt<4;mt++)
          acc[i][mt] = __builtin_amdgcn_mfma_f32_16x16x32_bf16(afr[mt], bfr[i], acc[i][mt], 0, 0, 0);
    }
    __syncthreads();
  }
  for (int i=0;i<4;i++){
    int nt = w + 4*i;
    if (nt >= 13) continue;
    int n = nt*16 + n_idx;
    if (n >= 200) continue;
    float bb = b2f(bd1[n]);
    #pragma unroll
    for (int mt=0;mt<4;mt++){
      #pragma unroll
      for (int reg=0;reg<4;reg++){
        int m = rb + mt*16 + quad*4 + reg;
        x4b[(size_t)m*200 + n] = f2b(fmaxf(acc[i][mt][reg] + bb, 0.f));
      }
    }
  }
}

__global__ __launch_bounds__(256) void k_pack_pred(const void* Wsub, const void* Wobj, bf16* wpkP,
                                                    const unsigned* flagp){
  long idx = (long)blockIdx.x*256 + threadIdx.x;
  long total = (long)2*PKS*PNT*512;
  if (idx >= total) return;
  int j = (int)(idx & 7), lane = (int)((idx>>3) & 63);
  long rem = idx >> 9;
  int ntile = (int)(rem % PNT); rem /= PNT;
  int ks = (int)(rem % PKS); int page = (int)(rem / PKS);
  int k = ks*32 + (lane>>4)*8 + j;
  int n = ntile*16 + (lane&15);
  const void* W = page ? Wobj : Wsub;
  bool f32m = flagp[0] != 0u;
  float v = 0.f;
  if (k < 300) v = f32m ? ((const float*)W)[(size_t)k*NUME + n]
                        : b2f(((const bf16*)W)[(size_t)k*NUME + n]);
  wpkP[idx] = f2b(v);
}

__global__ __launch_bounds__(256) void k_prep_pred(const bf16* x4b, const bf16* nSrel, const bf16* nOrel,
                                                    const int* rel, bf16* Apack){
  long idx = (long)blockIdx.x*256 + threadIdx.x;
  if (idx >= (long)2*1024*320) return;
  int j = (int)(idx % 320); long rem = idx/320;
  int row = (int)(rem % 1024); int page = (int)(rem / 1024);
  bf16 v = f2b(0.f);
  if (j < 200) v = x4b[((size_t)(page==0 ? 1024+row : row))*DIM + j];
  else if (j < 300){
    const bf16* re = (page==0) ? nOrel : nSrel;
    v = re[(size_t)rel[row]*DIMR + (j-200)];
  }
  Apack[idx] = v;
}

__global__ __launch_bounds__(256) void k_pred_mfma(const bf16* __restrict__ Apack, const bf16* __restrict__ wpkP,
                                                   const bf16* bsub, const bf16* bobj, void* outb,
                                                   const unsigned* flagp){
  constexpr int SR = 320 + 8;
  __shared__ bf16 As[64*SR];
  int page = blockIdx.z;
  int rb = blockIdx.y*64;
  int cb = blockIdx.x*16;
  int t = threadIdx.x;
  const bf16* Ap = Apack + (size_t)page*1024*320;
  for (int c=t; c<64*80; c+=256){
    int m=c/80, j4=c%80;
    *(uint2*)(As + m*SR + j4*4) = *(const uint2*)(Ap + (size_t)(rb+m)*320 + j4*4);
  }
  __syncthreads();
  int lane = t&63, w = t>>6;
  int n_idx = lane&15, quad = lane>>4;
  const short8* wp8 = (const short8*)(wpkP + (size_t)page*PKS*PNT*512);
  f32x4 acc[4][4];
  #pragma unroll
  for (int i=0;i<4;i++)
    #pragma unroll
    for (int mt=0;mt<4;mt++) acc[i][mt] = (f32x4){0.f,0.f,0.f,0.f};
  short8 bz = {0,0,0,0,0,0,0,0};
  for (int ks=0; ks<PKS; ks++){
    short8 bfr[4];
    #pragma unroll
    for (int i=0;i<4;i++){
      int ntile = cb + w + 4*i;
      bfr[i] = (ntile < PNT) ? wp8[((size_t)ks*PNT + ntile)*64 + lane] : bz;
    }
    short8 afr[4];
    #pragma unroll
    for (int mt=0;mt<4;mt++) afr[mt] = *(const short8*)(As + (size_t)(mt*16 + n_idx)*SR + ks*32 + quad*8);
    #pragma unroll
    for (int i=0;i<4;i++)
      #pragma unroll
      for (int mt=0;mt<4;mt++)
        acc[i][mt] = __builtin_amdgcn_mfma_f32_16x16x32_bf16(afr[mt], bfr[i], acc[i][mt], 0, 0, 0);
  }
  bool f32m = flagp[0] != 0u;
  const bf16* bias = page ? bobj : bsub;
  size_t elem_off = (size_t)page*BQ*NUME;
  for (int i=0;i<4;i++){
    int ntile = cb + w + 4*i;
    if (ntile >= PNT) continue;
    int n = ntile*16 + n_idx;
    float bb = b2f(bias[n]);
    #pragma unroll
    for (int mt=0;mt<4;mt++){
      #pragma unroll
      for (int reg=0;reg<4;reg++){
        int m = rb + mt*16 + quad*4 + reg;
        size_t oi = elem_off + (size_t)m*NUME + n;
        float val = acc[i][mt][reg] + bb;
        if (f32m) ((float*)outb)[oi] = val; else ((bf16*)outb)[oi] = f2b(val);
      }
    }
  }
}

// scalar fallback pred
__global__ __launch_bounds__(256) void k_pred(const bf16* xemb, const bf16* relemb, const int* rel,
                                              const void* W, const bf16* bias, void* outb, size_t elem_off,
                                              const unsigned* flagp){
  __shared__ float As[16*304];
  bool f32m = flagp[0] != 0u;
  int rb = blockIdx.y*16;
  int cb = blockIdx.x*512;
  int t = threadIdx.x;
  for (int idx=t; idx<16*300; idx+=256){
    int r = idx/300, i = idx%300;
    int row = rb + r;
    float v = (i < DIM) ? b2f(xemb[(size_t)row*DIM + i])
                        : b2f(relemb[(size_t)rel[row]*DIMR + (i-DIM)]);
    As[r*304+i] = v;
  }
  __syncthreads();
  int c0 = cb + t, c1 = cb + 256 + t;
  bool g0 = c0 < NUME, g1 = c1 < NUME;
  float acc0[16], acc1[16];
  #pragma unroll
  for (int r=0;r<16;r++){ acc0[r]=0.f; acc1[r]=0.f; }
  if (f32m){
    const float* W32 = (const float*)W;
    for (int k=0;k<300;k++){
      float w0 = g0 ? W32[(size_t)k*NUME + c0] : 0.f;
      float w1 = g1 ? W32[(size_t)k*NUME + c1] : 0.f;
      #pragma unroll
      for (int r=0;r<16;r++){ float a = As[r*304+k]; acc0[r] += a*w0; acc1[r] += a*w1; }
    }
  } else {
    const bf16* W16 = (const bf16*)W;
    for (int k=0;k<300;k++){
      float w0 = g0 ? b2f(W16[(size_t)k*NUME + c0]) : 0.f;
      float w1 = g1 ? b2f(W16[(size_t)k*NUME + c1]) : 0.f;
      #pragma unroll
      for (int r=0;r<16;r++){ float a = As[r*304+k]; acc0[r] += a*w0; acc1[r] += a*w1; }
    }
  }
  #pragma unroll
  for (int rr=0; rr<2; rr++){
    int c = rr ? c1 : c0;
    float* acc = rr ? acc1 : acc0;
    if (c < NUME){
      float bb = b2f(bias[c]);
      for (int r=0;r<16;r++){
        size_t oi = elem_off + (size_t)(rb+r)*NUME + c;
        float val = acc[r] + bb;
        if (f32m) ((float*)outb)[oi] = val; else ((bf16*)outb)[oi] = f2b(val);
      }
    }
  }
}

__global__ __launch_bounds__(256) void k_transpose(const void* in, bf16* out, int rows, int cols,
                                                   const unsigned* flagp){
  __shared__ bf16 tile[32][33];
  bool f32m = flagp[0] != 0u;
  int c0 = blockIdx.x*32, r0 = blockIdx.y*32;
  int tx = threadIdx.x % 32, ty = threadIdx.x / 32;
  for (int rr=ty; rr<32; rr+=8){
    int r = r0+rr, c = c0+tx;
    if (r<rows && c<cols){
      size_t i = (size_t)r*cols + c;
      tile[rr][tx] = f32m ? f2b(((const float*)in)[i]) : ((const bf16*)in)[i];
    }
  }
  __syncthreads();
  for (int rr=ty; rr<32; rr+=8){
    int ocol = c0+rr, orow = r0+tx;
    if (ocol<cols && orow<rows) out[(size_t)ocol*rows + orow] = tile[tx][rr];
  }
}

__global__ __launch_bounds__(256) void k_scatter(const int* copy_rows, const int* copy_cols, const int* rel,
                                                 const float* hid, const bf16* csrel, const bf16* corel,
                                                 const bf16* cWsubT, const bf16* cWobjT,
                                                 const bf16* cbsub, const bf16* cbobj,
                                                 void* outb, const unsigned* flagp){
  bool f32m = flagp[0] != 0u;
  int wid = threadIdx.x >> 6, lane = threadIdx.x & 63;
  long k = (long)blockIdx.x*4 + wid;
  if (k >= KK) return;
  int row = copy_rows[k], col = copy_cols[k];
  const float* chrow; const bf16* re; const bf16* wt; float bias_v;
  if (row < BQ){
    chrow = hid + ((size_t)(BQ+row))*HD + 600;
    re = corel + (size_t)rel[row]*DIMR;
    wt = cWsubT + (size_t)col*300;
    bias_v = b2f(cbsub[col]);
  } else {
    int rr = row - BQ;
    chrow = hid + ((size_t)rr)*HD + 600;
    re = csrel + (size_t)rel[rr]*DIMR;
    wt = cWobjT + (size_t)col*300;
    bias_v = b2f(cbobj[col]);
  }
  float s = 0.f;
  for (int i=lane; i<300; i+=64){
    float a = (i < DIM) ? chrow[i] : b2f(re[i-DIM]);
    s += a * b2f(wt[i]);
  }
  for (int off=32; off; off>>=1) s += __shfl_down(s, off);
  if (lane==0){
    size_t oi = (size_t)2*BQ*NUME + (size_t)row*NUME + col;
    float val = s + bias_v;
    if (f32m) ((float*)outb)[oi] = val; else ((bf16*)outb)[oi] = f2b(val);
  }
}

static inline dim3 GS(long n){ return dim3((unsigned)((n + 255)/256)); }

extern "C" void kernel_launch(void* const* d_in, const int* in_sizes, int n_in,
                              void* d_out, int out_size, void* d_ws, size_t ws_size,
                              hipStream_t stream){
  const int* rel       = (const int*)d_in[2];
  const int* ts_p      = (const int*)d_in[3];
  const int* nid0      = (const int*)d_in[4];
  const int* root_idx  = (const int*)d_in[5];
  const int* src0      = (const int*)d_in[6];
  const int* dst0      = (const int*)d_in[7];
  const int* src1      = (const int*)d_in[8];
  const int* dst1      = (const int*)d_in[9];
  const int* copy_rows = (const int*)d_in[10];
  const int* copy_cols = (const int*)d_in[11];
  const void* Wsub  = d_in[35];
  const void* Wobj  = d_in[37];
  const void* cWsub = d_in[41];
  const void* cWobj = d_in[43];

  // ---- workspace layout ----
  char* base = (char*)d_ws;
  size_t off = 0;
  auto alloc = [&](size_t bytes)->char*{
    char* p = base + off; off = (off + bytes + 255) & ~(size_t)255; return p;
  };
  unsigned* flagp = (unsigned*)alloc(256);
  long cvt_total = 0; for (int i=0;i<CVT_NREG;i++) cvt_total += CVT_N[i];
  bf16* normb = (bf16*)alloc((size_t)cvt_total*2);
  bf16* x0    = (bf16*)alloc((size_t)N0*DIN0*2);
  bf16* x1    = (bf16*)alloc((size_t)N1*DIN1*2);
  float* msg0 = (float*)alloc((size_t)N1*DIM*4);
  float* wal0 = (float*)alloc((size_t)NET*DIN0*4*4);
  float* war0 = (float*)alloc((size_t)NET*DIN0*4*4);
  float* wal1 = (float*)alloc((size_t)NET*DIN1*4*4);
  float* war1 = (float*)alloc((size_t)NET*DIN1*4*4);
  float* bgs0 = (float*)alloc(DIM*4);
  float* bgs1 = (float*)alloc(DIM*4);
  bf16* wpk0  = (bf16*)alloc((size_t)NET*4*13*512*2);
  bf16* wpk1  = (bf16*)alloc((size_t)NET*8*13*512*2);
  bf16* wpkE0 = (bf16*)alloc((size_t)4*9*512*2);
  bf16* wpkE1 = (bf16*)alloc((size_t)8*9*512*2);
  bf16* wpkQV = (bf16*)alloc((size_t)2*8*13*512*2);
  bf16* wpkD1 = (bf16*)alloc((size_t)28*13*512*2);
  size_t arena = off;
  // phase-1 (GAT layer 0)
  char* P1 = base + arena;
  bf16*  a0b = (bf16*)P1;                                   // NET*E0*8
  float* z0  = (float*)(P1 + (size_t)NET*E0*8);             // NET*N1*16
  size_t ext1 = (size_t)NET*E0*8 + (size_t)NET*N1*16;
  // phase-2 (layer 1 + tail) — overlays phase-1
  char* A = base + arena;
  bf16*  a1b  = (bf16*)A;
  float* z1   = (float*)(A + (size_t)NET*E1*8);
  size_t msg1_off = (size_t)NET*E1*8 + (size_t)NET*RNODES*16;
  float* msg1 = (float*)(A + msg1_off);
  size_t hid_off = msg1_off + (size_t)RNODES*DIM*4;
  float* hid  = (float*)(A + hid_off);
  size_t xlnb_off = hid_off + (size_t)NROWS*HD*4;
  bf16* xlnb = (bf16*)(A + xlnb_off);
  size_t qv_off = xlnb_off + (size_t)NROWS*HD*2;
  float* qvb = (float*)(A + qv_off);
  size_t x3b_off = qv_off + (size_t)NROWS*4*400*4;
  bf16* x3b = (bf16*)(A + x3b_off);
  size_t x4b_off = x3b_off + (size_t)NROWS*HD*2;
  bf16* x4b = (bf16*)(A + x4b_off);
  size_t ext2 = x4b_off + (size_t)NROWS*DIM*2;
  bf16* cWsubT = (bf16*)x0;
  bf16* cWobjT = (bf16*)((char*)x0 + (size_t)NUME*300*2);

  // ---- tail region: CSR + F buffers ----
  size_t extmax = ext1 > ext2 ? ext1 : ext2;
  size_t tail = (arena + extmax + 255) & ~(size_t)255;
  size_t cnt_sz  = (((size_t)NET*N1*4) + 255) & ~(size_t)255;
  size_t offs_sz = (((size_t)NET*(N1+1)*4) + 255) & ~(size_t)255;
  size_t ids_sz  = (((size_t)NET*E0PAD*4) + 255) & ~(size_t)255;
  unsigned* cnt  = (unsigned*)(base + tail);
  unsigned* offs = (unsigned*)(base + tail + cnt_sz);
  unsigned* cur  = (unsigned*)(base + tail + cnt_sz + offs_sz);
  int* ids = (int*)(base + tail + cnt_sz + 2*offs_sz);
  size_t F_off = tail + cnt_sz + 2*offs_sz + ids_sz;
  bf16* fbuf = (bf16*)(base + F_off);
  size_t fcap = (ws_size > F_off) ? (ws_size - F_off) : 0;
  bool sortok0 = fcap >= (size_t)NET*E0PAD*400;
  bool sortok1 = fcap >= (size_t)NET*E1PAD*400;
  // node-relation tables alias fbuf (dead before fbuf writes begin)
  float* tab0 = (float*)fbuf;
  float* tab1 = (float*)fbuf;
  bool elrok0 = fcap >= (size_t)N0*TABW*4;
  bool elrok1 = fcap >= (size_t)N1*TABW*4;
  // legacy er scratch (fallback only)
  bf16* er0f = (bf16*)x1;
  bf16* er1f = (bf16*)x0;
  // pred MFMA buffers alias fbuf (dead after last gather)
  size_t wpkP_sz = (size_t)2*PKS*PNT*512*2;
  size_t Apack_sz = (size_t)2*1024*320*2;
  bf16* wpkP  = (bf16*)(base + F_off);
  bf16* Apack = (bf16*)(base + F_off + wpkP_sz);
  bool predok = fcap >= (wpkP_sz + Apack_sz);

  long cum[CVT_NREG+1]; cum[0]=0;
  for (int i=0;i<CVT_NREG;i++) cum[i+1] = cum[i] + CVT_N[i];
  auto NP = [&](int i)->const bf16*{ return normb + cum[i]; };
  const bf16 *nEmb=NP(0), *nTf=NP(1), *nTp=NP(2), *nWg0=NP(3), *nAl0=NP(4), *nAr0=NP(5), *nBg0=NP(6),
             *nWg1=NP(7), *nAl1=NP(8), *nAr1=NP(9), *nBg1=NP(10), *nLn0w=NP(11), *nLn0b=NP(12),
             *nWq=NP(13), *nBq=NP(14), *nWv=NP(15), *nBv=NP(16), *nLn1w=NP(17), *nLn1b=NP(18),
             *nWd1=NP(19), *nBd1=NP(20), *nSrel=NP(21), *nOrel=NP(22), *nBsub=NP(23), *nBobj=NP(24),
             *nCsrel=NP(25), *nCorel=NP(26), *nCbsub=NP(27), *nCbobj=NP(28);

  // ---- phase 0 ----
  k_detect<<<dim3(1),64,0,stream>>>((const unsigned*)d_in[13], flagp);
  CvtSrcs srcs;
  for (int i=0;i<CVT_NREG;i++) srcs.p[i] = d_in[CVT_DIN[i]];
  CvtMeta meta;
  { int c=0, bc=0;
    for (int i=0;i<CVT_NREG;i++){ meta.cum[i]=c; meta.bcum[i]=bc; c+=CVT_N[i]; bc += (CVT_N[i]+255)/256; }
    meta.cum[CVT_NREG]=c; meta.bcum[CVT_NREG]=bc;
    k_cvt<<<dim3((unsigned)bc),256,0,stream>>>(srcs, meta, normb, flagp);
  }
  k_fill_u32<<<GS((long)NET*N1*4),256,0,stream>>>((unsigned*)z0, 0u, (long)NET*N1*4);
  k_fill_out<<<GS((long)2*BQ*NUME),256,0,stream>>>(d_out, flagp);
  k_prep_w<<<GS(NET*DIN0*4),256,0,stream>>>(nWg0, nAl0, nAr0, wal0, war0, DIN0);
  k_prep_w<<<GS(NET*DIN1*4),256,0,stream>>>(nWg1, nAl1, nAr1, wal1, war1, DIN1);
  k_pack<<<GS((long)NET*4*13*512),256,0,stream>>>(nWg0, wpk0, DIN0, 4);
  k_pack<<<GS((long)NET*8*13*512),256,0,stream>>>(nWg1, wpk1, DIN1, 8);
  k_pack_walr<<<GS((long)4*9*512),256,0,stream>>>(wal0, war0, wpkE0, DIN0, 4);
  k_pack_walr<<<GS((long)8*9*512),256,0,stream>>>(wal1, war1, wpkE1, DIN1, 8);
  k_pack_qv<<<GS((long)2*8*13*512),256,0,stream>>>(nWq, nWv, wpkQV);
  k_pack_d1<<<GS((long)28*13*512),256,0,stream>>>(nWd1, wpkD1);
  k_bgs<<<GS(2*DIM),256,0,stream>>>(nBg0, nBg1, bgs0, bgs1);
  k_build_x0<<<GS((long)N0*DIN0),256,0,stream>>>(nid0, ts_p, nEmb, nTf, nTp, x0);

  // ---- GAT layer 0: edge logits ----
  if (elrok0){
    k_elr<DIN0,4><<<dim3(N0/64),256,0,stream>>>(x0, wpkE0, tab0);
    k_edge_lite<<<GS((long)NET*E0),256,0,stream>>>(tab0, src0, dst0, a0b, z0, E0, N1);
  } else {
    k_er<DIN0><<<GS((long)NET*N1),256,0,stream>>>(x0, war0, er0f, N1);
    k_edge<DIN0><<<GS((long)NET*E0),256,0,stream>>>(x0, wal0, er0f, src0, dst0, a0b, z0, E0, N1);
  }
  // ---- GAT layer 0: message accumulate ----
  if (sortok0){
    k_fill_u32<<<GS((long)NET*N1),256,0,stream>>>(cnt, 0u, (long)NET*N1);
    k_count2<<<GS((long)NET*E0),256,0,stream>>>(dst0, E0, N1, cnt);
    k_scan2<<<dim3(NET),256,0,stream>>>(cnt, offs, cur, N1, E0, E0PAD);
    k_fillcsr2<<<GS((long)NET*E0),256,0,stream>>>(dst0, E0, N1, cur, ids);
    k_acc_mfma<DIN0,4><<<dim3((E0+63)/64, NET),256,0,stream>>>(x0, wpk0, a0b, z0, src0, dst0, ids,
                                                                msg0, fbuf, E0, E0PAD, N1, 1);
    k_gather2<<<dim3((N1+3)/4),256,0,stream>>>(fbuf, offs, msg0, N1);
  } else {
    k_fill_u32<<<GS((long)N1*DIM),256,0,stream>>>((unsigned*)msg0, 0u, (long)N1*DIM);
    k_acc_mfma<DIN0,4><<<dim3((E0+63)/64, NET),256,0,stream>>>(x0, wpk0, a0b, z0, src0, dst0, (int*)nullptr,
                                                                msg0, (bf16*)nullptr, E0, E0, N1, 0);
  }

  // ---- build x1, GAT layer 1 ----
  k_build_x1<<<GS((long)N1*DIN1),256,0,stream>>>(nid0, ts_p, msg0, bgs0, nTf, nTp, x1);
  k_fill_u32<<<GS((long)NET*RNODES*4),256,0,stream>>>((unsigned*)z1, 0u, (long)NET*RNODES*4);
  if (elrok1){
    k_elr<DIN1,8><<<dim3(N1/64),256,0,stream>>>(x1, wpkE1, tab1);
    k_edge_lite<<<GS((long)NET*E1),256,0,stream>>>(tab1, src1, dst1, a1b, z1, E1, RNODES);
  } else {
    k_er<DIN1><<<GS((long)NET*RNODES),256,0,stream>>>(x1, war1, er1f, RNODES);
    k_edge<DIN1><<<GS((long)NET*E1),256,0,stream>>>(x1, wal1, er1f, src1, dst1, a1b, z1, E1, RNODES);
  }
  if (sortok1){
    k_fill_u32<<<GS((long)NET*RNODES),256,0,stream>>>(cnt, 0u, (long)NET*RNODES);
    k_count2<<<GS((long)NET*E1),256,0,stream>>>(dst1, E1, RNODES, cnt);
    k_scan2<<<dim3(NET),256,0,stream>>>(cnt, offs, cur, RNODES, E1, E1PAD);
    k_fillcsr2<<<GS((long)NET*E1),256,0,stream>>>(dst1, E1, RNODES, cur, ids);
    k_acc_mfma<DIN1,8><<<dim3((E1+63)/64, NET),256,0,stream>>>(x1, wpk1, a1b, z1, src1, dst1, ids,
                                                                msg1, fbuf, E1, E1PAD, RNODES, 1);
    k_gather2<<<dim3((RNODES+3)/4),256,0,stream>>>(fbuf, offs, msg1, RNODES);
  } else {
    k_fill_u32<<<GS((long)RNODES*DIM),256,0,stream>>>((unsigned*)msg1, 0u, (long)RNODES*DIM);
    k_acc_mfma<DIN1,8><<<dim3((E1+63)/64, NET),256,0,stream>>>(x1, wpk1, a1b, z1, src1, dst1, (int*)nullptr,
                                                                msg1, (bf16*)nullptr, E1, E1, RNODES, 0);
  }

  // ---- pred W pack (aliases fbuf — dead after last gather) ----
  if (predok)
    k_pack_pred<<<GS((long)2*PKS*PNT*512),256,0,stream>>>(Wsub, Wobj, wpkP, flagp);

  // ---- gather hid, copy-head scatter ----
  k_hid<<<GS((long)NROWS*HD),256,0,stream>>>(msg1, bgs1, root_idx, hid);
  k_transpose<<<dim3(625,10),256,0,stream>>>(cWsub, cWsubT, 300, NUME, flagp);
  k_transpose<<<dim3(625,10),256,0,stream>>>(cWobj, cWobjT, 300, NUME, flagp);
  k_scatter<<<dim3((KK+3)/4),256,0,stream>>>(copy_rows, copy_cols, rel, hid, nCsrel, nCorel,
                                             cWsubT, cWobjT, nCbsub, nCbobj, d_out, flagp);

  // ---- attention tail (MFMA) ----
  k_ln_bf16<<<dim3(NROWS),256,0,stream>>>(hid, nLn0w, nLn0b, xlnb);
  k_qv_mfma<<<dim3(NROWS*4/64, 2),256,0,stream>>>(xlnb, wpkQV, nBq, nBv, qvb);
  k_att2<<<dim3(NROWS),256,0,stream>>>(qvb, nLn1w, nLn1b, x3b);
  k_d1_mfma<<<dim3(NROWS/64),256,0,stream>>>(x3b, wpkD1, nBd1, x4b);

  // ---- final predictions ----
  if (predok){
    k_prep_pred<<<GS((long)2*1024*320),256,0,stream>>>(x4b, nSrel, nOrel, rel, Apack);
    k_pred_mfma<<<dim3(79,16,2),256,0,stream>>>(Apack, wpkP, nBsub, nBobj, d_out, flagp);
  } else {
    k_pred<<<dim3(40,64),256,0,stream>>>(x4b + (size_t)BQ*DIM, nOrel, rel, Wsub, nBsub, d_out, 0, flagp);
    k_pred<<<dim3(40,64),256,0,stream>>>(x4b,                  nSrel, rel, Wobj, nBobj, d_out, (size_t)BQ*NUME, flagp);
  }
  (void)in_sizes; (void)n_in; (void)out_size; (void)ws_size;
}